// Round 3
// baseline (7180.128 us; speedup 1.0000x reference)
//
#include <hip/hip_runtime.h>

typedef unsigned short u16;

// ======================= small utility kernels =======================

__global__ void zero8(int* c){ if (threadIdx.x < 8) c[threadIdx.x] = 0; }

// f32 transpose: in [R][C] -> out [C][R]
__global__ __launch_bounds__(256)
void transpose_f32(const float* __restrict__ in, float* __restrict__ outp, int R, int C)
{
  __shared__ float tile[32][33];
  const int c0 = blockIdx.x << 5, r0 = blockIdx.y << 5;
  const int tx = threadIdx.x, ty = threadIdx.y;
  #pragma unroll
  for (int i = ty; i < 32; i += 8)
    tile[i][tx] = in[(long)(r0 + i) * C + c0 + tx];
  __syncthreads();
  #pragma unroll
  for (int i = ty; i < 32; i += 8)
    outp[(long)(c0 + i) * R + r0 + tx] = tile[tx][i];
}

// ======================= f32 tiled GEMM (VALU) =======================
// C[M][N] = A[M][K] @ B[K][N] (+bias, +relu).  B in natural [K][N] layout.
// AMAP: 0 = A row r (identity; local row when SEG)
//       1 = h_all row map: r -> (b = r>>11, t = r&2047): t<1024 ? hc : h
//       2 = gather: A row = gather[rbase + r] (clamped to [0,maxA))
// SEG:  rbase = segoff[0], cnt = segcnt[0] (launched per-expert)
// CGLOBAL: C row = rbase + r (else local r)

template<int AMAP, bool RELU, bool BIAS, bool SEG, bool CGLOBAL>
__global__ __launch_bounds__(256)
void gemmf(const float* __restrict__ A, const float* __restrict__ A2,
           const float* __restrict__ B, float* __restrict__ C,
           const float* __restrict__ bias, int M, int N, int Kd, int maxA,
           const int* __restrict__ segoff, const int* __restrict__ segcnt,
           const int* __restrict__ gather)
{
  __shared__ float As[64][17];
  __shared__ float Bs[16][68];

  int rbase = 0, cnt = M;
  if (SEG){ rbase = segoff[0]; cnt = segcnt[0]; }
  const int tm = blockIdx.y, tn = blockIdx.x;
  if (tm * 64 >= cnt) return;
  const int cn0 = tn << 6;

  const int t = threadIdx.x;
  // staging indices
  const int sar = t >> 2;            // A row 0..63
  const int sac = (t & 3) << 2;      // A col {0,4,8,12}
  const int sbr = t >> 4;            // B row 0..15
  const int sbc = (t & 15) << 2;     // B col 0..60
  // compute indices
  const int tr = (t >> 4) << 2;      // out row base 0..60
  const int tc = (t & 15) << 2;      // out col base 0..60

  // resolve A row pointer for staging
  const float* aptr;
  {
    int r = tm*64 + sar;
    int rc = (r < cnt) ? r : (cnt - 1);
    if (AMAP == 1){
      int gr = rc;                   // non-SEG path
      int b = gr >> 11, tt = gr & 2047;
      aptr = (tt < 1024) ? (A  + ((long)b*1024 + tt)*1024)
                         : (A2 + ((long)b*1024 + (tt-1024))*1024);
    } else if (AMAP == 2){
      int gi = rbase + rc; gi = (gi < 0) ? 0 : ((gi > 8191) ? 8191 : gi);
      int tok = gather[gi];
      tok = (tok < 0) ? 0 : ((tok >= maxA) ? (maxA-1) : tok);
      aptr = A + (long)tok * Kd;
    } else {
      aptr = A + (long)rc * Kd;      // local row (SEG) or global (non-SEG)
    }
  }

  float acc[4][4];
  #pragma unroll
  for (int i=0;i<4;i++)
    #pragma unroll
    for (int j=0;j<4;j++) acc[i][j] = 0.f;

  const int nk = Kd >> 4;
  for (int kt = 0; kt < nk; ++kt){
    float4 av = *(const float4*)(aptr + kt*16 + sac);
    float4 bv = *(const float4*)(B + (long)(kt*16 + sbr)*N + cn0 + sbc);
    __syncthreads();
    *(float4*)&As[sar][sac] = av;
    *(float4*)&Bs[sbr][sbc] = bv;
    __syncthreads();
    #pragma unroll
    for (int kk = 0; kk < 16; ++kk){
      float a0 = As[tr+0][kk], a1 = As[tr+1][kk], a2 = As[tr+2][kk], a3 = As[tr+3][kk];
      float4 b4 = *(const float4*)&Bs[kk][tc];
      acc[0][0] += a0*b4.x; acc[0][1] += a0*b4.y; acc[0][2] += a0*b4.z; acc[0][3] += a0*b4.w;
      acc[1][0] += a1*b4.x; acc[1][1] += a1*b4.y; acc[1][2] += a1*b4.z; acc[1][3] += a1*b4.w;
      acc[2][0] += a2*b4.x; acc[2][1] += a2*b4.y; acc[2][2] += a2*b4.z; acc[2][3] += a2*b4.w;
      acc[3][0] += a3*b4.x; acc[3][1] += a3*b4.y; acc[3][2] += a3*b4.z; acc[3][3] += a3*b4.w;
    }
  }

  #pragma unroll
  for (int i=0;i<4;i++){
    const int r = tm*64 + tr + i;
    if (r >= cnt) continue;
    const long crow = CGLOBAL ? (long)(rbase + r) : (long)r;
    #pragma unroll
    for (int j=0;j<4;j++){
      const int c = cn0 + tc + j;
      float vv = acc[i][j];
      if (BIAS) vv += bias[c];
      if (RELU) vv = fmaxf(vv, 0.f);
      C[crow * N + c] = vv;
    }
  }
}

// ======================= f32 sliding-window attention =======================
// score[i][j] = q_i . (k_{i+j} + pe_j) / 8,  j in [0,1024);  out_i = sum_j p[i][j] v_{i+j}

__global__ __launch_bounds__(256)
void attn_f32(const float* __restrict__ q, const float* __restrict__ k,
              const float* __restrict__ v, const float* __restrict__ peT,
              float* __restrict__ outp)
{
  __shared__ float s[8][1024];     // 32 KB
  __shared__ float qs[8][64];      //  2 KB
  __shared__ float kvf[64][68];    // 17.4 KB
  const int qb0 = blockIdx.x << 3;
  const int hd = blockIdx.y, b = blockIdx.z;
  const int t = threadIdx.x;

  for (int i = t; i < 512; i += 256){
    int qq = i >> 6, d = i & 63;
    qs[qq][d] = q[((long)(b*1024 + qb0 + qq))*1024 + hd*64 + d];
  }
  const long kbase = (long)b * 2048;

  // phase A: scores
  for (int c = 0; c < 17; ++c){
    const int tb = qb0 + (c << 6);
    __syncthreads();
    for (int i = t; i < 1024; i += 256){
      int rr = i >> 4, c4 = i & 15;
      int tabs = tb + rr;
      if (tabs < 2048)
        *(float4*)&kvf[rr][c4<<2] = *(const float4*)(k + (kbase + tabs)*1024 + hd*64 + (c4<<2));
    }
    __syncthreads();
    #pragma unroll
    for (int pp = 0; pp < 2; ++pp){
      int pidx = t + (pp << 8);
      int qq = pidx >> 6, tt = pidx & 63;
      int j = tb + tt - qb0 - qq;
      if (j >= 0 && j < 1024){
        const float4* kp  = (const float4*)&kvf[tt][0];
        const float4* pep = (const float4*)(peT + (long)j*64);
        const float4* qp  = (const float4*)&qs[qq][0];
        float acc = 0.f;
        #pragma unroll
        for (int d4 = 0; d4 < 16; ++d4){
          float4 kk = kp[d4];
          float4 pe = pep[d4];
          float4 qv = qp[d4];
          acc += qv.x * (kk.x + pe.x);
          acc += qv.y * (kk.y + pe.y);
          acc += qv.z * (kk.z + pe.z);
          acc += qv.w * (kk.w + pe.w);
        }
        s[qq][j] = acc * 0.125f;
      }
    }
  }
  __syncthreads();

  // phase B: softmax (32 lanes per row; xor offsets <32 stay within halves)
  {
    int qq = t >> 5, j0 = t & 31;
    float mx = -3.0e38f;
    for (int j = j0; j < 1024; j += 32) mx = fmaxf(mx, s[qq][j]);
    #pragma unroll
    for (int o = 16; o; o >>= 1) mx = fmaxf(mx, __shfl_xor(mx, o, 64));
    float sum = 0.f;
    for (int j = j0; j < 1024; j += 32){
      float ee = __expf(s[qq][j] - mx);
      s[qq][j] = ee; sum += ee;
    }
    #pragma unroll
    for (int o = 16; o; o >>= 1) sum += __shfl_xor(sum, o, 64);
    float inv = 1.f / sum;
    for (int j = j0; j < 1024; j += 32) s[qq][j] *= inv;
  }

  // phase C: PV
  float oacc0 = 0.f, oacc1 = 0.f;
  const int qqA = t >> 6, dA = t & 63;
  const int qqB = qqA + 4;
  for (int c = 0; c < 17; ++c){
    const int tb = qb0 + (c << 6);
    __syncthreads();
    for (int i = t; i < 1024; i += 256){
      int rr = i >> 4, c4 = i & 15;
      int tabs = tb + rr;
      if (tabs < 2048)
        *(float4*)&kvf[rr][c4<<2] = *(const float4*)(v + (kbase + tabs)*1024 + hd*64 + (c4<<2));
    }
    __syncthreads();
    {
      int i0 = qb0 + qqA;
      int jlo = (tb - i0 < 0) ? 0 : (tb - i0);
      int jhi = (tb + 64 - i0 < 1024) ? (tb + 64 - i0) : 1024;
      for (int j = jlo; j < jhi; ++j)
        oacc0 += s[qqA][j] * kvf[i0 + j - tb][dA];
    }
    {
      int i1 = qb0 + qqB;
      int jlo = (tb - i1 < 0) ? 0 : (tb - i1);
      int jhi = (tb + 64 - i1 < 1024) ? (tb + 64 - i1) : 1024;
      for (int j = jlo; j < jhi; ++j)
        oacc1 += s[qqB][j] * kvf[i1 + j - tb][dA];
    }
  }
  outp[((long)(b*1024 + qb0 + qqA))*1024 + hd*64 + dA] = oacc0;
  outp[((long)(b*1024 + qb0 + qqB))*1024 + hd*64 + dA] = oacc1;
}

// ======================= layernorm / gate / moe plumbing =======================

__device__ __forceinline__ void block_reduce2(float& s1, float& s2){
  #pragma unroll
  for (int o = 32; o; o >>= 1){
    s1 += __shfl_xor(s1, o, 64);
    s2 += __shfl_xor(s2, o, 64);
  }
  __shared__ float r1[4], r2[4];
  const int wid = threadIdx.x >> 6;
  if ((threadIdx.x & 63) == 0){ r1[wid] = s1; r2[wid] = s2; }
  __syncthreads();
  s1 = r1[0] + r1[1] + r1[2] + r1[3];
  s2 = r2[0] + r2[1] + r2[2] + r2[3];
  __syncthreads();
}

__global__ __launch_bounds__(256)
void add_ln_kernel(const float* __restrict__ a, const float* __restrict__ r,
                   const float* __restrict__ g, const float* __restrict__ bb,
                   float* __restrict__ of)
{
  const long row = blockIdx.x;
  const int t = threadIdx.x;
  float y[4]; float sum = 0.f, sq = 0.f;
  #pragma unroll
  for (int i = 0; i < 4; ++i){
    const long idx = row*1024 + t + (i<<8);
    float vv = a[idx] + r[idx];
    y[i] = vv; sum += vv; sq += vv*vv;
  }
  block_reduce2(sum, sq);
  const float mu = sum * (1.f/1024.f);
  const float var = fmaxf(sq * (1.f/1024.f) - mu*mu, 0.f);
  const float rs = rsqrtf(var + 1e-5f);
  #pragma unroll
  for (int i = 0; i < 4; ++i){
    const int hcol = t + (i<<8);
    of[row*1024 + hcol] = (y[i] - mu) * rs * g[hcol] + bb[hcol];
  }
}

__global__ __launch_bounds__(256)
void gate_kernel(const float* __restrict__ x, const float* __restrict__ gw,
                 const float* __restrict__ gb, int* __restrict__ eidx,
                 float* __restrict__ esc, int* __restrict__ counts)
{
  const long row = blockIdx.x;
  const int t = threadIdx.x;
  float a[8];
  #pragma unroll
  for (int e=0;e<8;e++) a[e]=0.f;
  for (int hcol = t; hcol < 1024; hcol += 256){
    float xv = x[row*1024 + hcol];
    const float* gr = gw + hcol*8;
    #pragma unroll
    for (int e=0;e<8;e++) a[e] += xv * gr[e];
  }
  #pragma unroll
  for (int e=0;e<8;e++)
    #pragma unroll
    for (int o=32;o;o>>=1) a[e] += __shfl_xor(a[e], o, 64);
  __shared__ float red[4][8];
  const int wid = t >> 6;
  if ((t & 63)==0){
    #pragma unroll
    for (int e=0;e<8;e++) red[wid][e]=a[e];
  }
  __syncthreads();
  if (t == 0){
    float l[8];
    #pragma unroll
    for (int e=0;e<8;e++) l[e] = red[0][e]+red[1][e]+red[2][e]+red[3][e] + gb[e];
    int i0 = 0; float v0 = l[0];
    #pragma unroll
    for (int e=1;e<8;e++) if (l[e] > v0){ v0=l[e]; i0=e; }
    int i1 = -1; float v1 = -3.0e38f;
    #pragma unroll
    for (int e=0;e<8;e++) if (e != i0 && l[e] > v1){ v1=l[e]; i1=e; }
    float e1 = __expf(v1 - v0);
    float den = 1.f + e1;
    eidx[row*2+0]=i0; eidx[row*2+1]=i1;
    esc[row*2+0]=1.f/den; esc[row*2+1]=e1/den;
    atomicAdd(&counts[i0],1); atomicAdd(&counts[i1],1);
  }
}

__global__ void scan_kernel(const int* __restrict__ counts, int* __restrict__ offs,
                            int* __restrict__ curs)
{
  if (threadIdx.x == 0 && blockIdx.x == 0){
    int acc = 0;
    for (int e=0;e<8;e++){ offs[e]=acc; curs[e]=acc; acc += counts[e]; }
  }
}

__global__ __launch_bounds__(256)
void scatter_kernel(const int* __restrict__ eidx, int* __restrict__ curs,
                    int* __restrict__ stok, int* __restrict__ ppos)
{
  int id = blockIdx.x*256 + threadIdx.x;
  if (id >= 8192) return;
  int e = eidx[id];
  e = (e < 0) ? 0 : ((e > 7) ? 7 : e);
  int pos = atomicAdd(&curs[e], 1);
  pos = (pos < 0) ? 0 : ((pos > 8191) ? 8191 : pos);
  stok[pos] = id >> 1;
  ppos[id] = pos;
}

__global__ __launch_bounds__(256)
void moe_combine_ln(const float* __restrict__ h1, const float* __restrict__ pout,
                    const float* __restrict__ esc, const int* __restrict__ ppos,
                    const float* __restrict__ mg, const float* __restrict__ mb,
                    const float* __restrict__ n2g, const float* __restrict__ n2b,
                    float* __restrict__ outp)
{
  const long row = blockIdx.x;
  const int t = threadIdx.x;
  int p0i = ppos[row*2+0], p1i = ppos[row*2+1];
  p0i = (p0i < 0) ? 0 : ((p0i > 8191) ? 8191 : p0i);
  p1i = (p1i < 0) ? 0 : ((p1i > 8191) ? 8191 : p1i);
  const long p0 = p0i, p1 = p1i;
  const float s0 = esc[row*2+0], s1 = esc[row*2+1];
  float x[4], y[4];
  float sum=0.f, sq=0.f;
  #pragma unroll
  for (int i=0;i<4;i++){
    const int hcol = t + (i<<8);
    const long idx = row*1024 + hcol;
    float xv = h1[idx];
    float m = s0 * pout[p0*1024 + hcol] + s1 * pout[p1*1024 + hcol];
    x[i]=xv; y[i]=xv+m; sum+=y[i]; sq+=y[i]*y[i];
  }
  block_reduce2(sum, sq);
  float mu = sum*(1.f/1024.f), var = fmaxf(sq*(1.f/1024.f)-mu*mu, 0.f), rs = rsqrtf(var+1e-5f);
  float zz[4]; float sum2=0.f, sq2=0.f;
  #pragma unroll
  for (int i=0;i<4;i++){
    const int hcol = t + (i<<8);
    float core = (y[i]-mu)*rs*mg[hcol]+mb[hcol];
    zz[i] = x[i] + core; sum2+=zz[i]; sq2+=zz[i]*zz[i];
  }
  block_reduce2(sum2, sq2);
  float mu2 = sum2*(1.f/1024.f), var2 = fmaxf(sq2*(1.f/1024.f)-mu2*mu2, 0.f), rs2 = rsqrtf(var2+1e-5f);
  #pragma unroll
  for (int i=0;i<4;i++){
    const int hcol = t + (i<<8);
    outp[row*1024 + hcol] = (zz[i]-mu2)*rs2*n2g[hcol]+n2b[hcol];
  }
}

// ======================= launcher =======================
// Workspace (peak 146 MB; METADATA FIRST at offset 0):
//   0..1MB    : counts/offs/curs/eidx/esc/stok/ppos
//   1..2MB    : peT f32 [1024][64]
//   2..18MB   : q    [4096][1024] f32     (QKV -> attn)
//   18..50MB  : k    [8192][1024] f32     (-> attn)   | after attn: h1 18..34, aproj 34..50
//   50..82MB  : v    [8192][1024] f32     (-> attn)   | after attn: pout [8192][1024] 50..82
//   82..98MB  : aout [4096][1024] f32     (attn -> WO GEMM)
//   82..146MB : xhid_e [4096][4096] f32   (per-expert, written stage 6, over dead aout)

extern "C" void kernel_launch(void* const* d_in, const int* in_sizes, int n_in,
                              void* d_out, int out_size, void* d_ws, size_t ws_size,
                              hipStream_t stream)
{
  const float* h      = (const float*)d_in[0];
  const float* hc     = (const float*)d_in[1];
  const float* key_pe = (const float*)d_in[2];
  const float* wq     = (const float*)d_in[3];
  const float* wk     = (const float*)d_in[4];
  const float* wv     = (const float*)d_in[5];
  const float* wo     = (const float*)d_in[6];
  const float* n1g    = (const float*)d_in[7];
  const float* n1b    = (const float*)d_in[8];
  const float* n2g    = (const float*)d_in[9];
  const float* n2b    = (const float*)d_in[10];
  const float* mlg    = (const float*)d_in[11];
  const float* mlb    = (const float*)d_in[12];
  const float* gw     = (const float*)d_in[13];
  const float* gb     = (const float*)d_in[14];
  const float* ew1    = (const float*)d_in[15];
  const float* eb1    = (const float*)d_in[16];
  const float* ew2    = (const float*)d_in[17];
  const float* eb2    = (const float*)d_in[18];
  float* outp = (float*)d_out;

  const size_t MB = 1ull << 20;
  char* base = (char*)d_ws;
  // metadata first (offset 0) — safe even for small ws_size
  int*   counts= (int*)(base);             // 32B
  int*   offs  = (int*)(base + 256);
  int*   curs  = (int*)(base + 512);
  int*   eidx  = (int*)(base + 1024);      // 32KB
  float* esc   = (float*)(base + 64*1024); // 32KB
  int*   stok  = (int*)(base + 128*1024);  // 32KB
  int*   ppos  = (int*)(base + 192*1024);  // 32KB
  float* peT   = (float*)(base + 1*MB);    // 256KB
  float* q     = (float*)(base + 2*MB);    // 16MB
  float* kbuf  = (float*)(base + 18*MB);   // 32MB
  float* h1    = (float*)(base + 18*MB);   //   alias (after attn)
  float* aproj = (float*)(base + 34*MB);   //   alias (after attn)
  float* vbuf  = (float*)(base + 50*MB);   // 32MB
  float* pout  = (float*)(base + 50*MB);   //   alias (after attn)
  float* aout  = (float*)(base + 82*MB);   // 16MB
  float* xhid  = (float*)(base + 82*MB);   // 64MB (over dead aout, stage 6+)

  zero8<<<1, 64, 0, stream>>>(counts);

  // pe transpose: [64][1024] -> [1024][64]
  transpose_f32<<<dim3(32,2,1), dim3(32,8), 0, stream>>>(key_pe, peT, 64, 1024);

  // QKV projections (f32)
  gemmf<0,false,false,false,false><<<dim3(16,64), 256, 0, stream>>>(h,  nullptr, wq, q,    nullptr, 4096, 1024, 1024, 4096, nullptr, nullptr, nullptr);
  gemmf<1,false,false,false,false><<<dim3(16,128),256, 0, stream>>>(hc, h,       wk, kbuf, nullptr, 8192, 1024, 1024, 8192, nullptr, nullptr, nullptr);
  gemmf<1,false,false,false,false><<<dim3(16,128),256, 0, stream>>>(hc, h,       wv, vbuf, nullptr, 8192, 1024, 1024, 8192, nullptr, nullptr, nullptr);

  // attention (f32)
  attn_f32<<<dim3(128,16,4), 256, 0, stream>>>(q, kbuf, vbuf, peT, aout);

  // output projection + residual LN (h1/aproj overlay dead k)
  gemmf<0,false,false,false,false><<<dim3(16,64), 256, 0, stream>>>(aout, nullptr, wo, aproj, nullptr, 4096, 1024, 1024, 4096, nullptr, nullptr, nullptr);
  add_ln_kernel<<<4096, 256, 0, stream>>>(h, aproj, n1g, n1b, h1);

  // MoE gate + bucketing (f32 gate — exact top-2 vs reference)
  gate_kernel<<<4096, 256, 0, stream>>>(h1, gw, gb, eidx, esc, counts);
  scan_kernel<<<1, 64, 0, stream>>>(counts, offs, curs);
  scatter_kernel<<<32, 256, 0, stream>>>(eidx, curs, stok, ppos);

  // per-expert FFN (f32); xhid local rows, pout global rows
  for (int e = 0; e < 8; ++e){
    gemmf<2,true, true, true, false><<<dim3(64,64), 256, 0, stream>>>(
        h1, nullptr, ew1 + (long)e*1024*4096, xhid, eb1 + (long)e*4096,
        0, 4096, 1024, 4096, offs + e, counts + e, stok);
    gemmf<0,false,true, true, true ><<<dim3(16,64), 256, 0, stream>>>(
        xhid, nullptr, ew2 + (long)e*4096*1024, pout, eb2 + (long)e*1024,
        0, 1024, 4096, 4096, offs + e, counts + e, nullptr);
  }

  // combine + the two trailing layernorms
  moe_combine_ln<<<4096, 256, 0, stream>>>(h1, pout, esc, ppos, mlg, mlb, n2g, n2b, outp);
}

// Round 5
// 3064.190 us; speedup vs baseline: 2.3432x; 2.3432x over previous
//
#include <hip/hip_runtime.h>

typedef unsigned short u16;
typedef __attribute__((ext_vector_type(8))) __bf16 bf16x8;
typedef __attribute__((ext_vector_type(4))) float f32x4;

__device__ __forceinline__ u16 f2bf(float f){
  unsigned int u = __float_as_uint(f);
  u += 0x7FFFu + ((u >> 16) & 1u);     // RNE
  return (u16)(u >> 16);
}
__device__ __forceinline__ float bf2f(u16 s){
  return __uint_as_float(((unsigned int)s) << 16);
}

// ======================= small utility kernels =======================

__global__ void zero8(int* c){ if (threadIdx.x < 8) c[threadIdx.x] = 0; }

// f32 transpose: in [R][C] -> out [C][R]
__global__ __launch_bounds__(256)
void transpose_f32(const float* __restrict__ in, float* __restrict__ outp, int R, int C)
{
  __shared__ float tile[32][33];
  const int c0 = blockIdx.x << 5, r0 = blockIdx.y << 5;
  const int tx = threadIdx.x, ty = threadIdx.y;
  #pragma unroll
  for (int i = ty; i < 32; i += 8)
    tile[i][tx] = in[(long)(r0 + i) * C + c0 + tx];
  __syncthreads();
  #pragma unroll
  for (int i = ty; i < 32; i += 8)
    outp[(long)(c0 + i) * R + r0 + tx] = tile[tx][i];
}

// transpose + convert: in [R][C] f32 -> out [C][R] bf16
__global__ __launch_bounds__(256)
void transpose_cvt(const float* __restrict__ in, u16* __restrict__ outp, int R, int C)
{
  __shared__ float tile[32][33];
  const int c0 = blockIdx.x << 5, r0 = blockIdx.y << 5;
  const int tx = threadIdx.x, ty = threadIdx.y;
  #pragma unroll
  for (int i = ty; i < 32; i += 8)
    tile[i][tx] = in[(long)(r0 + i) * C + c0 + tx];
  __syncthreads();
  #pragma unroll
  for (int i = ty; i < 32; i += 8)
    outp[(long)(c0 + i) * R + r0 + tx] = f2bf(tile[tx][i]);
}

// ======================= f32 GEMM (VALU), k-major A staging =======================
// C[M][N] = A[M][K] @ B[K][N].  64x64 tile, K-chunk 32, 256 threads, 4x4/thread.

__global__ __launch_bounds__(256)
void gemmf2(const float* __restrict__ A, const float* __restrict__ B,
            float* __restrict__ C, int M, int N, int Kd)
{
  __shared__ float As[32][68];
  __shared__ float Bs[32][68];
  const int tm = blockIdx.y, tn = blockIdx.x;
  const int t = threadIdx.x;
  const int tr = (t >> 4) << 2, tc = (t & 15) << 2;
  const int cn0 = tn << 6;

  float4 acc0 = {0,0,0,0}, acc1 = {0,0,0,0}, acc2 = {0,0,0,0}, acc3 = {0,0,0,0};

  for (int kc = 0; kc < Kd; kc += 32){
    float4 av[2], bv[2];
    #pragma unroll
    for (int u = 0; u < 2; ++u){
      int li = t + (u << 8);
      int ar = li >> 3, kq = (li & 7) << 2;
      av[u] = *(const float4*)(A + (long)(tm*64 + ar)*Kd + kc + kq);
      int kr = li >> 4, c4 = (li & 15) << 2;
      bv[u] = *(const float4*)(B + (long)(kc + kr)*N + cn0 + c4);
    }
    __syncthreads();
    #pragma unroll
    for (int u = 0; u < 2; ++u){
      int li = t + (u << 8);
      int ar = li >> 3, kq = (li & 7) << 2;
      As[kq+0][ar] = av[u].x; As[kq+1][ar] = av[u].y;
      As[kq+2][ar] = av[u].z; As[kq+3][ar] = av[u].w;
      int kr = li >> 4, c4 = (li & 15) << 2;
      *(float4*)&Bs[kr][c4] = bv[u];
    }
    __syncthreads();
    #pragma unroll
    for (int kk = 0; kk < 32; ++kk){
      float4 a4 = *(const float4*)&As[kk][tr];
      float4 b4 = *(const float4*)&Bs[kk][tc];
      acc0.x += a4.x*b4.x; acc0.y += a4.x*b4.y; acc0.z += a4.x*b4.z; acc0.w += a4.x*b4.w;
      acc1.x += a4.y*b4.x; acc1.y += a4.y*b4.y; acc1.z += a4.y*b4.z; acc1.w += a4.y*b4.w;
      acc2.x += a4.z*b4.x; acc2.y += a4.z*b4.y; acc2.z += a4.z*b4.z; acc2.w += a4.z*b4.w;
      acc3.x += a4.w*b4.x; acc3.y += a4.w*b4.y; acc3.z += a4.w*b4.z; acc3.w += a4.w*b4.w;
    }
  }
  *(float4*)(C + (long)(tm*64 + tr + 0)*N + cn0 + tc) = acc0;
  *(float4*)(C + (long)(tm*64 + tr + 1)*N + cn0 + tc) = acc1;
  *(float4*)(C + (long)(tm*64 + tr + 2)*N + cn0 + tc) = acc2;
  *(float4*)(C + (long)(tm*64 + tr + 3)*N + cn0 + tc) = acc3;
}

// Dual-B variant for K and V: A = h_all (hc rows 0..1023, h rows 1024..2047 per batch)
__global__ __launch_bounds__(256)
void gemmf2d(const float* __restrict__ hc, const float* __restrict__ h,
             const float* __restrict__ Bk, const float* __restrict__ Bv,
             float* __restrict__ Ck, float* __restrict__ Cv, int N, int Kd)
{
  __shared__ float As[32][68];
  __shared__ float Bks[32][68];
  __shared__ float Bvs[32][68];
  const int tm = blockIdx.y, tn = blockIdx.x;
  const int t = threadIdx.x;
  const int tr = (t >> 4) << 2, tc = (t & 15) << 2;
  const int cn0 = tn << 6;

  float4 k0 = {0,0,0,0}, k1 = {0,0,0,0}, k2 = {0,0,0,0}, k3 = {0,0,0,0};
  float4 v0 = {0,0,0,0}, v1 = {0,0,0,0}, v2 = {0,0,0,0}, v3 = {0,0,0,0};

  for (int kc = 0; kc < Kd; kc += 32){
    float4 av[2], bkv[2], bvv[2];
    #pragma unroll
    for (int u = 0; u < 2; ++u){
      int li = t + (u << 8);
      int ar = li >> 3, kq = (li & 7) << 2;
      int row = tm*64 + ar;
      int b = row >> 11, tt = row & 2047;
      const float* ap = (tt < 1024) ? (hc + ((long)b*1024 + tt)*1024)
                                    : (h  + ((long)b*1024 + (tt-1024))*1024);
      av[u] = *(const float4*)(ap + kc + kq);
      int kr = li >> 4, c4 = (li & 15) << 2;
      bkv[u] = *(const float4*)(Bk + (long)(kc + kr)*N + cn0 + c4);
      bvv[u] = *(const float4*)(Bv + (long)(kc + kr)*N + cn0 + c4);
    }
    __syncthreads();
    #pragma unroll
    for (int u = 0; u < 2; ++u){
      int li = t + (u << 8);
      int ar = li >> 3, kq = (li & 7) << 2;
      As[kq+0][ar] = av[u].x; As[kq+1][ar] = av[u].y;
      As[kq+2][ar] = av[u].z; As[kq+3][ar] = av[u].w;
      int kr = li >> 4, c4 = (li & 15) << 2;
      *(float4*)&Bks[kr][c4] = bkv[u];
      *(float4*)&Bvs[kr][c4] = bvv[u];
    }
    __syncthreads();
    #pragma unroll
    for (int kk = 0; kk < 32; ++kk){
      float4 a4 = *(const float4*)&As[kk][tr];
      float4 bk4 = *(const float4*)&Bks[kk][tc];
      float4 bv4 = *(const float4*)&Bvs[kk][tc];
      k0.x += a4.x*bk4.x; k0.y += a4.x*bk4.y; k0.z += a4.x*bk4.z; k0.w += a4.x*bk4.w;
      k1.x += a4.y*bk4.x; k1.y += a4.y*bk4.y; k1.z += a4.y*bk4.z; k1.w += a4.y*bk4.w;
      k2.x += a4.z*bk4.x; k2.y += a4.z*bk4.y; k2.z += a4.z*bk4.z; k2.w += a4.z*bk4.w;
      k3.x += a4.w*bk4.x; k3.y += a4.w*bk4.y; k3.z += a4.w*bk4.z; k3.w += a4.w*bk4.w;
      v0.x += a4.x*bv4.x; v0.y += a4.x*bv4.y; v0.z += a4.x*bv4.z; v0.w += a4.x*bv4.w;
      v1.x += a4.y*bv4.x; v1.y += a4.y*bv4.y; v1.z += a4.y*bv4.z; v1.w += a4.y*bv4.w;
      v2.x += a4.z*bv4.x; v2.y += a4.z*bv4.y; v2.z += a4.z*bv4.z; v2.w += a4.z*bv4.w;
      v3.x += a4.w*bv4.x; v3.y += a4.w*bv4.y; v3.z += a4.w*bv4.z; v3.w += a4.w*bv4.w;
    }
  }
  const long r0 = (long)(tm*64 + tr);
  *(float4*)(Ck + (r0+0)*N + cn0 + tc) = k0;
  *(float4*)(Ck + (r0+1)*N + cn0 + tc) = k1;
  *(float4*)(Ck + (r0+2)*N + cn0 + tc) = k2;
  *(float4*)(Ck + (r0+3)*N + cn0 + tc) = k3;
  *(float4*)(Cv + (r0+0)*N + cn0 + tc) = v0;
  *(float4*)(Cv + (r0+1)*N + cn0 + tc) = v1;
  *(float4*)(Cv + (r0+2)*N + cn0 + tc) = v2;
  *(float4*)(Cv + (r0+3)*N + cn0 + tc) = v3;
}

// ======================= MFMA bf16 GEMM for MoE (Bt[N][K] layout) =======================
// STAGING FIX (R4 post-mortem): each thread stages 16 u16 (two uint4), covering the
// full 128x32 K-chunk. Previous version staged only [0..8)+[16..24) per row -> lanes
// with fq in {1,3} read uninitialized LDS -> NaN (the R0/R1/R2/R4 failure).

#define LDP 40

template<bool GATHER, bool RELU>
__global__ __launch_bounds__(256, 2)
void gemm_bt(const u16* __restrict__ A, const u16* __restrict__ Bt, u16* __restrict__ Cp,
             const float* __restrict__ bias, int N, int Kd, int maxA,
             const int* __restrict__ rbase_p, const int* __restrict__ cnt_p,
             const int* __restrict__ gather)
{
  __shared__ __align__(16) u16 As[128*LDP];
  __shared__ __align__(16) u16 Bs[128*LDP];
  const int rbase = rbase_p[0];
  const int cnt   = cnt_p[0];
  const int tm = blockIdx.y, tn = blockIdx.x;
  if (tm * 128 >= cnt) return;

  const int t = threadIdx.x;
  const int lane = t & 63, wid = t >> 6;
  const int wm = wid >> 1, wn = wid & 1;
  const int srow = t >> 1;
  const int scol = (t & 1) << 4;

  long arow;
  {
    int r = tm*128 + srow;
    int rc = (r < cnt) ? r : (cnt - 1);
    if (GATHER){
      int gi = rbase + rc; gi = (gi < 0) ? 0 : ((gi > 8191) ? 8191 : gi);
      int tok = gather[gi];
      tok = (tok < 0) ? 0 : ((tok >= maxA) ? (maxA - 1) : tok);
      arow = (long)tok;
    } else {
      arow = (long)rc;
    }
  }
  const long brow = (long)(tn*128 + srow);

  f32x4 acc[4][4];
  const f32x4 z4 = {0.f,0.f,0.f,0.f};
  #pragma unroll
  for (int m=0;m<4;m++)
    #pragma unroll
    for (int n=0;n<4;n++) acc[m][n] = z4;

  const u16* aptr = A + arow * Kd + scol;
  const u16* bptr = Bt + brow * Kd + scol;
  u16* as_w = As + srow*LDP + scol;
  u16* bs_w = Bs + srow*LDP + scol;
  const int fr = lane & 15, fq = lane >> 4;

  const int nk = Kd >> 5;
  for (int kt = 0; kt < nk; ++kt) {
    uint4 av0 = *(const uint4*)(aptr + (kt<<5));
    uint4 av1 = *(const uint4*)(aptr + (kt<<5) + 8);
    uint4 bv0 = *(const uint4*)(bptr + (kt<<5));
    uint4 bv1 = *(const uint4*)(bptr + (kt<<5) + 8);
    __syncthreads();
    *(uint4*)as_w       = av0;
    *(uint4*)(as_w + 8) = av1;
    *(uint4*)bs_w       = bv0;
    *(uint4*)(bs_w + 8) = bv1;
    __syncthreads();
    bf16x8 af[4], bfv[4];
    #pragma unroll
    for (int m=0;m<4;m++) af[m]  = *(const bf16x8*)(As + (wm*64 + m*16 + fr)*LDP + fq*8);
    #pragma unroll
    for (int n=0;n<4;n++) bfv[n] = *(const bf16x8*)(Bs + (wn*64 + n*16 + fr)*LDP + fq*8);
    #pragma unroll
    for (int m=0;m<4;m++)
      #pragma unroll
      for (int n=0;n<4;n++)
        acc[m][n] = __builtin_amdgcn_mfma_f32_16x16x32_bf16(af[m], bfv[n], acc[m][n], 0, 0, 0);
  }

  // C/D layout: col = lane&15, row = (lane>>4)*4 + reg
  #pragma unroll
  for (int m=0;m<4;m++){
    #pragma unroll
    for (int j=0;j<4;j++){
      const int r = tm*128 + wm*64 + m*16 + fq*4 + j;
      if (r >= cnt) continue;
      const long crow = GATHER ? (long)r : (long)(rbase + r);
      #pragma unroll
      for (int n=0;n<4;n++){
        const int c = tn*128 + wn*64 + n*16 + fr;
        float vv = acc[m][n][j] + bias[c];
        if (RELU) vv = fmaxf(vv, 0.f);
        Cp[crow * N + c] = f2bf(vv);
      }
    }
  }
}

// ======================= f32 sliding-window attention, 16q/block =======================
// score[i][j] = q_i . (k_{i+j} + pe_j) / 8, j in [0,1024); out_i = sum_j p[i][j] v_{i+j}

__global__ __launch_bounds__(512)
void attn16(const float* __restrict__ q, const float* __restrict__ k,
            const float* __restrict__ v, const float* __restrict__ pe,
            float* __restrict__ outp)
{
  __shared__ float s[16][1024];    // 64 KB
  __shared__ float kvs[80][68];    // 21.25 KB
  __shared__ float pes[64][68];    // 17 KB   (104 KB total; gfx950 allows 160 KB/WG)
  const int qb0 = blockIdx.x << 4;
  const int hd = blockIdx.y, b = blockIdx.z;
  const int t = threadIdx.x;
  const int qq = t >> 5;
  const long kbase = ((long)b*2048)*1024 + hd*64;

  // hoist this thread's q row into registers
  float4 qreg[16];
  {
    const float4* qp = (const float4*)(q + ((long)(b*1024 + qb0 + qq))*1024 + hd*64);
    #pragma unroll
    for (int i = 0; i < 16; ++i) qreg[i] = qp[i];
  }

  // ---- phase A: scores (j-chunked; k rows and pe rows staged in LDS) ----
  const int jl = t & 31;
  for (int jc = 0; jc < 16; ++jc){
    const int j0 = jc << 6;
    __syncthreads();
    for (int i = t; i < 1280; i += 512){          // 80 k-rows x 16 float4
      int rr = i >> 4, c4 = (i & 15) << 2;
      *(float4*)&kvs[rr][c4] = *(const float4*)(k + kbase + (long)(qb0 + j0 + rr)*1024 + c4);
    }
    for (int i = t; i < 1024; i += 512){          // 64 pe-rows x 16 float4
      int rr = i >> 4, c4 = (i & 15) << 2;
      *(float4*)&pes[rr][c4] = *(const float4*)(pe + (long)(j0 + rr)*64 + c4);
    }
    __syncthreads();
    #pragma unroll
    for (int ss = 0; ss < 2; ++ss){
      const int jloc = jl + (ss << 5);
      const float4* kp = (const float4*)&kvs[qq + jloc][0];
      const float4* pp = (const float4*)&pes[jloc][0];
      float a0 = 0.f, a1 = 0.f, a2 = 0.f, a3 = 0.f;
      #pragma unroll
      for (int d4 = 0; d4 < 16; ++d4){
        float4 kk = kp[d4];
        float4 pe4 = pp[d4];
        float4 qv = qreg[d4];
        a0 += qv.x * (kk.x + pe4.x);
        a1 += qv.y * (kk.y + pe4.y);
        a2 += qv.z * (kk.z + pe4.z);
        a3 += qv.w * (kk.w + pe4.w);
      }
      s[qq][j0 + jloc] = (a0 + a1 + a2 + a3) * 0.125f;
    }
  }
  __syncthreads();

  // ---- phase B: softmax (32 lanes per row; xor offsets <32 stay within halves) ----
  {
    const int j0 = t & 31;
    float mx = -3.0e38f;
    for (int j = j0; j < 1024; j += 32) mx = fmaxf(mx, s[qq][j]);
    #pragma unroll
    for (int o = 16; o; o >>= 1) mx = fmaxf(mx, __shfl_xor(mx, o, 64));
    float sum = 0.f;
    for (int j = j0; j < 1024; j += 32){
      float ee = __expf(s[qq][j] - mx);
      s[qq][j] = ee; sum += ee;
    }
    #pragma unroll
    for (int o = 16; o; o >>= 1) sum += __shfl_xor(sum, o, 64);
    float inv = 1.f / sum;
    for (int j = j0; j < 1024; j += 32) s[qq][j] *= inv;
  }

  // ---- phase C: PV (v rows staged per j-chunk; 4 d per thread) ----
  const int hq = (t >> 4) & 1;
  const int d0 = (t & 15) << 2;
  float4 oaccA = {0,0,0,0}, oaccB = {0,0,0,0};
  for (int jc = 0; jc < 16; ++jc){
    const int j0 = jc << 6;
    __syncthreads();
    for (int i = t; i < 1280; i += 512){
      int rr = i >> 4, c4 = (i & 15) << 2;
      *(float4*)&kvs[rr][c4] = *(const float4*)(v + kbase + (long)(qb0 + j0 + rr)*1024 + c4);
    }
    __syncthreads();
    #pragma unroll
    for (int jj = 0; jj < 8; ++jj){
      const int j4 = (hq << 5) + (jj << 2);
      float4 p4 = *(const float4*)&s[qq][j0 + j4];
      float4 w0 = *(const float4*)&kvs[qq + j4 + 0][d0];
      float4 w1 = *(const float4*)&kvs[qq + j4 + 1][d0];
      float4 w2 = *(const float4*)&kvs[qq + j4 + 2][d0];
      float4 w3 = *(const float4*)&kvs[qq + j4 + 3][d0];
      float4& oa = (jj & 1) ? oaccB : oaccA;
      oa.x += p4.x*w0.x; oa.y += p4.x*w0.y; oa.z += p4.x*w0.z; oa.w += p4.x*w0.w;
      oa.x += p4.y*w1.x; oa.y += p4.y*w1.y; oa.z += p4.y*w1.z; oa.w += p4.y*w1.w;
      oa.x += p4.z*w2.x; oa.y += p4.z*w2.y; oa.z += p4.z*w2.z; oa.w += p4.z*w2.w;
      oa.x += p4.w*w3.x; oa.y += p4.w*w3.y; oa.z += p4.w*w3.z; oa.w += p4.w*w3.w;
    }
  }
  float4 oc;
  oc.x = oaccA.x + oaccB.x; oc.y = oaccA.y + oaccB.y;
  oc.z = oaccA.z + oaccB.z; oc.w = oaccA.w + oaccB.w;
  oc.x += __shfl_xor(oc.x, 16, 64);
  oc.y += __shfl_xor(oc.y, 16, 64);
  oc.z += __shfl_xor(oc.z, 16, 64);
  oc.w += __shfl_xor(oc.w, 16, 64);
  if (hq == 0)
    *(float4*)(outp + ((long)(b*1024 + qb0 + qq))*1024 + hd*64 + d0) = oc;
}

// ======================= layernorm / gate / moe plumbing =======================

__device__ __forceinline__ void block_reduce2(float& s1, float& s2){
  #pragma unroll
  for (int o = 32; o; o >>= 1){
    s1 += __shfl_xor(s1, o, 64);
    s2 += __shfl_xor(s2, o, 64);
  }
  __shared__ float r1[4], r2[4];
  const int wid = threadIdx.x >> 6;
  if ((threadIdx.x & 63) == 0){ r1[wid] = s1; r2[wid] = s2; }
  __syncthreads();
  s1 = r1[0] + r1[1] + r1[2] + r1[3];
  s2 = r2[0] + r2[1] + r2[2] + r2[3];
  __syncthreads();
}

__global__ __launch_bounds__(256)
void add_ln_kernel(const float* __restrict__ a, const float* __restrict__ r,
                   const float* __restrict__ g, const float* __restrict__ bb,
                   float* __restrict__ of, u16* __restrict__ ob)
{
  const long row = blockIdx.x;
  const int t = threadIdx.x;
  float y[4]; float sum = 0.f, sq = 0.f;
  #pragma unroll
  for (int i = 0; i < 4; ++i){
    const long idx = row*1024 + t + (i<<8);
    float vv = a[idx] + r[idx];
    y[i] = vv; sum += vv; sq += vv*vv;
  }
  block_reduce2(sum, sq);
  const float mu = sum * (1.f/1024.f);
  const float var = fmaxf(sq * (1.f/1024.f) - mu*mu, 0.f);
  const float rs = rsqrtf(var + 1e-5f);
  #pragma unroll
  for (int i = 0; i < 4; ++i){
    const int hcol = t + (i<<8);
    float o = (y[i] - mu) * rs * g[hcol] + bb[hcol];
    of[row*1024 + hcol] = o;
    ob[row*1024 + hcol] = f2bf(o);
  }
}

__global__ __launch_bounds__(256)
void gate_kernel(const float* __restrict__ x, const float* __restrict__ gw,
                 const float* __restrict__ gb, int* __restrict__ eidx,
                 float* __restrict__ esc, int* __restrict__ counts)
{
  const long row = blockIdx.x;
  const int t = threadIdx.x;
  float a[8];
  #pragma unroll
  for (int e=0;e<8;e++) a[e]=0.f;
  for (int hcol = t; hcol < 1024; hcol += 256){
    float xv = x[row*1024 + hcol];
    const float* gr = gw + hcol*8;
    #pragma unroll
    for (int e=0;e<8;e++) a[e] += xv * gr[e];
  }
  #pragma unroll
  for (int e=0;e<8;e++)
    #pragma unroll
    for (int o=32;o;o>>=1) a[e] += __shfl_xor(a[e], o, 64);
  __shared__ float red[4][8];
  const int wid = t >> 6;
  if ((t & 63)==0){
    #pragma unroll
    for (int e=0;e<8;e++) red[wid][e]=a[e];
  }
  __syncthreads();
  if (t == 0){
    float l[8];
    #pragma unroll
    for (int e=0;e<8;e++) l[e] = red[0][e]+red[1][e]+red[2][e]+red[3][e] + gb[e];
    int i0 = 0; float v0 = l[0];
    #pragma unroll
    for (int e=1;e<8;e++) if (l[e] > v0){ v0=l[e]; i0=e; }
    int i1 = -1; float v1 = -3.0e38f;
    #pragma unroll
    for (int e=0;e<8;e++) if (e != i0 && l[e] > v1){ v1=l[e]; i1=e; }
    float e1 = __expf(v1 - v0);
    float den = 1.f + e1;
    eidx[row*2+0]=i0; eidx[row*2+1]=i1;
    esc[row*2+0]=1.f/den; esc[row*2+1]=e1/den;
    atomicAdd(&counts[i0],1); atomicAdd(&counts[i1],1);
  }
}

__global__ void scan_kernel(const int* __restrict__ counts, int* __restrict__ offs,
                            int* __restrict__ curs)
{
  if (threadIdx.x == 0 && blockIdx.x == 0){
    int acc = 0;
    for (int e=0;e<8;e++){ offs[e]=acc; curs[e]=acc; acc += counts[e]; }
  }
}

__global__ __launch_bounds__(256)
void scatter_kernel(const int* __restrict__ eidx, int* __restrict__ curs,
                    int* __restrict__ stok, int* __restrict__ ppos)
{
  int id = blockIdx.x*256 + threadIdx.x;
  if (id >= 8192) return;
  int e = eidx[id];
  e = (e < 0) ? 0 : ((e > 7) ? 7 : e);
  int pos = atomicAdd(&curs[e], 1);
  pos = (pos < 0) ? 0 : ((pos > 8191) ? 8191 : pos);
  stok[pos] = id >> 1;
  ppos[id] = pos;
}

__global__ __launch_bounds__(256)
void moe_combine_ln(const float* __restrict__ h1, const u16* __restrict__ pout,
                    const float* __restrict__ esc, const int* __restrict__ ppos,
                    const float* __restrict__ mg, const float* __restrict__ mb,
                    const float* __restrict__ n2g, const float* __restrict__ n2b,
                    float* __restrict__ outp)
{
  const long row = blockIdx.x;
  const int t = threadIdx.x;
  int p0i = ppos[row*2+0], p1i = ppos[row*2+1];
  p0i = (p0i < 0) ? 0 : ((p0i > 8191) ? 8191 : p0i);
  p1i = (p1i < 0) ? 0 : ((p1i > 8191) ? 8191 : p1i);
  const long p0 = p0i, p1 = p1i;
  const float s0 = esc[row*2+0], s1 = esc[row*2+1];
  float x[4], y[4];
  float sum=0.f, sq=0.f;
  #pragma unroll
  for (int i=0;i<4;i++){
    const int hcol = t + (i<<8);
    const long idx = row*1024 + hcol;
    float xv = h1[idx];
    float m = s0 * bf2f(pout[p0*1024 + hcol]) + s1 * bf2f(pout[p1*1024 + hcol]);
    x[i]=xv; y[i]=xv+m; sum+=y[i]; sq+=y[i]*y[i];
  }
  block_reduce2(sum, sq);
  float mu = sum*(1.f/1024.f), var = fmaxf(sq*(1.f/1024.f)-mu*mu, 0.f), rs = rsqrtf(var+1e-5f);
  float zz[4]; float sum2=0.f, sq2=0.f;
  #pragma unroll
  for (int i=0;i<4;i++){
    const int hcol = t + (i<<8);
    float core = (y[i]-mu)*rs*mg[hcol]+mb[hcol];
    zz[i] = x[i] + core; sum2+=zz[i]; sq2+=zz[i]*zz[i];
  }
  block_reduce2(sum2, sq2);
  float mu2 = sum2*(1.f/1024.f), var2 = fmaxf(sq2*(1.f/1024.f)-mu2*mu2, 0.f), rs2 = rsqrtf(var2+1e-5f);
  #pragma unroll
  for (int i=0;i<4;i++){
    const int hcol = t + (i<<8);
    outp[row*1024 + hcol] = (zz[i]-mu2)*rs2*n2g[hcol]+n2b[hcol];
  }
}

// ======================= launcher =======================
// Workspace (peak 146 MB; metadata at offset 0):
//   0..1MB    : counts/offs/curs/eidx/esc/stok/ppos
//   1..2MB    : peT f32 [1024][64]
//   2..18MB   : q f32 (dead after attn) -> h1b bf16 2..10, w1Te bf16 10..18
//   18..50MB  : kbuf f32 (dead after attn) -> aproj 18..34 (dead after add_ln -> w2Te 18..26), h1 34..50
//   50..82MB  : vbuf f32 (dead after attn) -> pout bf16 50..66
//   82..98MB  : aout f32 (dead after WO) -> xhid bf16 82..146

extern "C" void kernel_launch(void* const* d_in, const int* in_sizes, int n_in,
                              void* d_out, int out_size, void* d_ws, size_t ws_size,
                              hipStream_t stream)
{
  const float* h      = (const float*)d_in[0];
  const float* hc     = (const float*)d_in[1];
  const float* key_pe = (const float*)d_in[2];
  const float* wq     = (const float*)d_in[3];
  const float* wk     = (const float*)d_in[4];
  const float* wv     = (const float*)d_in[5];
  const float* wo     = (const float*)d_in[6];
  const float* n1g    = (const float*)d_in[7];
  const float* n1b    = (const float*)d_in[8];
  const float* n2g    = (const float*)d_in[9];
  const float* n2b    = (const float*)d_in[10];
  const float* mlg    = (const float*)d_in[11];
  const float* mlb    = (const float*)d_in[12];
  const float* gw     = (const float*)d_in[13];
  const float* gb     = (const float*)d_in[14];
  const float* ew1    = (const float*)d_in[15];
  const float* eb1    = (const float*)d_in[16];
  const float* ew2    = (const float*)d_in[17];
  const float* eb2    = (const float*)d_in[18];
  float* outp = (float*)d_out;

  const size_t MB = 1ull << 20;
  char* base = (char*)d_ws;
  int*   counts= (int*)(base);
  int*   offs  = (int*)(base + 256);
  int*   curs  = (int*)(base + 512);
  int*   eidx  = (int*)(base + 1024);
  float* esc   = (float*)(base + 64*1024);
  int*   stok  = (int*)(base + 128*1024);
  int*   ppos  = (int*)(base + 192*1024);
  float* peT   = (float*)(base + 1*MB);
  float* q     = (float*)(base + 2*MB);
  u16*   h1b   = (u16*)(base + 2*MB);      // alias (after attn)
  u16*   w1Te  = (u16*)(base + 10*MB);     // alias (after attn)
  float* kbuf  = (float*)(base + 18*MB);
  float* aproj = (float*)(base + 18*MB);   // alias (after attn)
  u16*   w2Te  = (u16*)(base + 18*MB);     // alias (after add_ln)
  float* h1    = (float*)(base + 34*MB);   // alias (after attn)
  float* vbuf  = (float*)(base + 50*MB);
  u16*   pout  = (u16*)(base + 50*MB);     // alias (after attn)
  float* aout  = (float*)(base + 82*MB);
  u16*   xhid  = (u16*)(base + 82*MB);     // alias (after WO)

  zero8<<<1, 64, 0, stream>>>(counts);
  transpose_f32<<<dim3(32,2,1), dim3(32,8), 0, stream>>>(key_pe, peT, 64, 1024);

  // QKV projections (f32)
  gemmf2<<<dim3(16,64), 256, 0, stream>>>(h, wq, q, 4096, 1024, 1024);
  gemmf2d<<<dim3(16,128), 256, 0, stream>>>(hc, h, wk, wv, kbuf, vbuf, 1024, 1024);

  // attention (f32)
  attn16<<<dim3(64,16,4), 512, 0, stream>>>(q, kbuf, vbuf, peT, aout);

  // output projection + residual LN (aproj/h1 overlay dead kbuf)
  gemmf2<<<dim3(16,64), 256, 0, stream>>>(aout, wo, aproj, 4096, 1024, 1024);
  add_ln_kernel<<<4096, 256, 0, stream>>>(h, aproj, n1g, n1b, h1, h1b);

  // MoE gate + bucketing (f32 — exact top-2 vs reference)
  gate_kernel<<<4096, 256, 0, stream>>>(h1, gw, gb, eidx, esc, counts);
  scan_kernel<<<1, 64, 0, stream>>>(counts, offs, curs);
  scatter_kernel<<<32, 256, 0, stream>>>(eidx, curs, stok, ppos);

  // per-expert FFN: bf16 MFMA (downstream of gate; threshold-safe)
  for (int e = 0; e < 8; ++e){
    transpose_cvt<<<dim3(128,32), dim3(32,8), 0, stream>>>(ew1 + (long)e*1024*4096, w1Te, 1024, 4096);
    transpose_cvt<<<dim3(32,128), dim3(32,8), 0, stream>>>(ew2 + (long)e*4096*1024, w2Te, 4096, 1024);
    gemm_bt<true,  true ><<<dim3(32,64), 256, 0, stream>>>(h1b,  w1Te, xhid, eb1 + (long)e*4096,
                                                           4096, 1024, 4096, offs + e, counts + e, stok);
    gemm_bt<false, false><<<dim3(8,64),  256, 0, stream>>>(xhid, w2Te, pout, eb2 + (long)e*1024,
                                                           1024, 4096, 8192, offs + e, counts + e, nullptr);
  }

  // combine + the two trailing layernorms
  moe_combine_ln<<<4096, 256, 0, stream>>>(h1, pout, esc, ppos, mlg, mlb, n2g, n2b, outp);
}

// Round 6
// 2442.773 us; speedup vs baseline: 2.9393x; 1.2544x over previous
//
#include <hip/hip_runtime.h>

typedef unsigned short u16;
typedef __attribute__((ext_vector_type(8))) __bf16 bf16x8;
typedef __attribute__((ext_vector_type(8))) _Float16 f16x8;
typedef __attribute__((ext_vector_type(4))) float f32x4;

__device__ __forceinline__ u16 f2bf(float f){
  unsigned int u = __float_as_uint(f);
  u += 0x7FFFu + ((u >> 16) & 1u);     // RNE
  return (u16)(u >> 16);
}
__device__ __forceinline__ float bf2f(u16 s){
  return __uint_as_float(((unsigned int)s) << 16);
}
// split-f16: x = hi + lo with |x - hi - lo| <= 2^-24 |x|  (f32-emulation via 3 f16 MFMAs)
__device__ __forceinline__ void fsplit(float x, u16& hi, u16& lo){
  _Float16 h = (_Float16)x;
  float r = x - (float)h;
  _Float16 l = (_Float16)r;
  hi = *(u16*)&h; lo = *(u16*)&l;
}

// ======================= small utility kernels =======================

__global__ void zero8(int* c){ if (threadIdx.x < 8) c[threadIdx.x] = 0; }

// f32 transpose: in [R][C] -> out [C][R]
__global__ __launch_bounds__(256)
void transpose_f32(const float* __restrict__ in, float* __restrict__ outp, int R, int C)
{
  __shared__ float tile[32][33];
  const int c0 = blockIdx.x << 5, r0 = blockIdx.y << 5;
  const int tx = threadIdx.x, ty = threadIdx.y;
  #pragma unroll
  for (int i = ty; i < 32; i += 8)
    tile[i][tx] = in[(long)(r0 + i) * C + c0 + tx];
  __syncthreads();
  #pragma unroll
  for (int i = ty; i < 32; i += 8)
    outp[(long)(c0 + i) * R + r0 + tx] = tile[tx][i];
}

// transpose + convert: in [R][C] f32 -> out [C][R] bf16
__global__ __launch_bounds__(256)
void transpose_cvt(const float* __restrict__ in, u16* __restrict__ outp, int R, int C)
{
  __shared__ float tile[32][33];
  const int c0 = blockIdx.x << 5, r0 = blockIdx.y << 5;
  const int tx = threadIdx.x, ty = threadIdx.y;
  #pragma unroll
  for (int i = ty; i < 32; i += 8)
    tile[i][tx] = in[(long)(r0 + i) * C + c0 + tx];
  __syncthreads();
  #pragma unroll
  for (int i = ty; i < 32; i += 8)
    outp[(long)(c0 + i) * R + r0 + tx] = f2bf(tile[tx][i]);
}

// transpose + split-f16: in [R][C] f32 -> outh/outl [C][R] f16
__global__ __launch_bounds__(256)
void transpose_split(const float* __restrict__ in, u16* __restrict__ oh, u16* __restrict__ ol,
                     int R, int C)
{
  __shared__ float tile[32][33];
  const int c0 = blockIdx.x << 5, r0 = blockIdx.y << 5;
  const int tx = threadIdx.x, ty = threadIdx.y;
  #pragma unroll
  for (int i = ty; i < 32; i += 8)
    tile[i][tx] = in[(long)(r0 + i) * C + c0 + tx];
  __syncthreads();
  #pragma unroll
  for (int i = ty; i < 32; i += 8){
    u16 hh, ll;
    fsplit(tile[tx][i], hh, ll);
    oh[(long)(c0 + i) * R + r0 + tx] = hh;
    ol[(long)(c0 + i) * R + r0 + tx] = ll;
  }
}

// h_all = concat(hc, h) per batch -> split-f16 pair [8192][1024]
__global__ __launch_bounds__(256)
void cvt_split_hall(const float* __restrict__ hc, const float* __restrict__ h,
                    u16* __restrict__ hi, u16* __restrict__ lo)
{
  long i4 = (long)blockIdx.x * 256 + threadIdx.x;   // grid exact: 8192 blocks = 2M float4
  long row = i4 >> 8;
  int c4 = (int)(i4 & 255);
  int b = (int)(row >> 11), tt = (int)(row & 2047);
  const float4* src = (const float4*)((tt < 1024) ? (hc + ((long)b*1024 + tt)*1024)
                                                  : (h  + ((long)b*1024 + (tt-1024))*1024));
  float4 v = src[c4];
  ushort4 h4, l4;
  fsplit(v.x, h4.x, l4.x); fsplit(v.y, h4.y, l4.y);
  fsplit(v.z, h4.z, l4.z); fsplit(v.w, h4.w, l4.w);
  ((ushort4*)hi)[i4] = h4;
  ((ushort4*)lo)[i4] = l4;
}

// ======================= split-f16 emulated-f32 MFMA GEMM =======================
// C[M][N] f32 = A @ B with A given as (Ah+Al) f16 pair [M][K] and B as (Bh+Bl)
// f16 pair transposed [N][K]. 3 MFMAs per tile: Ah*Bh + Ah*Bl + Al*Bh (error ~2^-24).
// AMAP 1: A row r -> h_all row (r>>10)*2048 + 1024 + (r&1023)   (Q projection)

#define LDP 40

template<int AMAP>
__global__ __launch_bounds__(256)
void gemm_sp(const u16* __restrict__ Ah_, const u16* __restrict__ Al_,
             const u16* __restrict__ Bh_, const u16* __restrict__ Bl_,
             float* __restrict__ C, int N, int Kd)
{
  __shared__ __align__(16) u16 Ahs[128*LDP];
  __shared__ __align__(16) u16 Als[128*LDP];
  __shared__ __align__(16) u16 Bhs[128*LDP];
  __shared__ __align__(16) u16 Bls[128*LDP];
  const int tm = blockIdx.y, tn = blockIdx.x;
  const int t = threadIdx.x;
  const int lane = t & 63, wid = t >> 6;
  const int wm = wid >> 1, wn = wid & 1;
  const int srow = t >> 1;
  const int scol = (t & 1) << 4;

  long arow;
  {
    int r = tm*128 + srow;
    if (AMAP == 1){ int b = r >> 10, tt = r & 1023; arow = (long)b*2048 + 1024 + tt; }
    else arow = (long)r;
  }
  const long brow = (long)(tn*128 + srow);

  f32x4 acc[4][4];
  const f32x4 z4 = {0.f,0.f,0.f,0.f};
  #pragma unroll
  for (int m=0;m<4;m++)
    #pragma unroll
    for (int n=0;n<4;n++) acc[m][n] = z4;

  const u16* pah = Ah_ + arow * Kd + scol;
  const u16* pal = Al_ + arow * Kd + scol;
  const u16* pbh = Bh_ + brow * Kd + scol;
  const u16* pbl = Bl_ + brow * Kd + scol;
  u16* wah = Ahs + srow*LDP + scol;
  u16* wal = Als + srow*LDP + scol;
  u16* wbh = Bhs + srow*LDP + scol;
  u16* wbl = Bls + srow*LDP + scol;
  const int fr = lane & 15, fq = lane >> 4;

  const int nk = Kd >> 5;
  for (int kt = 0; kt < nk; ++kt) {
    const int ko = kt << 5;
    uint4 ah0 = *(const uint4*)(pah + ko), ah1 = *(const uint4*)(pah + ko + 8);
    uint4 al0 = *(const uint4*)(pal + ko), al1 = *(const uint4*)(pal + ko + 8);
    uint4 bh0 = *(const uint4*)(pbh + ko), bh1 = *(const uint4*)(pbh + ko + 8);
    uint4 bl0 = *(const uint4*)(pbl + ko), bl1 = *(const uint4*)(pbl + ko + 8);
    __syncthreads();
    *(uint4*)wah = ah0; *(uint4*)(wah + 8) = ah1;
    *(uint4*)wal = al0; *(uint4*)(wal + 8) = al1;
    *(uint4*)wbh = bh0; *(uint4*)(wbh + 8) = bh1;
    *(uint4*)wbl = bl0; *(uint4*)(wbl + 8) = bl1;
    __syncthreads();
    f16x8 afh[4], afl[4], bfh[4], bfl[4];
    #pragma unroll
    for (int m=0;m<4;m++){
      afh[m] = *(const f16x8*)(Ahs + (wm*64 + m*16 + fr)*LDP + fq*8);
      afl[m] = *(const f16x8*)(Als + (wm*64 + m*16 + fr)*LDP + fq*8);
    }
    #pragma unroll
    for (int n=0;n<4;n++){
      bfh[n] = *(const f16x8*)(Bhs + (wn*64 + n*16 + fr)*LDP + fq*8);
      bfl[n] = *(const f16x8*)(Bls + (wn*64 + n*16 + fr)*LDP + fq*8);
    }
    #pragma unroll
    for (int m=0;m<4;m++)
      #pragma unroll
      for (int n=0;n<4;n++){
        acc[m][n] = __builtin_amdgcn_mfma_f32_16x16x32_f16(afl[m], bfh[n], acc[m][n], 0, 0, 0);
        acc[m][n] = __builtin_amdgcn_mfma_f32_16x16x32_f16(afh[m], bfl[n], acc[m][n], 0, 0, 0);
        acc[m][n] = __builtin_amdgcn_mfma_f32_16x16x32_f16(afh[m], bfh[n], acc[m][n], 0, 0, 0);
      }
  }

  // C/D layout: col = lane&15, row = (lane>>4)*4 + reg   [m89-verified]
  #pragma unroll
  for (int m=0;m<4;m++){
    #pragma unroll
    for (int j=0;j<4;j++){
      const long crow = (long)(tm*128 + wm*64 + m*16 + fq*4 + j);
      #pragma unroll
      for (int n=0;n<4;n++){
        const int c = tn*128 + wn*64 + n*16 + fr;
        C[crow * N + c] = acc[m][n][j];
      }
    }
  }
}

// ======================= MFMA bf16 GEMM for MoE (Bt[N][K] layout) =======================

template<bool GATHER, bool RELU>
__global__ __launch_bounds__(256, 2)
void gemm_bt(const u16* __restrict__ A, const u16* __restrict__ Bt, u16* __restrict__ Cp,
             const float* __restrict__ bias, int N, int Kd, int maxA,
             const int* __restrict__ rbase_p, const int* __restrict__ cnt_p,
             const int* __restrict__ gather)
{
  __shared__ __align__(16) u16 As[128*LDP];
  __shared__ __align__(16) u16 Bs[128*LDP];
  const int rbase = rbase_p[0];
  const int cnt   = cnt_p[0];
  const int tm = blockIdx.y, tn = blockIdx.x;
  if (tm * 128 >= cnt) return;

  const int t = threadIdx.x;
  const int lane = t & 63, wid = t >> 6;
  const int wm = wid >> 1, wn = wid & 1;
  const int srow = t >> 1;
  const int scol = (t & 1) << 4;

  long arow;
  {
    int r = tm*128 + srow;
    int rc = (r < cnt) ? r : (cnt - 1);
    if (GATHER){
      int gi = rbase + rc; gi = (gi < 0) ? 0 : ((gi > 8191) ? 8191 : gi);
      int tok = gather[gi];
      tok = (tok < 0) ? 0 : ((tok >= maxA) ? (maxA - 1) : tok);
      arow = (long)tok;
    } else {
      arow = (long)rc;
    }
  }
  const long brow = (long)(tn*128 + srow);

  f32x4 acc[4][4];
  const f32x4 z4 = {0.f,0.f,0.f,0.f};
  #pragma unroll
  for (int m=0;m<4;m++)
    #pragma unroll
    for (int n=0;n<4;n++) acc[m][n] = z4;

  const u16* aptr = A + arow * Kd + scol;
  const u16* bptr = Bt + brow * Kd + scol;
  u16* as_w = As + srow*LDP + scol;
  u16* bs_w = Bs + srow*LDP + scol;
  const int fr = lane & 15, fq = lane >> 4;

  const int nk = Kd >> 5;
  for (int kt = 0; kt < nk; ++kt) {
    uint4 av0 = *(const uint4*)(aptr + (kt<<5));
    uint4 av1 = *(const uint4*)(aptr + (kt<<5) + 8);
    uint4 bv0 = *(const uint4*)(bptr + (kt<<5));
    uint4 bv1 = *(const uint4*)(bptr + (kt<<5) + 8);
    __syncthreads();
    *(uint4*)as_w       = av0;
    *(uint4*)(as_w + 8) = av1;
    *(uint4*)bs_w       = bv0;
    *(uint4*)(bs_w + 8) = bv1;
    __syncthreads();
    bf16x8 af[4], bfv[4];
    #pragma unroll
    for (int m=0;m<4;m++) af[m]  = *(const bf16x8*)(As + (wm*64 + m*16 + fr)*LDP + fq*8);
    #pragma unroll
    for (int n=0;n<4;n++) bfv[n] = *(const bf16x8*)(Bs + (wn*64 + n*16 + fr)*LDP + fq*8);
    #pragma unroll
    for (int m=0;m<4;m++)
      #pragma unroll
      for (int n=0;n<4;n++)
        acc[m][n] = __builtin_amdgcn_mfma_f32_16x16x32_bf16(af[m], bfv[n], acc[m][n], 0, 0, 0);
  }

  #pragma unroll
  for (int m=0;m<4;m++){
    #pragma unroll
    for (int j=0;j<4;j++){
      const int r = tm*128 + wm*64 + m*16 + fq*4 + j;
      if (r >= cnt) continue;
      const long crow = GATHER ? (long)r : (long)(rbase + r);
      #pragma unroll
      for (int n=0;n<4;n++){
        const int c = tn*128 + wn*64 + n*16 + fr;
        float vv = acc[m][n][j] + bias[c];
        if (RELU) vv = fmaxf(vv, 0.f);
        Cp[crow * N + c] = f2bf(vv);
      }
    }
  }
}

// ======================= f32 sliding-window attention, 16q/block =======================
// score[i][j] = q_i . (k_{i+j} + pe_j) / 8, j in [0,1024); out_i = sum_j p[i][j] v_{i+j}
// output written as split-f16 pair (feeds the WO split GEMM).

__global__ __launch_bounds__(512)
void attn16(const float* __restrict__ q, const float* __restrict__ k,
            const float* __restrict__ v, const float* __restrict__ pe,
            u16* __restrict__ out_hi, u16* __restrict__ out_lo)
{
  __shared__ float s[16][1024];    // 64 KB
  __shared__ float kvs[80][68];    // 21.25 KB
  __shared__ float pes[64][68];    // 17 KB
  const int qb0 = blockIdx.x << 4;
  const int hd = blockIdx.y, b = blockIdx.z;
  const int t = threadIdx.x;
  const int qq = t >> 5;
  const long kbase = ((long)b*2048)*1024 + hd*64;

  float4 qreg[16];
  {
    const float4* qp = (const float4*)(q + ((long)(b*1024 + qb0 + qq))*1024 + hd*64);
    #pragma unroll
    for (int i = 0; i < 16; ++i) qreg[i] = qp[i];
  }

  // ---- phase A: scores ----
  const int jl = t & 31;
  for (int jc = 0; jc < 16; ++jc){
    const int j0 = jc << 6;
    __syncthreads();
    for (int i = t; i < 1280; i += 512){
      int rr = i >> 4, c4 = (i & 15) << 2;
      *(float4*)&kvs[rr][c4] = *(const float4*)(k + kbase + (long)(qb0 + j0 + rr)*1024 + c4);
    }
    for (int i = t; i < 1024; i += 512){
      int rr = i >> 4, c4 = (i & 15) << 2;
      *(float4*)&pes[rr][c4] = *(const float4*)(pe + (long)(j0 + rr)*64 + c4);
    }
    __syncthreads();
    #pragma unroll
    for (int ss = 0; ss < 2; ++ss){
      const int jloc = jl + (ss << 5);
      const float4* kp = (const float4*)&kvs[qq + jloc][0];
      const float4* pp = (const float4*)&pes[jloc][0];
      float a0 = 0.f, a1 = 0.f, a2 = 0.f, a3 = 0.f;
      #pragma unroll
      for (int d4 = 0; d4 < 16; ++d4){
        float4 kk = kp[d4];
        float4 pe4 = pp[d4];
        float4 qv = qreg[d4];
        a0 += qv.x * (kk.x + pe4.x);
        a1 += qv.y * (kk.y + pe4.y);
        a2 += qv.z * (kk.z + pe4.z);
        a3 += qv.w * (kk.w + pe4.w);
      }
      s[qq][j0 + jloc] = (a0 + a1 + a2 + a3) * 0.125f;
    }
  }
  __syncthreads();

  // ---- phase B: softmax ----
  {
    const int j0 = t & 31;
    float mx = -3.0e38f;
    for (int j = j0; j < 1024; j += 32) mx = fmaxf(mx, s[qq][j]);
    #pragma unroll
    for (int o = 16; o; o >>= 1) mx = fmaxf(mx, __shfl_xor(mx, o, 64));
    float sum = 0.f;
    for (int j = j0; j < 1024; j += 32){
      float ee = __expf(s[qq][j] - mx);
      s[qq][j] = ee; sum += ee;
    }
    #pragma unroll
    for (int o = 16; o; o >>= 1) sum += __shfl_xor(sum, o, 64);
    float inv = 1.f / sum;
    for (int j = j0; j < 1024; j += 32) s[qq][j] *= inv;
  }

  // ---- phase C: PV ----
  const int hq = (t >> 4) & 1;
  const int d0 = (t & 15) << 2;
  float4 oaccA = {0,0,0,0}, oaccB = {0,0,0,0};
  for (int jc = 0; jc < 16; ++jc){
    const int j0 = jc << 6;
    __syncthreads();
    for (int i = t; i < 1280; i += 512){
      int rr = i >> 4, c4 = (i & 15) << 2;
      *(float4*)&kvs[rr][c4] = *(const float4*)(v + kbase + (long)(qb0 + j0 + rr)*1024 + c4);
    }
    __syncthreads();
    #pragma unroll
    for (int jj = 0; jj < 8; ++jj){
      const int j4 = (hq << 5) + (jj << 2);
      float4 p4 = *(const float4*)&s[qq][j0 + j4];
      float4 w0 = *(const float4*)&kvs[qq + j4 + 0][d0];
      float4 w1 = *(const float4*)&kvs[qq + j4 + 1][d0];
      float4 w2 = *(const float4*)&kvs[qq + j4 + 2][d0];
      float4 w3 = *(const float4*)&kvs[qq + j4 + 3][d0];
      float4& oa = (jj & 1) ? oaccB : oaccA;
      oa.x += p4.x*w0.x; oa.y += p4.x*w0.y; oa.z += p4.x*w0.z; oa.w += p4.x*w0.w;
      oa.x += p4.y*w1.x; oa.y += p4.y*w1.y; oa.z += p4.y*w1.z; oa.w += p4.y*w1.w;
      oa.x += p4.z*w2.x; oa.y += p4.z*w2.y; oa.z += p4.z*w2.z; oa.w += p4.z*w2.w;
      oa.x += p4.w*w3.x; oa.y += p4.w*w3.y; oa.z += p4.w*w3.z; oa.w += p4.w*w3.w;
    }
  }
  float4 oc;
  oc.x = oaccA.x + oaccB.x; oc.y = oaccA.y + oaccB.y;
  oc.z = oaccA.z + oaccB.z; oc.w = oaccA.w + oaccB.w;
  oc.x += __shfl_xor(oc.x, 16, 64);
  oc.y += __shfl_xor(oc.y, 16, 64);
  oc.z += __shfl_xor(oc.z, 16, 64);
  oc.w += __shfl_xor(oc.w, 16, 64);
  if (hq == 0){
    ushort4 h4, l4;
    fsplit(oc.x, h4.x, l4.x); fsplit(oc.y, h4.y, l4.y);
    fsplit(oc.z, h4.z, l4.z); fsplit(oc.w, h4.w, l4.w);
    const long o = ((long)(b*1024 + qb0 + qq))*1024 + hd*64 + d0;
    *(ushort4*)(out_hi + o) = h4;
    *(ushort4*)(out_lo + o) = l4;
  }
}

// ======================= layernorm / gate / moe plumbing =======================

__device__ __forceinline__ void block_reduce2(float& s1, float& s2){
  #pragma unroll
  for (int o = 32; o; o >>= 1){
    s1 += __shfl_xor(s1, o, 64);
    s2 += __shfl_xor(s2, o, 64);
  }
  __shared__ float r1[4], r2[4];
  const int wid = threadIdx.x >> 6;
  if ((threadIdx.x & 63) == 0){ r1[wid] = s1; r2[wid] = s2; }
  __syncthreads();
  s1 = r1[0] + r1[1] + r1[2] + r1[3];
  s2 = r2[0] + r2[1] + r2[2] + r2[3];
  __syncthreads();
}

__global__ __launch_bounds__(256)
void add_ln_kernel(const float* __restrict__ a, const float* __restrict__ r,
                   const float* __restrict__ g, const float* __restrict__ bb,
                   float* __restrict__ of, u16* __restrict__ ob)
{
  const long row = blockIdx.x;
  const int t = threadIdx.x;
  float y[4]; float sum = 0.f, sq = 0.f;
  #pragma unroll
  for (int i = 0; i < 4; ++i){
    const long idx = row*1024 + t + (i<<8);
    float vv = a[idx] + r[idx];
    y[i] = vv; sum += vv; sq += vv*vv;
  }
  block_reduce2(sum, sq);
  const float mu = sum * (1.f/1024.f);
  const float var = fmaxf(sq * (1.f/1024.f) - mu*mu, 0.f);
  const float rs = rsqrtf(var + 1e-5f);
  #pragma unroll
  for (int i = 0; i < 4; ++i){
    const int hcol = t + (i<<8);
    float o = (y[i] - mu) * rs * g[hcol] + bb[hcol];
    of[row*1024 + hcol] = o;
    ob[row*1024 + hcol] = f2bf(o);
  }
}

__global__ __launch_bounds__(256)
void gate_kernel(const float* __restrict__ x, const float* __restrict__ gw,
                 const float* __restrict__ gb, int* __restrict__ eidx,
                 float* __restrict__ esc, int* __restrict__ counts)
{
  const long row = blockIdx.x;
  const int t = threadIdx.x;
  float a[8];
  #pragma unroll
  for (int e=0;e<8;e++) a[e]=0.f;
  for (int hcol = t; hcol < 1024; hcol += 256){
    float xv = x[row*1024 + hcol];
    const float* gr = gw + hcol*8;
    #pragma unroll
    for (int e=0;e<8;e++) a[e] += xv * gr[e];
  }
  #pragma unroll
  for (int e=0;e<8;e++)
    #pragma unroll
    for (int o=32;o;o>>=1) a[e] += __shfl_xor(a[e], o, 64);
  __shared__ float red[4][8];
  const int wid = t >> 6;
  if ((t & 63)==0){
    #pragma unroll
    for (int e=0;e<8;e++) red[wid][e]=a[e];
  }
  __syncthreads();
  if (t == 0){
    float l[8];
    #pragma unroll
    for (int e=0;e<8;e++) l[e] = red[0][e]+red[1][e]+red[2][e]+red[3][e] + gb[e];
    int i0 = 0; float v0 = l[0];
    #pragma unroll
    for (int e=1;e<8;e++) if (l[e] > v0){ v0=l[e]; i0=e; }
    int i1 = -1; float v1 = -3.0e38f;
    #pragma unroll
    for (int e=0;e<8;e++) if (e != i0 && l[e] > v1){ v1=l[e]; i1=e; }
    float e1 = __expf(v1 - v0);
    float den = 1.f + e1;
    eidx[row*2+0]=i0; eidx[row*2+1]=i1;
    esc[row*2+0]=1.f/den; esc[row*2+1]=e1/den;
    atomicAdd(&counts[i0],1); atomicAdd(&counts[i1],1);
  }
}

__global__ void scan_kernel(const int* __restrict__ counts, int* __restrict__ offs,
                            int* __restrict__ curs)
{
  if (threadIdx.x == 0 && blockIdx.x == 0){
    int acc = 0;
    for (int e=0;e<8;e++){ offs[e]=acc; curs[e]=acc; acc += counts[e]; }
  }
}

__global__ __launch_bounds__(256)
void scatter_kernel(const int* __restrict__ eidx, int* __restrict__ curs,
                    int* __restrict__ stok, int* __restrict__ ppos)
{
  int id = blockIdx.x*256 + threadIdx.x;
  if (id >= 8192) return;
  int e = eidx[id];
  e = (e < 0) ? 0 : ((e > 7) ? 7 : e);
  int pos = atomicAdd(&curs[e], 1);
  pos = (pos < 0) ? 0 : ((pos > 8191) ? 8191 : pos);
  stok[pos] = id >> 1;
  ppos[id] = pos;
}

__global__ __launch_bounds__(256)
void moe_combine_ln(const float* __restrict__ h1, const u16* __restrict__ pout,
                    const float* __restrict__ esc, const int* __restrict__ ppos,
                    const float* __restrict__ mg, const float* __restrict__ mb,
                    const float* __restrict__ n2g, const float* __restrict__ n2b,
                    float* __restrict__ outp)
{
  const long row = blockIdx.x;
  const int t = threadIdx.x;
  int p0i = ppos[row*2+0], p1i = ppos[row*2+1];
  p0i = (p0i < 0) ? 0 : ((p0i > 8191) ? 8191 : p0i);
  p1i = (p1i < 0) ? 0 : ((p1i > 8191) ? 8191 : p1i);
  const long p0 = p0i, p1 = p1i;
  const float s0 = esc[row*2+0], s1 = esc[row*2+1];
  float x[4], y[4];
  float sum=0.f, sq=0.f;
  #pragma unroll
  for (int i=0;i<4;i++){
    const int hcol = t + (i<<8);
    const long idx = row*1024 + hcol;
    float xv = h1[idx];
    float m = s0 * bf2f(pout[p0*1024 + hcol]) + s1 * bf2f(pout[p1*1024 + hcol]);
    x[i]=xv; y[i]=xv+m; sum+=y[i]; sq+=y[i]*y[i];
  }
  block_reduce2(sum, sq);
  float mu = sum*(1.f/1024.f), var = fmaxf(sq*(1.f/1024.f)-mu*mu, 0.f), rs = rsqrtf(var+1e-5f);
  float zz[4]; float sum2=0.f, sq2=0.f;
  #pragma unroll
  for (int i=0;i<4;i++){
    const int hcol = t + (i<<8);
    float core = (y[i]-mu)*rs*mg[hcol]+mb[hcol];
    zz[i] = x[i] + core; sum2+=zz[i]; sq2+=zz[i]*zz[i];
  }
  block_reduce2(sum2, sq2);
  float mu2 = sum2*(1.f/1024.f), var2 = fmaxf(sq2*(1.f/1024.f)-mu2*mu2, 0.f), rs2 = rsqrtf(var2+1e-5f);
  #pragma unroll
  for (int i=0;i<4;i++){
    const int hcol = t + (i<<8);
    outp[row*1024 + hcol] = (zz[i]-mu2)*rs2*n2g[hcol]+n2b[hcol];
  }
}

// ======================= launcher =======================
// Workspace (peak exactly 146 MB, same proven envelope; metadata at offset 0):
//   0..1    : metadata       1..2 : peT
//   2..18   : hall_hi        -> aproj f32 (after QKV)  -> pout bf16 (after add_ln)
//   18..34  : hall_lo        -> h1 f32 (after QKV)
//   34..50  : wT f16 hi/lo x4 (2 MB each)
//   50..66  : q f32          -> h1b bf16 50..58, w1Te 58..66 (after attn)
//   66..98  : k f32          -> w2Te 66..74, xhid 74..138 (after attn/WO)
//   98..130 : v f32          (xhid overlay)
//   130..138: aout_hi f16    (xhid overlay after WO)
//   138..146: aout_lo f16

extern "C" void kernel_launch(void* const* d_in, const int* in_sizes, int n_in,
                              void* d_out, int out_size, void* d_ws, size_t ws_size,
                              hipStream_t stream)
{
  const float* h      = (const float*)d_in[0];
  const float* hc     = (const float*)d_in[1];
  const float* key_pe = (const float*)d_in[2];
  const float* wq     = (const float*)d_in[3];
  const float* wk     = (const float*)d_in[4];
  const float* wv     = (const float*)d_in[5];
  const float* wo     = (const float*)d_in[6];
  const float* n1g    = (const float*)d_in[7];
  const float* n1b    = (const float*)d_in[8];
  const float* n2g    = (const float*)d_in[9];
  const float* n2b    = (const float*)d_in[10];
  const float* mlg    = (const float*)d_in[11];
  const float* mlb    = (const float*)d_in[12];
  const float* gw     = (const float*)d_in[13];
  const float* gb     = (const float*)d_in[14];
  const float* ew1    = (const float*)d_in[15];
  const float* eb1    = (const float*)d_in[16];
  const float* ew2    = (const float*)d_in[17];
  const float* eb2    = (const float*)d_in[18];
  float* outp = (float*)d_out;

  const size_t MB = 1ull << 20;
  char* base = (char*)d_ws;
  int*   counts = (int*)(base);
  int*   offs   = (int*)(base + 256);
  int*   curs   = (int*)(base + 512);
  int*   eidx   = (int*)(base + 1024);
  float* esc    = (float*)(base + 64*1024);
  int*   stok   = (int*)(base + 128*1024);
  int*   ppos   = (int*)(base + 192*1024);
  float* peT    = (float*)(base + 1*MB);
  u16*   hall_h = (u16*)(base + 2*MB);
  float* aproj  = (float*)(base + 2*MB);    // alias (after QKV GEMMs)
  u16*   pout   = (u16*)(base + 2*MB);      // alias (after add_ln)
  u16*   hall_l = (u16*)(base + 18*MB);
  float* h1     = (float*)(base + 18*MB);   // alias (after QKV GEMMs)
  u16*   wqT_h  = (u16*)(base + 34*MB);
  u16*   wqT_l  = (u16*)(base + 36*MB);
  u16*   wkT_h  = (u16*)(base + 38*MB);
  u16*   wkT_l  = (u16*)(base + 40*MB);
  u16*   wvT_h  = (u16*)(base + 42*MB);
  u16*   wvT_l  = (u16*)(base + 44*MB);
  u16*   woT_h  = (u16*)(base + 46*MB);
  u16*   woT_l  = (u16*)(base + 48*MB);
  float* q      = (float*)(base + 50*MB);
  u16*   h1b    = (u16*)(base + 50*MB);     // alias (after attn)
  u16*   w1Te   = (u16*)(base + 58*MB);     // alias (after attn)
  float* kbuf   = (float*)(base + 66*MB);
  u16*   w2Te   = (u16*)(base + 66*MB);     // alias (after attn)
  u16*   xhid   = (u16*)(base + 74*MB);     // alias (after attn/WO; 74..138)
  float* vbuf   = (float*)(base + 98*MB);
  u16*   aout_h = (u16*)(base + 130*MB);
  u16*   aout_l = (u16*)(base + 138*MB);

  zero8<<<1, 64, 0, stream>>>(counts);
  transpose_f32<<<dim3(32,2,1), dim3(32,8), 0, stream>>>(key_pe, peT, 64, 1024);

  // split-f16 conversions
  cvt_split_hall<<<8192, 256, 0, stream>>>(hc, h, hall_h, hall_l);
  dim3 tb32(32, 8);
  transpose_split<<<dim3(32,32), tb32, 0, stream>>>(wq, wqT_h, wqT_l, 1024, 1024);
  transpose_split<<<dim3(32,32), tb32, 0, stream>>>(wk, wkT_h, wkT_l, 1024, 1024);
  transpose_split<<<dim3(32,32), tb32, 0, stream>>>(wv, wvT_h, wvT_l, 1024, 1024);
  transpose_split<<<dim3(32,32), tb32, 0, stream>>>(wo, woT_h, woT_l, 1024, 1024);

  // QKV projections: split-f16 MFMA (f32-exact)
  gemm_sp<1><<<dim3(8,32), 256, 0, stream>>>(hall_h, hall_l, wqT_h, wqT_l, q,    1024, 1024);
  gemm_sp<0><<<dim3(8,64), 256, 0, stream>>>(hall_h, hall_l, wkT_h, wkT_l, kbuf, 1024, 1024);
  gemm_sp<0><<<dim3(8,64), 256, 0, stream>>>(hall_h, hall_l, wvT_h, wvT_l, vbuf, 1024, 1024);

  // attention (f32 VALU; outputs split-f16)
  attn16<<<dim3(64,16,4), 512, 0, stream>>>(q, kbuf, vbuf, peT, aout_h, aout_l);

  // WO projection (split-f16 MFMA) + residual LN
  gemm_sp<0><<<dim3(8,32), 256, 0, stream>>>(aout_h, aout_l, woT_h, woT_l, aproj, 1024, 1024);
  add_ln_kernel<<<4096, 256, 0, stream>>>(h, aproj, n1g, n1b, h1, h1b);

  // MoE gate + bucketing (f32 — exact top-2 vs reference)
  gate_kernel<<<4096, 256, 0, stream>>>(h1, gw, gb, eidx, esc, counts);
  scan_kernel<<<1, 64, 0, stream>>>(counts, offs, curs);
  scatter_kernel<<<32, 256, 0, stream>>>(eidx, curs, stok, ppos);

  // per-expert FFN: bf16 MFMA (downstream of gate; threshold-safe)
  for (int e = 0; e < 8; ++e){
    transpose_cvt<<<dim3(128,32), tb32, 0, stream>>>(ew1 + (long)e*1024*4096, w1Te, 1024, 4096);
    transpose_cvt<<<dim3(32,128), tb32, 0, stream>>>(ew2 + (long)e*4096*1024, w2Te, 4096, 1024);
    gemm_bt<true,  true ><<<dim3(32,64), 256, 0, stream>>>(h1b,  w1Te, xhid, eb1 + (long)e*4096,
                                                           4096, 1024, 4096, offs + e, counts + e, stok);
    gemm_bt<false, false><<<dim3(8,64),  256, 0, stream>>>(xhid, w2Te, pout, eb2 + (long)e*1024,
                                                           1024, 4096, 8192, offs + e, counts + e, nullptr);
  }

  // combine + the two trailing layernorms
  moe_combine_ln<<<4096, 256, 0, stream>>>(h1, pout, esc, ppos, mlg, mlb, n2g, n2b, outp);
}

// Round 7
// 1897.393 us; speedup vs baseline: 3.7842x; 1.2874x over previous
//
#include <hip/hip_runtime.h>

typedef unsigned short u16;
typedef __attribute__((ext_vector_type(8))) __bf16 bf16x8;
typedef __attribute__((ext_vector_type(8))) _Float16 f16x8;
typedef __attribute__((ext_vector_type(4))) float f32x4;

__device__ __forceinline__ u16 f2bf(float f){
  unsigned int u = __float_as_uint(f);
  u += 0x7FFFu + ((u >> 16) & 1u);     // RNE
  return (u16)(u >> 16);
}
__device__ __forceinline__ float bf2f(u16 s){
  return __uint_as_float(((unsigned int)s) << 16);
}
// split-f16: x = hi + lo with |x - hi - lo| <= 2^-24 |x|
__device__ __forceinline__ void fsplit(float x, u16& hi, u16& lo){
  _Float16 h = (_Float16)x;
  float r = x - (float)h;
  _Float16 l = (_Float16)r;
  hi = *(u16*)&h; lo = *(u16*)&l;
}

// ======================= small utility kernels =======================

__global__ void zero8(int* c){ if (threadIdx.x < 8) c[threadIdx.x] = 0; }

// transpose + convert: in [R][C] f32 -> out [C][R] bf16
__global__ __launch_bounds__(256)
void transpose_cvt(const float* __restrict__ in, u16* __restrict__ outp, int R, int C)
{
  __shared__ float tile[32][33];
  const int c0 = blockIdx.x << 5, r0 = blockIdx.y << 5;
  const int tx = threadIdx.x, ty = threadIdx.y;
  #pragma unroll
  for (int i = ty; i < 32; i += 8)
    tile[i][tx] = in[(long)(r0 + i) * C + c0 + tx];
  __syncthreads();
  #pragma unroll
  for (int i = ty; i < 32; i += 8)
    outp[(long)(c0 + i) * R + r0 + tx] = f2bf(tile[tx][i]);
}

// transpose + split-f16: in [R][C] f32 -> outh/outl [C][R] f16
__global__ __launch_bounds__(256)
void transpose_split(const float* __restrict__ in, u16* __restrict__ oh, u16* __restrict__ ol,
                     int R, int C)
{
  __shared__ float tile[32][33];
  const int c0 = blockIdx.x << 5, r0 = blockIdx.y << 5;
  const int tx = threadIdx.x, ty = threadIdx.y;
  #pragma unroll
  for (int i = ty; i < 32; i += 8)
    tile[i][tx] = in[(long)(r0 + i) * C + c0 + tx];
  __syncthreads();
  #pragma unroll
  for (int i = ty; i < 32; i += 8){
    u16 hh, ll;
    fsplit(tile[tx][i], hh, ll);
    oh[(long)(c0 + i) * R + r0 + tx] = hh;
    ol[(long)(c0 + i) * R + r0 + tx] = ll;
  }
}

// h_all = concat(hc, h) per batch -> split-f16 pair [8192][1024]
__global__ __launch_bounds__(256)
void cvt_split_hall(const float* __restrict__ hc, const float* __restrict__ h,
                    u16* __restrict__ hi, u16* __restrict__ lo)
{
  long i4 = (long)blockIdx.x * 256 + threadIdx.x;
  long row = i4 >> 8;
  int c4 = (int)(i4 & 255);
  int b = (int)(row >> 11), tt = (int)(row & 2047);
  const float4* src = (const float4*)((tt < 1024) ? (hc + ((long)b*1024 + tt)*1024)
                                                  : (h  + ((long)b*1024 + (tt-1024))*1024));
  float4 v = src[c4];
  ushort4 h4, l4;
  fsplit(v.x, h4.x, l4.x); fsplit(v.y, h4.y, l4.y);
  fsplit(v.z, h4.z, l4.z); fsplit(v.w, h4.w, l4.w);
  ((ushort4*)hi)[i4] = h4;
  ((ushort4*)lo)[i4] = l4;
}

// ======================= split-f16 emulated-f32 MFMA GEMM =======================
// AMAP 1: A row r -> h_all row (r>>10)*2048 + 1024 + (r&1023)   (Q projection)
// EPI 0: C f32;  EPI 1: C as split-f16 pair (Ch, Cl)

#define LDP 40

template<int AMAP, int EPI>
__global__ __launch_bounds__(256)
void gemm_sp(const u16* __restrict__ Ah_, const u16* __restrict__ Al_,
             const u16* __restrict__ Bh_, const u16* __restrict__ Bl_,
             float* __restrict__ C, u16* __restrict__ Ch, u16* __restrict__ Cl,
             int N, int Kd)
{
  __shared__ __align__(16) u16 Ahs[128*LDP];
  __shared__ __align__(16) u16 Als[128*LDP];
  __shared__ __align__(16) u16 Bhs[128*LDP];
  __shared__ __align__(16) u16 Bls[128*LDP];
  const int tm = blockIdx.y, tn = blockIdx.x;
  const int t = threadIdx.x;
  const int lane = t & 63, wid = t >> 6;
  const int wm = wid >> 1, wn = wid & 1;
  const int srow = t >> 1;
  const int scol = (t & 1) << 4;

  long arow;
  {
    int r = tm*128 + srow;
    if (AMAP == 1){ int b = r >> 10, tt = r & 1023; arow = (long)b*2048 + 1024 + tt; }
    else arow = (long)r;
  }
  const long brow = (long)(tn*128 + srow);

  f32x4 acc[4][4];
  const f32x4 z4 = {0.f,0.f,0.f,0.f};
  #pragma unroll
  for (int m=0;m<4;m++)
    #pragma unroll
    for (int n=0;n<4;n++) acc[m][n] = z4;

  const u16* pah = Ah_ + arow * Kd + scol;
  const u16* pal = Al_ + arow * Kd + scol;
  const u16* pbh = Bh_ + brow * Kd + scol;
  const u16* pbl = Bl_ + brow * Kd + scol;
  u16* wah = Ahs + srow*LDP + scol;
  u16* wal = Als + srow*LDP + scol;
  u16* wbh = Bhs + srow*LDP + scol;
  u16* wbl = Bls + srow*LDP + scol;
  const int fr = lane & 15, fq = lane >> 4;

  const int nk = Kd >> 5;
  for (int kt = 0; kt < nk; ++kt) {
    const int ko = kt << 5;
    uint4 ah0 = *(const uint4*)(pah + ko), ah1 = *(const uint4*)(pah + ko + 8);
    uint4 al0 = *(const uint4*)(pal + ko), al1 = *(const uint4*)(pal + ko + 8);
    uint4 bh0 = *(const uint4*)(pbh + ko), bh1 = *(const uint4*)(pbh + ko + 8);
    uint4 bl0 = *(const uint4*)(pbl + ko), bl1 = *(const uint4*)(pbl + ko + 8);
    __syncthreads();
    *(uint4*)wah = ah0; *(uint4*)(wah + 8) = ah1;
    *(uint4*)wal = al0; *(uint4*)(wal + 8) = al1;
    *(uint4*)wbh = bh0; *(uint4*)(wbh + 8) = bh1;
    *(uint4*)wbl = bl0; *(uint4*)(wbl + 8) = bl1;
    __syncthreads();
    f16x8 afh[4], afl[4], bfh[4], bfl[4];
    #pragma unroll
    for (int m=0;m<4;m++){
      afh[m] = *(const f16x8*)(Ahs + (wm*64 + m*16 + fr)*LDP + fq*8);
      afl[m] = *(const f16x8*)(Als + (wm*64 + m*16 + fr)*LDP + fq*8);
    }
    #pragma unroll
    for (int n=0;n<4;n++){
      bfh[n] = *(const f16x8*)(Bhs + (wn*64 + n*16 + fr)*LDP + fq*8);
      bfl[n] = *(const f16x8*)(Bls + (wn*64 + n*16 + fr)*LDP + fq*8);
    }
    #pragma unroll
    for (int m=0;m<4;m++)
      #pragma unroll
      for (int n=0;n<4;n++){
        acc[m][n] = __builtin_amdgcn_mfma_f32_16x16x32_f16(afl[m], bfh[n], acc[m][n], 0, 0, 0);
        acc[m][n] = __builtin_amdgcn_mfma_f32_16x16x32_f16(afh[m], bfl[n], acc[m][n], 0, 0, 0);
        acc[m][n] = __builtin_amdgcn_mfma_f32_16x16x32_f16(afh[m], bfh[n], acc[m][n], 0, 0, 0);
      }
  }

  // C/D layout: col = lane&15, row = (lane>>4)*4 + reg
  #pragma unroll
  for (int m=0;m<4;m++){
    #pragma unroll
    for (int j=0;j<4;j++){
      const long crow = (long)(tm*128 + wm*64 + m*16 + fq*4 + j);
      #pragma unroll
      for (int n=0;n<4;n++){
        const int c = tn*128 + wn*64 + n*16 + fr;
        float vv = acc[m][n][j];
        if (EPI == 0) C[crow * N + c] = vv;
        else {
          u16 hh, ll; fsplit(vv, hh, ll);
          Ch[crow * N + c] = hh;
          Cl[crow * N + c] = ll;
        }
      }
    }
  }
}

// ======================= MFMA split-f16 sliding-window attention =======================
// 16 q-rows per block, 4 waves. score[i][j] = q_i.(k_{i+j}+pe_j)/8, j in [0,1024).
// Phase A : Sj[r][j]  = Q @ Kwin^T   (c-coords tiles, scatter to j = c - r)
// Phase A2: Sj[r][j] += Q @ PE^T     (j-coords tiles, direct add)
// Softmax : per-row, 16 lanes/row, values in registers; emit P split-f16 (c-coords, band-masked)
// Phase C : out = P' @ Vwin          (A=P' from LDS, B=V^T split pair from global)

__global__ __launch_bounds__(256)
void attn_mfma(const u16* __restrict__ qh, const u16* __restrict__ ql,
               const u16* __restrict__ kh, const u16* __restrict__ kl,
               const u16* __restrict__ vth, const u16* __restrict__ vtl,
               const u16* __restrict__ peh, const u16* __restrict__ pel,
               u16* __restrict__ oh, u16* __restrict__ ol)
{
  __shared__ __align__(16) char smem[68608];
  float* Sj = (float*)smem;                  // [16][1024] f32
  u16*   Ph = (u16*)smem;                    // [16][1064] u16 (overlay, after Sj consumed)
  u16*   Pl = (u16*)(smem + 34048);          // [16][1064] u16
  const int q0 = blockIdx.x << 4;
  const int hd = blockIdx.y, b = blockIdx.z;
  const int t = threadIdx.x, lane = t & 63, wid = t >> 6;
  const int fr = lane & 15, fq = lane >> 4;
  const long kbase = (long)b * 2048;

  // Q A-fragments (held in registers; shared by phases A and A2)
  f16x8 qfh[2], qfl[2];
  {
    const long qoff = ((long)(b*1024 + q0 + fr))*1024 + hd*64 + fq*8;
    qfh[0] = *(const f16x8*)(qh + qoff);
    qfh[1] = *(const f16x8*)(qh + qoff + 32);
    qfl[0] = *(const f16x8*)(ql + qoff);
    qfl[1] = *(const f16x8*)(ql + qoff + 32);
  }

  // ---- phase A: Sj = Q @ Kwin^T (65 col-tiles; c = key - q0; j = c - row) ----
  for (int ct = wid; ct < 65; ct += 4){
    const int c = ct*16 + fr;                // key offset in window; key = q0 + c <= 2047
    const long koff = (kbase + q0 + c)*1024 + hd*64 + fq*8;
    f32x4 acc = {0.f,0.f,0.f,0.f};
    #pragma unroll
    for (int ks = 0; ks < 2; ++ks){
      f16x8 bh = *(const f16x8*)(kh + koff + ks*32);
      f16x8 bl = *(const f16x8*)(kl + koff + ks*32);
      acc = __builtin_amdgcn_mfma_f32_16x16x32_f16(qfl[ks], bh, acc, 0, 0, 0);
      acc = __builtin_amdgcn_mfma_f32_16x16x32_f16(qfh[ks], bl, acc, 0, 0, 0);
      acc = __builtin_amdgcn_mfma_f32_16x16x32_f16(qfh[ks], bh, acc, 0, 0, 0);
    }
    #pragma unroll
    for (int jj = 0; jj < 4; ++jj){
      const int row = fq*4 + jj;
      const int j = c - row;
      if (j >= 0 && j < 1024) Sj[row*1024 + j] = acc[jj];
    }
  }
  __syncthreads();

  // ---- phase A2: Sj += Q @ PE^T (64 j-tiles; unique (row,j) per lane-output) ----
  for (int jt = wid; jt < 64; jt += 4){
    const long poff = (long)(jt*16 + fr)*64 + fq*8;
    f32x4 acc = {0.f,0.f,0.f,0.f};
    #pragma unroll
    for (int ks = 0; ks < 2; ++ks){
      f16x8 bh = *(const f16x8*)(peh + poff + ks*32);
      f16x8 bl = *(const f16x8*)(pel + poff + ks*32);
      acc = __builtin_amdgcn_mfma_f32_16x16x32_f16(qfl[ks], bh, acc, 0, 0, 0);
      acc = __builtin_amdgcn_mfma_f32_16x16x32_f16(qfh[ks], bl, acc, 0, 0, 0);
      acc = __builtin_amdgcn_mfma_f32_16x16x32_f16(qfh[ks], bh, acc, 0, 0, 0);
    }
    const int j = jt*16 + fr;
    #pragma unroll
    for (int jj = 0; jj < 4; ++jj){
      const int row = fq*4 + jj;
      Sj[row*1024 + j] += acc[jj];
    }
  }
  __syncthreads();

  // ---- softmax: row r = t>>4, lane g = t&15 handles j = g + 16m ----
  {
    const int r = t >> 4, g = t & 15;
    float sv[64];
    float mx = -3.0e38f;
    #pragma unroll
    for (int m = 0; m < 64; ++m){
      float x = Sj[r*1024 + g + (m<<4)] * 0.125f;
      sv[m] = x; mx = fmaxf(mx, x);
    }
    #pragma unroll
    for (int o = 8; o; o >>= 1) mx = fmaxf(mx, __shfl_xor(mx, o, 64));
    float sum = 0.f;
    #pragma unroll
    for (int m = 0; m < 64; ++m){ sv[m] = __expf(sv[m] - mx); sum += sv[m]; }
    #pragma unroll
    for (int o = 8; o; o >>= 1) sum += __shfl_xor(sum, o, 64);
    const float inv = 1.f / sum;
    __syncthreads();                           // Sj fully consumed into registers
    for (int i = t; i < 17024; i += 256) ((unsigned*)smem)[i] = 0;   // zero Ph+Pl
    __syncthreads();
    #pragma unroll
    for (int m = 0; m < 64; ++m){
      float p = sv[m] * inv;
      u16 hh, ll; fsplit(p, hh, ll);
      const int c = r + g + (m<<4);            // band position
      Ph[r*1064 + c] = hh;
      Pl[r*1064 + c] = ll;
    }
  }
  __syncthreads();

  // ---- phase C: PV. wave wid owns d-tile wid (16 d); K-dim = 33x32 over c ----
  {
    f32x4 acc0 = {0.f,0.f,0.f,0.f}, acc1 = {0.f,0.f,0.f,0.f};
    const long vrow = (long)(hd*64 + wid*16 + fr) * 8192 + kbase;
    for (int ks = 0; ks < 33; ++ks){
      int st = q0 + ks*32 + fq*8;
      if (st > 2040) st = 2040;                // clamp (P' zero there)
      f16x8 vh = *(const f16x8*)(vth + vrow + st);
      f16x8 vl = *(const f16x8*)(vtl + vrow + st);
      f16x8 ah = *(const f16x8*)(Ph + fr*1064 + ks*32 + fq*8);
      f16x8 al = *(const f16x8*)(Pl + fr*1064 + ks*32 + fq*8);
      f32x4& a = (ks & 1) ? acc1 : acc0;
      a = __builtin_amdgcn_mfma_f32_16x16x32_f16(al, vh, a, 0, 0, 0);
      a = __builtin_amdgcn_mfma_f32_16x16x32_f16(ah, vl, a, 0, 0, 0);
      a = __builtin_amdgcn_mfma_f32_16x16x32_f16(ah, vh, a, 0, 0, 0);
    }
    #pragma unroll
    for (int jj = 0; jj < 4; ++jj){
      float v = acc0[jj] + acc1[jj];
      u16 hh, ll; fsplit(v, hh, ll);
      const int row = fq*4 + jj;
      const long o = ((long)(b*1024 + q0 + row))*1024 + hd*64 + wid*16 + fr;
      oh[o] = hh; ol[o] = ll;
    }
  }
}

// ======================= MFMA bf16 GEMM for MoE (Bt[N][K] layout) =======================

template<bool GATHER, bool RELU>
__global__ __launch_bounds__(256, 2)
void gemm_bt(const u16* __restrict__ A, const u16* __restrict__ Bt, u16* __restrict__ Cp,
             const float* __restrict__ bias, int N, int Kd, int maxA,
             const int* __restrict__ rbase_p, const int* __restrict__ cnt_p,
             const int* __restrict__ gather)
{
  __shared__ __align__(16) u16 As[128*LDP];
  __shared__ __align__(16) u16 Bs[128*LDP];
  const int rbase = rbase_p[0];
  const int cnt   = cnt_p[0];
  const int tm = blockIdx.y, tn = blockIdx.x;
  if (tm * 128 >= cnt) return;

  const int t = threadIdx.x;
  const int lane = t & 63, wid = t >> 6;
  const int wm = wid >> 1, wn = wid & 1;
  const int srow = t >> 1;
  const int scol = (t & 1) << 4;

  long arow;
  {
    int r = tm*128 + srow;
    int rc = (r < cnt) ? r : (cnt - 1);
    if (GATHER){
      int gi = rbase + rc; gi = (gi < 0) ? 0 : ((gi > 8191) ? 8191 : gi);
      int tok = gather[gi];
      tok = (tok < 0) ? 0 : ((tok >= maxA) ? (maxA - 1) : tok);
      arow = (long)tok;
    } else {
      arow = (long)rc;
    }
  }
  const long brow = (long)(tn*128 + srow);

  f32x4 acc[4][4];
  const f32x4 z4 = {0.f,0.f,0.f,0.f};
  #pragma unroll
  for (int m=0;m<4;m++)
    #pragma unroll
    for (int n=0;n<4;n++) acc[m][n] = z4;

  const u16* aptr = A + arow * Kd + scol;
  const u16* bptr = Bt + brow * Kd + scol;
  u16* as_w = As + srow*LDP + scol;
  u16* bs_w = Bs + srow*LDP + scol;
  const int fr = lane & 15, fq = lane >> 4;

  const int nk = Kd >> 5;
  for (int kt = 0; kt < nk; ++kt) {
    uint4 av0 = *(const uint4*)(aptr + (kt<<5));
    uint4 av1 = *(const uint4*)(aptr + (kt<<5) + 8);
    uint4 bv0 = *(const uint4*)(bptr + (kt<<5));
    uint4 bv1 = *(const uint4*)(bptr + (kt<<5) + 8);
    __syncthreads();
    *(uint4*)as_w       = av0;
    *(uint4*)(as_w + 8) = av1;
    *(uint4*)bs_w       = bv0;
    *(uint4*)(bs_w + 8) = bv1;
    __syncthreads();
    bf16x8 af[4], bfv[4];
    #pragma unroll
    for (int m=0;m<4;m++) af[m]  = *(const bf16x8*)(As + (wm*64 + m*16 + fr)*LDP + fq*8);
    #pragma unroll
    for (int n=0;n<4;n++) bfv[n] = *(const bf16x8*)(Bs + (wn*64 + n*16 + fr)*LDP + fq*8);
    #pragma unroll
    for (int m=0;m<4;m++)
      #pragma unroll
      for (int n=0;n<4;n++)
        acc[m][n] = __builtin_amdgcn_mfma_f32_16x16x32_bf16(af[m], bfv[n], acc[m][n], 0, 0, 0);
  }

  #pragma unroll
  for (int m=0;m<4;m++){
    #pragma unroll
    for (int j=0;j<4;j++){
      const int r = tm*128 + wm*64 + m*16 + fq*4 + j;
      if (r >= cnt) continue;
      const long crow = GATHER ? (long)r : (long)(rbase + r);
      #pragma unroll
      for (int n=0;n<4;n++){
        const int c = tn*128 + wn*64 + n*16 + fr;
        float vv = acc[m][n][j] + bias[c];
        if (RELU) vv = fmaxf(vv, 0.f);
        Cp[crow * N + c] = f2bf(vv);
      }
    }
  }
}

// ======================= layernorm / gate / moe plumbing =======================

__device__ __forceinline__ void block_reduce2(float& s1, float& s2){
  #pragma unroll
  for (int o = 32; o; o >>= 1){
    s1 += __shfl_xor(s1, o, 64);
    s2 += __shfl_xor(s2, o, 64);
  }
  __shared__ float r1[4], r2[4];
  const int wid = threadIdx.x >> 6;
  if ((threadIdx.x & 63) == 0){ r1[wid] = s1; r2[wid] = s2; }
  __syncthreads();
  s1 = r1[0] + r1[1] + r1[2] + r1[3];
  s2 = r2[0] + r2[1] + r2[2] + r2[3];
  __syncthreads();
}

__global__ __launch_bounds__(256)
void add_ln_kernel(const float* __restrict__ a, const float* __restrict__ r,
                   const float* __restrict__ g, const float* __restrict__ bb,
                   float* __restrict__ of, u16* __restrict__ ob)
{
  const long row = blockIdx.x;
  const int t = threadIdx.x;
  float y[4]; float sum = 0.f, sq = 0.f;
  #pragma unroll
  for (int i = 0; i < 4; ++i){
    const long idx = row*1024 + t + (i<<8);
    float vv = a[idx] + r[idx];
    y[i] = vv; sum += vv; sq += vv*vv;
  }
  block_reduce2(sum, sq);
  const float mu = sum * (1.f/1024.f);
  const float var = fmaxf(sq * (1.f/1024.f) - mu*mu, 0.f);
  const float rs = rsqrtf(var + 1e-5f);
  #pragma unroll
  for (int i = 0; i < 4; ++i){
    const int hcol = t + (i<<8);
    float o = (y[i] - mu) * rs * g[hcol] + bb[hcol];
    of[row*1024 + hcol] = o;
    ob[row*1024 + hcol] = f2bf(o);
  }
}

__global__ __launch_bounds__(256)
void gate_kernel(const float* __restrict__ x, const float* __restrict__ gw,
                 const float* __restrict__ gb, int* __restrict__ eidx,
                 float* __restrict__ esc, int* __restrict__ counts)
{
  const long row = blockIdx.x;
  const int t = threadIdx.x;
  float a[8];
  #pragma unroll
  for (int e=0;e<8;e++) a[e]=0.f;
  for (int hcol = t; hcol < 1024; hcol += 256){
    float xv = x[row*1024 + hcol];
    const float* gr = gw + hcol*8;
    #pragma unroll
    for (int e=0;e<8;e++) a[e] += xv * gr[e];
  }
  #pragma unroll
  for (int e=0;e<8;e++)
    #pragma unroll
    for (int o=32;o;o>>=1) a[e] += __shfl_xor(a[e], o, 64);
  __shared__ float red[4][8];
  const int wid = t >> 6;
  if ((t & 63)==0){
    #pragma unroll
    for (int e=0;e<8;e++) red[wid][e]=a[e];
  }
  __syncthreads();
  if (t == 0){
    float l[8];
    #pragma unroll
    for (int e=0;e<8;e++) l[e] = red[0][e]+red[1][e]+red[2][e]+red[3][e] + gb[e];
    int i0 = 0; float v0 = l[0];
    #pragma unroll
    for (int e=1;e<8;e++) if (l[e] > v0){ v0=l[e]; i0=e; }
    int i1 = -1; float v1 = -3.0e38f;
    #pragma unroll
    for (int e=0;e<8;e++) if (e != i0 && l[e] > v1){ v1=l[e]; i1=e; }
    float e1 = __expf(v1 - v0);
    float den = 1.f + e1;
    eidx[row*2+0]=i0; eidx[row*2+1]=i1;
    esc[row*2+0]=1.f/den; esc[row*2+1]=e1/den;
    atomicAdd(&counts[i0],1); atomicAdd(&counts[i1],1);
  }
}

__global__ void scan_kernel(const int* __restrict__ counts, int* __restrict__ offs,
                            int* __restrict__ curs)
{
  if (threadIdx.x == 0 && blockIdx.x == 0){
    int acc = 0;
    for (int e=0;e<8;e++){ offs[e]=acc; curs[e]=acc; acc += counts[e]; }
  }
}

__global__ __launch_bounds__(256)
void scatter_kernel(const int* __restrict__ eidx, int* __restrict__ curs,
                    int* __restrict__ stok, int* __restrict__ ppos)
{
  int id = blockIdx.x*256 + threadIdx.x;
  if (id >= 8192) return;
  int e = eidx[id];
  e = (e < 0) ? 0 : ((e > 7) ? 7 : e);
  int pos = atomicAdd(&curs[e], 1);
  pos = (pos < 0) ? 0 : ((pos > 8191) ? 8191 : pos);
  stok[pos] = id >> 1;
  ppos[id] = pos;
}

__global__ __launch_bounds__(256)
void moe_combine_ln(const float* __restrict__ h1, const u16* __restrict__ pout,
                    const float* __restrict__ esc, const int* __restrict__ ppos,
                    const float* __restrict__ mg, const float* __restrict__ mb,
                    const float* __restrict__ n2g, const float* __restrict__ n2b,
                    float* __restrict__ outp)
{
  const long row = blockIdx.x;
  const int t = threadIdx.x;
  int p0i = ppos[row*2+0], p1i = ppos[row*2+1];
  p0i = (p0i < 0) ? 0 : ((p0i > 8191) ? 8191 : p0i);
  p1i = (p1i < 0) ? 0 : ((p1i > 8191) ? 8191 : p1i);
  const long p0 = p0i, p1 = p1i;
  const float s0 = esc[row*2+0], s1 = esc[row*2+1];
  float x[4], y[4];
  float sum=0.f, sq=0.f;
  #pragma unroll
  for (int i=0;i<4;i++){
    const int hcol = t + (i<<8);
    const long idx = row*1024 + hcol;
    float xv = h1[idx];
    float m = s0 * bf2f(pout[p0*1024 + hcol]) + s1 * bf2f(pout[p1*1024 + hcol]);
    x[i]=xv; y[i]=xv+m; sum+=y[i]; sq+=y[i]*y[i];
  }
  block_reduce2(sum, sq);
  float mu = sum*(1.f/1024.f), var = fmaxf(sq*(1.f/1024.f)-mu*mu, 0.f), rs = rsqrtf(var+1e-5f);
  float zz[4]; float sum2=0.f, sq2=0.f;
  #pragma unroll
  for (int i=0;i<4;i++){
    const int hcol = t + (i<<8);
    float core = (y[i]-mu)*rs*mg[hcol]+mb[hcol];
    zz[i] = x[i] + core; sum2+=zz[i]; sq2+=zz[i]*zz[i];
  }
  block_reduce2(sum2, sq2);
  float mu2 = sum2*(1.f/1024.f), var2 = fmaxf(sq2*(1.f/1024.f)-mu2*mu2, 0.f), rs2 = rsqrtf(var2+1e-5f);
  #pragma unroll
  for (int i=0;i<4;i++){
    const int hcol = t + (i<<8);
    outp[row*1024 + hcol] = (zz[i]-mu2)*rs2*n2g[hcol]+n2b[hcol];
  }
}

// ======================= launcher =======================
// Workspace (peak 146 MB, proven envelope; metadata at offset 0):
//  0..0.25 : metadata     1..2 : peh/pel
//  2..18   : hall_h  -> vt_h (after V gemm) -> h1b 2..10, w1Te 10..18 (after attn)
//  18..34  : hall_l  -> vt_l               -> w2Te 18..26, pout 26..42 (after attn)
//  34..50  : wqT/wkT/wvT/woT h+l pairs (2 MB each); 34..42 dies into pout
//  50..66  : qh/ql   -> aproj f32 (after attn)
//  66..82  : kh      -> h1 f32 (after attn)
//  82..98  : kl      -> xhid 82..146 (after attn/WO)
//  98..130 : vbuf f32 -> aout_h 98..106, aout_l 106..114 (after V transpose)
//  130..146: (xhid tail)

extern "C" void kernel_launch(void* const* d_in, const int* in_sizes, int n_in,
                              void* d_out, int out_size, void* d_ws, size_t ws_size,
                              hipStream_t stream)
{
  const float* h      = (const float*)d_in[0];
  const float* hc     = (const float*)d_in[1];
  const float* key_pe = (const float*)d_in[2];
  const float* wq     = (const float*)d_in[3];
  const float* wk     = (const float*)d_in[4];
  const float* wv     = (const float*)d_in[5];
  const float* wo     = (const float*)d_in[6];
  const float* n1g    = (const float*)d_in[7];
  const float* n1b    = (const float*)d_in[8];
  const float* n2g    = (const float*)d_in[9];
  const float* n2b    = (const float*)d_in[10];
  const float* mlg    = (const float*)d_in[11];
  const float* mlb    = (const float*)d_in[12];
  const float* gw     = (const float*)d_in[13];
  const float* gb     = (const float*)d_in[14];
  const float* ew1    = (const float*)d_in[15];
  const float* eb1    = (const float*)d_in[16];
  const float* ew2    = (const float*)d_in[17];
  const float* eb2    = (const float*)d_in[18];
  float* outp = (float*)d_out;

  const size_t MB = 1ull << 20;
  char* base = (char*)d_ws;
  int*   counts = (int*)(base);
  int*   offs   = (int*)(base + 256);
  int*   curs   = (int*)(base + 512);
  int*   eidx   = (int*)(base + 1024);
  float* esc    = (float*)(base + 64*1024);
  int*   stok   = (int*)(base + 128*1024);
  int*   ppos   = (int*)(base + 192*1024);
  u16*   peh    = (u16*)(base + 1*MB);
  u16*   pel    = (u16*)(base + 1*MB + 512*1024);
  u16*   hall_h = (u16*)(base + 2*MB);
  u16*   vt_h   = (u16*)(base + 2*MB);      // alias (after V gemm)
  u16*   h1b    = (u16*)(base + 2*MB);      // alias (after attn)
  u16*   w1Te   = (u16*)(base + 10*MB);     // alias (after attn)
  u16*   hall_l = (u16*)(base + 18*MB);
  u16*   vt_l   = (u16*)(base + 18*MB);     // alias (after V gemm)
  u16*   w2Te   = (u16*)(base + 18*MB);     // alias (after attn)
  u16*   pout   = (u16*)(base + 26*MB);     // alias (after attn; spills into dead wq pair)
  u16*   wqT_h  = (u16*)(base + 34*MB);
  u16*   wqT_l  = (u16*)(base + 36*MB);
  u16*   wkT_h  = (u16*)(base + 38*MB);
  u16*   wkT_l  = (u16*)(base + 40*MB);
  u16*   wvT_h  = (u16*)(base + 42*MB);
  u16*   wvT_l  = (u16*)(base + 44*MB);
  u16*   woT_h  = (u16*)(base + 46*MB);
  u16*   woT_l  = (u16*)(base + 48*MB);
  u16*   qh     = (u16*)(base + 50*MB);
  u16*   ql     = (u16*)(base + 58*MB);
  float* aproj  = (float*)(base + 50*MB);   // alias (after attn)
  u16*   kh     = (u16*)(base + 66*MB);
  float* h1     = (float*)(base + 66*MB);   // alias (after attn)
  u16*   kl     = (u16*)(base + 82*MB);
  u16*   xhid   = (u16*)(base + 82*MB);     // alias (after attn/WO; 82..146)
  float* vbuf   = (float*)(base + 98*MB);
  u16*   aout_h = (u16*)(base + 98*MB);     // alias (after V transpose)
  u16*   aout_l = (u16*)(base + 106*MB);

  zero8<<<1, 64, 0, stream>>>(counts);
  dim3 tb32(32, 8);

  // conversions
  cvt_split_hall<<<8192, 256, 0, stream>>>(hc, h, hall_h, hall_l);
  transpose_split<<<dim3(32,2),  tb32, 0, stream>>>(key_pe, peh, pel, 64, 1024);
  transpose_split<<<dim3(32,32), tb32, 0, stream>>>(wq, wqT_h, wqT_l, 1024, 1024);
  transpose_split<<<dim3(32,32), tb32, 0, stream>>>(wk, wkT_h, wkT_l, 1024, 1024);
  transpose_split<<<dim3(32,32), tb32, 0, stream>>>(wv, wvT_h, wvT_l, 1024, 1024);
  transpose_split<<<dim3(32,32), tb32, 0, stream>>>(wo, woT_h, woT_l, 1024, 1024);

  // QKV projections (split-f16 MFMA, f32-exact); Q/K emit split pairs, V emits f32
  gemm_sp<1,1><<<dim3(8,32), 256, 0, stream>>>(hall_h, hall_l, wqT_h, wqT_l, nullptr, qh, ql, 1024, 1024);
  gemm_sp<0,1><<<dim3(8,64), 256, 0, stream>>>(hall_h, hall_l, wkT_h, wkT_l, nullptr, kh, kl, 1024, 1024);
  gemm_sp<0,0><<<dim3(8,64), 256, 0, stream>>>(hall_h, hall_l, wvT_h, wvT_l, vbuf, nullptr, nullptr, 1024, 1024);

  // V^T split pair [1024 d][8192 keys] (hall region dead now)
  transpose_split<<<dim3(32,256), tb32, 0, stream>>>(vbuf, vt_h, vt_l, 8192, 1024);

  // MFMA attention (outputs split pair over dead vbuf)
  attn_mfma<<<dim3(64,16,4), 256, 0, stream>>>(qh, ql, kh, kl, vt_h, vt_l, peh, pel, aout_h, aout_l);

  // WO projection + residual LN
  gemm_sp<0,0><<<dim3(8,32), 256, 0, stream>>>(aout_h, aout_l, woT_h, woT_l, aproj, nullptr, nullptr, 1024, 1024);
  add_ln_kernel<<<4096, 256, 0, stream>>>(h, aproj, n1g, n1b, h1, h1b);

  // MoE gate + bucketing (f32 — exact top-2 vs reference)
  gate_kernel<<<4096, 256, 0, stream>>>(h1, gw, gb, eidx, esc, counts);
  scan_kernel<<<1, 64, 0, stream>>>(counts, offs, curs);
  scatter_kernel<<<32, 256, 0, stream>>>(eidx, curs, stok, ppos);

  // per-expert FFN: bf16 MFMA (downstream of gate; threshold-safe)
  for (int e = 0; e < 8; ++e){
    transpose_cvt<<<dim3(128,32), tb32, 0, stream>>>(ew1 + (long)e*1024*4096, w1Te, 1024, 4096);
    transpose_cvt<<<dim3(32,128), tb32, 0, stream>>>(ew2 + (long)e*4096*1024, w2Te, 4096, 1024);
    gemm_bt<true,  true ><<<dim3(32,64), 256, 0, stream>>>(h1b,  w1Te, xhid, eb1 + (long)e*4096,
                                                           4096, 1024, 4096, offs + e, counts + e, stok);
    gemm_bt<false, false><<<dim3(8,64),  256, 0, stream>>>(xhid, w2Te, pout, eb2 + (long)e*1024,
                                                           1024, 4096, 8192, offs + e, counts + e, nullptr);
  }

  // combine + the two trailing layernorms
  moe_combine_ln<<<4096, 256, 0, stream>>>(h1, pout, esc, ppos, mlg, mlb, n2g, n2b, outp);
}

// Round 8
// 1891.738 us; speedup vs baseline: 3.7955x; 1.0030x over previous
//
#include <hip/hip_runtime.h>

typedef unsigned short u16;
typedef unsigned int u32;
typedef __attribute__((ext_vector_type(8))) __bf16 bf16x8;
typedef __attribute__((ext_vector_type(8))) _Float16 f16x8;
typedef __attribute__((ext_vector_type(4))) float f32x4;

__device__ __forceinline__ u16 f2bf(float f){
  unsigned int u = __float_as_uint(f);
  u += 0x7FFFu + ((u >> 16) & 1u);     // RNE
  return (u16)(u >> 16);
}
__device__ __forceinline__ float bf2f(u16 s){
  return __uint_as_float(((unsigned int)s) << 16);
}
// split-f16: x = hi + lo with |x - hi - lo| <= 2^-24 |x|
__device__ __forceinline__ void fsplit(float x, u16& hi, u16& lo){
  _Float16 h = (_Float16)x;
  float r = x - (float)h;
  _Float16 l = (_Float16)r;
  hi = *(u16*)&h; lo = *(u16*)&l;
}
// async global->LDS, 16B per lane. lds must be wave-uniform base (HW adds lane*16).
// generic->as3 via low-32-bit truncation (CK-proven; LLVM lowers flat->group the same way).
__device__ __forceinline__ void gll16(const u16* g, u16* lds){
  __builtin_amdgcn_global_load_lds(
      (const __attribute__((address_space(1))) u32*)g,
      (__attribute__((address_space(3))) u32*)(u32)(unsigned long long)lds,
      16, 0, 0);
}

// ======================= small utility kernels =======================

__global__ void zero8(int* c){ if (threadIdx.x < 8) c[threadIdx.x] = 0; }

// transpose + convert: in [R][C] f32 -> out [C][R] bf16
__global__ __launch_bounds__(256)
void transpose_cvt(const float* __restrict__ in, u16* __restrict__ outp, int R, int C)
{
  __shared__ float tile[32][33];
  const int c0 = blockIdx.x << 5, r0 = blockIdx.y << 5;
  const int tx = threadIdx.x, ty = threadIdx.y;
  #pragma unroll
  for (int i = ty; i < 32; i += 8)
    tile[i][tx] = in[(long)(r0 + i) * C + c0 + tx];
  __syncthreads();
  #pragma unroll
  for (int i = ty; i < 32; i += 8)
    outp[(long)(c0 + i) * R + r0 + tx] = f2bf(tile[tx][i]);
}

// transpose + split-f16: in [R][C] f32 -> outh/outl [C][R] f16
__global__ __launch_bounds__(256)
void transpose_split(const float* __restrict__ in, u16* __restrict__ oh, u16* __restrict__ ol,
                     int R, int C)
{
  __shared__ float tile[32][33];
  const int c0 = blockIdx.x << 5, r0 = blockIdx.y << 5;
  const int tx = threadIdx.x, ty = threadIdx.y;
  #pragma unroll
  for (int i = ty; i < 32; i += 8)
    tile[i][tx] = in[(long)(r0 + i) * C + c0 + tx];
  __syncthreads();
  #pragma unroll
  for (int i = ty; i < 32; i += 8){
    u16 hh, ll;
    fsplit(tile[tx][i], hh, ll);
    oh[(long)(c0 + i) * R + r0 + tx] = hh;
    ol[(long)(c0 + i) * R + r0 + tx] = ll;
  }
}

// h_all = concat(hc, h) per batch -> split-f16 pair [8192][1024]
__global__ __launch_bounds__(256)
void cvt_split_hall(const float* __restrict__ hc, const float* __restrict__ h,
                    u16* __restrict__ hi, u16* __restrict__ lo)
{
  long i4 = (long)blockIdx.x * 256 + threadIdx.x;
  long row = i4 >> 8;
  int c4 = (int)(i4 & 255);
  int b = (int)(row >> 11), tt = (int)(row & 2047);
  const float4* src = (const float4*)((tt < 1024) ? (hc + ((long)b*1024 + tt)*1024)
                                                  : (h  + ((long)b*1024 + (tt-1024))*1024));
  float4 v = src[c4];
  ushort4 h4, l4;
  fsplit(v.x, h4.x, l4.x); fsplit(v.y, h4.y, l4.y);
  fsplit(v.z, h4.z, l4.z); fsplit(v.w, h4.w, l4.w);
  ((ushort4*)hi)[i4] = h4;
  ((ushort4*)lo)[i4] = l4;
}

// ======================= split-f16 emulated-f32 MFMA GEMM =======================
// 128x128 tile, BK=32, linear LDS [128][32] (m97 layout), global_load_lds staging.
// AMAP 1: A row r -> h_all row (r>>10)*2048 + 1024 + (r&1023)   (Q projection)
// EPI 0: C f32;  EPI 1: C as split-f16 pair (Ch, Cl)

template<int AMAP, int EPI>
__global__ __launch_bounds__(256)
void gemm_sp(const u16* __restrict__ Ah_, const u16* __restrict__ Al_,
             const u16* __restrict__ Bh_, const u16* __restrict__ Bl_,
             float* __restrict__ C, u16* __restrict__ Ch, u16* __restrict__ Cl,
             int N, int Kd)
{
  __shared__ __align__(16) u16 Ahs[4096];
  __shared__ __align__(16) u16 Als[4096];
  __shared__ __align__(16) u16 Bhs[4096];
  __shared__ __align__(16) u16 Bls[4096];
  const int tm = blockIdx.y, tn = blockIdx.x;
  const int t = threadIdx.x;
  const int lane = t & 63, wv = t >> 6;
  const int wm = wv >> 1, wn = wv & 1;
  const int fr = lane & 15, fq = lane >> 4;

  // staging geometry: wave wv stages rows 32wv..32wv+31; issue u covers 16 rows;
  // lane l -> row 32wv+16u+(l>>2), col (l&3)*8 u16 (16B)
  const int r0l = 32*wv + (lane >> 2);
  const int r1l = r0l + 16;
  const int colu = (lane & 3) << 3;
  auto amap = [](int r)->long{
    if (AMAP == 1){ int b = r >> 10, tt = r & 1023; return (long)b*2048 + 1024 + tt; }
    return (long)r;
  };
  const long ar0 = amap(tm*128 + r0l), ar1 = amap(tm*128 + r1l);
  const long br0 = (long)(tn*128 + r0l), br1 = (long)(tn*128 + r1l);
  const u16* pah0 = Ah_ + ar0*Kd + colu;  const u16* pah1 = Ah_ + ar1*Kd + colu;
  const u16* pal0 = Al_ + ar0*Kd + colu;  const u16* pal1 = Al_ + ar1*Kd + colu;
  const u16* pbh0 = Bh_ + br0*Kd + colu;  const u16* pbh1 = Bh_ + br1*Kd + colu;
  const u16* pbl0 = Bl_ + br0*Kd + colu;  const u16* pbl1 = Bl_ + br1*Kd + colu;
  u16* lAh0 = Ahs + 1024*wv;  u16* lAh1 = lAh0 + 512;
  u16* lAl0 = Als + 1024*wv;  u16* lAl1 = lAl0 + 512;
  u16* lBh0 = Bhs + 1024*wv;  u16* lBh1 = lBh0 + 512;
  u16* lBl0 = Bls + 1024*wv;  u16* lBl1 = lBl0 + 512;

  f32x4 acc[4][4];
  const f32x4 z4 = {0.f,0.f,0.f,0.f};
  #pragma unroll
  for (int m=0;m<4;m++)
    #pragma unroll
    for (int n=0;n<4;n++) acc[m][n] = z4;

  const int nk = Kd >> 5;
  for (int kt = 0; kt < nk; ++kt) {
    const int ko = kt << 5;
    __syncthreads();
    gll16(pah0 + ko, lAh0); gll16(pah1 + ko, lAh1);
    gll16(pal0 + ko, lAl0); gll16(pal1 + ko, lAl1);
    gll16(pbh0 + ko, lBh0); gll16(pbh1 + ko, lBh1);
    gll16(pbl0 + ko, lBl0); gll16(pbl1 + ko, lBl1);
    __syncthreads();
    f16x8 afh[4], afl[4], bfh[4], bfl[4];
    #pragma unroll
    for (int m=0;m<4;m++){
      afh[m] = *(const f16x8*)(Ahs + (wm*64 + m*16 + fr)*32 + fq*8);
      afl[m] = *(const f16x8*)(Als + (wm*64 + m*16 + fr)*32 + fq*8);
    }
    #pragma unroll
    for (int n=0;n<4;n++){
      bfh[n] = *(const f16x8*)(Bhs + (wn*64 + n*16 + fr)*32 + fq*8);
      bfl[n] = *(const f16x8*)(Bls + (wn*64 + n*16 + fr)*32 + fq*8);
    }
    #pragma unroll
    for (int m=0;m<4;m++)
      #pragma unroll
      for (int n=0;n<4;n++){
        acc[m][n] = __builtin_amdgcn_mfma_f32_16x16x32_f16(afl[m], bfh[n], acc[m][n], 0, 0, 0);
        acc[m][n] = __builtin_amdgcn_mfma_f32_16x16x32_f16(afh[m], bfl[n], acc[m][n], 0, 0, 0);
        acc[m][n] = __builtin_amdgcn_mfma_f32_16x16x32_f16(afh[m], bfh[n], acc[m][n], 0, 0, 0);
      }
  }

  // C/D layout: col = lane&15, row = (lane>>4)*4 + reg
  #pragma unroll
  for (int m=0;m<4;m++){
    #pragma unroll
    for (int j=0;j<4;j++){
      const long crow = (long)(tm*128 + wm*64 + m*16 + fq*4 + j);
      #pragma unroll
      for (int n=0;n<4;n++){
        const int c = tn*128 + wn*64 + n*16 + fr;
        float vv = acc[m][n][j];
        if (EPI == 0) C[crow * N + c] = vv;
        else {
          u16 hh, ll; fsplit(vv, hh, ll);
          Ch[crow * N + c] = hh;
          Cl[crow * N + c] = ll;
        }
      }
    }
  }
}

// ======================= MFMA split-f16 sliding-window attention =======================
// 16 q-rows per block, 4 waves; 2-tile ILP in QK/PE phases; Sj stride 1032 (bank-safe).

#define SJP 1032

__global__ __launch_bounds__(256)
void attn_mfma(const u16* __restrict__ qh, const u16* __restrict__ ql,
               const u16* __restrict__ kh, const u16* __restrict__ kl,
               const u16* __restrict__ vth, const u16* __restrict__ vtl,
               const u16* __restrict__ peh, const u16* __restrict__ pel,
               u16* __restrict__ oh, u16* __restrict__ ol)
{
  __shared__ __align__(16) char smem[68608];
  float* Sj = (float*)smem;                  // [16][SJP] f32
  u16*   Ph = (u16*)smem;                    // [16][1064] u16 (overlay)
  u16*   Pl = (u16*)(smem + 34048);          // [16][1064] u16
  const int q0 = blockIdx.x << 4;
  const int hd = blockIdx.y, b = blockIdx.z;
  const int t = threadIdx.x, lane = t & 63, wid = t >> 6;
  const int fr = lane & 15, fq = lane >> 4;
  const long kbase = (long)b * 2048;

  // Q A-fragments
  f16x8 qfh[2], qfl[2];
  {
    const long qoff = ((long)(b*1024 + q0 + fr))*1024 + hd*64 + fq*8;
    qfh[0] = *(const f16x8*)(qh + qoff);
    qfh[1] = *(const f16x8*)(qh + qoff + 32);
    qfl[0] = *(const f16x8*)(ql + qoff);
    qfl[1] = *(const f16x8*)(ql + qoff + 32);
  }

  // ---- phase A: Sj = Q @ Kwin^T (65 col-tiles; pairs (ta, ta+4) for ILP) ----
  for (int base = 0; base < 65; base += 8){
    const int ta = base + wid;
    const int tb = base + wid + 4;
    const int tac = (ta < 65) ? ta : 64;
    const int tbc = (tb < 65) ? tb : 64;
    const int ca = tac*16 + fr, cb = tbc*16 + fr;
    const long koffA = (kbase + q0 + ca)*1024 + hd*64 + fq*8;
    const long koffB = (kbase + q0 + cb)*1024 + hd*64 + fq*8;
    f32x4 accA = {0.f,0.f,0.f,0.f}, accB = {0.f,0.f,0.f,0.f};
    #pragma unroll
    for (int ks = 0; ks < 2; ++ks){
      f16x8 bhA = *(const f16x8*)(kh + koffA + ks*32);
      f16x8 blA = *(const f16x8*)(kl + koffA + ks*32);
      f16x8 bhB = *(const f16x8*)(kh + koffB + ks*32);
      f16x8 blB = *(const f16x8*)(kl + koffB + ks*32);
      accA = __builtin_amdgcn_mfma_f32_16x16x32_f16(qfl[ks], bhA, accA, 0, 0, 0);
      accB = __builtin_amdgcn_mfma_f32_16x16x32_f16(qfl[ks], bhB, accB, 0, 0, 0);
      accA = __builtin_amdgcn_mfma_f32_16x16x32_f16(qfh[ks], blA, accA, 0, 0, 0);
      accB = __builtin_amdgcn_mfma_f32_16x16x32_f16(qfh[ks], blB, accB, 0, 0, 0);
      accA = __builtin_amdgcn_mfma_f32_16x16x32_f16(qfh[ks], bhA, accA, 0, 0, 0);
      accB = __builtin_amdgcn_mfma_f32_16x16x32_f16(qfh[ks], bhB, accB, 0, 0, 0);
    }
    if (ta < 65){
      #pragma unroll
      for (int jj = 0; jj < 4; ++jj){
        const int row = fq*4 + jj;
        const int j = ca - row;
        if (j >= 0 && j < 1024) Sj[row*SJP + j] = accA[jj];
      }
    }
    if (tb < 65){
      #pragma unroll
      for (int jj = 0; jj < 4; ++jj){
        const int row = fq*4 + jj;
        const int j = cb - row;
        if (j >= 0 && j < 1024) Sj[row*SJP + j] = accB[jj];
      }
    }
  }
  __syncthreads();

  // ---- phase A2: Sj += Q @ PE^T (64 tiles; pairs for ILP; always valid) ----
  for (int base = 0; base < 64; base += 8){
    const int ta = base + wid, tb = base + wid + 4;
    const long poffA = (long)(ta*16 + fr)*64 + fq*8;
    const long poffB = (long)(tb*16 + fr)*64 + fq*8;
    f32x4 accA = {0.f,0.f,0.f,0.f}, accB = {0.f,0.f,0.f,0.f};
    #pragma unroll
    for (int ks = 0; ks < 2; ++ks){
      f16x8 bhA = *(const f16x8*)(peh + poffA + ks*32);
      f16x8 blA = *(const f16x8*)(pel + poffA + ks*32);
      f16x8 bhB = *(const f16x8*)(peh + poffB + ks*32);
      f16x8 blB = *(const f16x8*)(pel + poffB + ks*32);
      accA = __builtin_amdgcn_mfma_f32_16x16x32_f16(qfl[ks], bhA, accA, 0, 0, 0);
      accB = __builtin_amdgcn_mfma_f32_16x16x32_f16(qfl[ks], bhB, accB, 0, 0, 0);
      accA = __builtin_amdgcn_mfma_f32_16x16x32_f16(qfh[ks], blA, accA, 0, 0, 0);
      accB = __builtin_amdgcn_mfma_f32_16x16x32_f16(qfh[ks], blB, accB, 0, 0, 0);
      accA = __builtin_amdgcn_mfma_f32_16x16x32_f16(qfh[ks], bhA, accA, 0, 0, 0);
      accB = __builtin_amdgcn_mfma_f32_16x16x32_f16(qfh[ks], bhB, accB, 0, 0, 0);
    }
    const int ja = ta*16 + fr, jb = tb*16 + fr;
    #pragma unroll
    for (int jj = 0; jj < 4; ++jj){
      const int row = fq*4 + jj;
      Sj[row*SJP + ja] += accA[jj];
      Sj[row*SJP + jb] += accB[jj];
    }
  }
  __syncthreads();

  // ---- softmax: row r = t>>4, lane g = t&15 handles j = g + 16m ----
  {
    const int r = t >> 4, g = t & 15;
    float sv[64];
    float mx = -3.0e38f;
    #pragma unroll
    for (int m = 0; m < 64; ++m){
      float x = Sj[r*SJP + g + (m<<4)] * 0.125f;
      sv[m] = x; mx = fmaxf(mx, x);
    }
    #pragma unroll
    for (int o = 8; o; o >>= 1) mx = fmaxf(mx, __shfl_xor(mx, o, 64));
    float sum = 0.f;
    #pragma unroll
    for (int m = 0; m < 64; ++m){ sv[m] = __expf(sv[m] - mx); sum += sv[m]; }
    #pragma unroll
    for (int o = 8; o; o >>= 1) sum += __shfl_xor(sum, o, 64);
    const float inv = 1.f / sum;
    __syncthreads();                           // Sj fully consumed into registers
    for (int i = t; i < 17024; i += 256) ((unsigned*)smem)[i] = 0;   // zero Ph+Pl
    __syncthreads();
    #pragma unroll
    for (int m = 0; m < 64; ++m){
      float p = sv[m] * inv;
      u16 hh, ll; fsplit(p, hh, ll);
      const int c = r + g + (m<<4);            // band position
      Ph[r*1064 + c] = hh;
      Pl[r*1064 + c] = ll;
    }
  }
  __syncthreads();

  // ---- phase C: PV. wave wid owns d-tile wid (16 d); K-dim = 33x32 over c ----
  {
    f32x4 acc0 = {0.f,0.f,0.f,0.f}, acc1 = {0.f,0.f,0.f,0.f};
    const long vrow = (long)(hd*64 + wid*16 + fr) * 8192 + kbase;
    for (int ks = 0; ks < 33; ++ks){
      int st = q0 + ks*32 + fq*8;
      if (st > 2040) st = 2040;                // clamp (P' zero there)
      f16x8 vh = *(const f16x8*)(vth + vrow + st);
      f16x8 vl = *(const f16x8*)(vtl + vrow + st);
      f16x8 ah = *(const f16x8*)(Ph + fr*1064 + ks*32 + fq*8);
      f16x8 al = *(const f16x8*)(Pl + fr*1064 + ks*32 + fq*8);
      f32x4& a = (ks & 1) ? acc1 : acc0;
      a = __builtin_amdgcn_mfma_f32_16x16x32_f16(al, vh, a, 0, 0, 0);
      a = __builtin_amdgcn_mfma_f32_16x16x32_f16(ah, vl, a, 0, 0, 0);
      a = __builtin_amdgcn_mfma_f32_16x16x32_f16(ah, vh, a, 0, 0, 0);
    }
    #pragma unroll
    for (int jj = 0; jj < 4; ++jj){
      float v = acc0[jj] + acc1[jj];
      u16 hh, ll; fsplit(v, hh, ll);
      const int row = fq*4 + jj;
      const long o = ((long)(b*1024 + q0 + row))*1024 + hd*64 + wid*16 + fr;
      oh[o] = hh; ol[o] = ll;
    }
  }
}

// ======================= MFMA bf16 GEMM for MoE (Bt[N][K] layout) =======================
// linear LDS [128][32] + global_load_lds staging (per-lane gathered sources).

template<bool GATHER, bool RELU>
__global__ __launch_bounds__(256)
void gemm_bt(const u16* __restrict__ A, const u16* __restrict__ Bt, u16* __restrict__ Cp,
             const float* __restrict__ bias, int N, int Kd, int maxA,
             const int* __restrict__ rbase_p, const int* __restrict__ cnt_p,
             const int* __restrict__ gather)
{
  __shared__ __align__(16) u16 As[4096];
  __shared__ __align__(16) u16 Bs[4096];
  const int rbase = rbase_p[0];
  const int cnt   = cnt_p[0];
  const int tm = blockIdx.y, tn = blockIdx.x;
  if (tm * 128 >= cnt) return;

  const int t = threadIdx.x;
  const int lane = t & 63, wv = t >> 6;
  const int wm = wv >> 1, wn = wv & 1;
  const int fr = lane & 15, fq = lane >> 4;

  const int r0l = 32*wv + (lane >> 2);
  const int r1l = r0l + 16;
  const int colu = (lane & 3) << 3;
  auto amap = [&](int rl)->long{
    int r = tm*128 + rl;
    int rc = (r < cnt) ? r : (cnt - 1);
    if (GATHER){
      int gi = rbase + rc; gi = (gi < 0) ? 0 : ((gi > 8191) ? 8191 : gi);
      int tok = gather[gi];
      tok = (tok < 0) ? 0 : ((tok >= maxA) ? (maxA - 1) : tok);
      return (long)tok;
    }
    return (long)rc;
  };
  const long ar0 = amap(r0l), ar1 = amap(r1l);
  const long br0 = (long)(tn*128 + r0l), br1 = (long)(tn*128 + r1l);
  const u16* pa0 = A + ar0*Kd + colu;   const u16* pa1 = A + ar1*Kd + colu;
  const u16* pb0 = Bt + br0*Kd + colu;  const u16* pb1 = Bt + br1*Kd + colu;
  u16* lA0 = As + 1024*wv;  u16* lA1 = lA0 + 512;
  u16* lB0 = Bs + 1024*wv;  u16* lB1 = lB0 + 512;

  f32x4 acc[4][4];
  const f32x4 z4 = {0.f,0.f,0.f,0.f};
  #pragma unroll
  for (int m=0;m<4;m++)
    #pragma unroll
    for (int n=0;n<4;n++) acc[m][n] = z4;

  const int nk = Kd >> 5;
  for (int kt = 0; kt < nk; ++kt) {
    const int ko = kt << 5;
    __syncthreads();
    gll16(pa0 + ko, lA0); gll16(pa1 + ko, lA1);
    gll16(pb0 + ko, lB0); gll16(pb1 + ko, lB1);
    __syncthreads();
    bf16x8 af[4], bfv[4];
    #pragma unroll
    for (int m=0;m<4;m++) af[m]  = *(const bf16x8*)(As + (wm*64 + m*16 + fr)*32 + fq*8);
    #pragma unroll
    for (int n=0;n<4;n++) bfv[n] = *(const bf16x8*)(Bs + (wn*64 + n*16 + fr)*32 + fq*8);
    #pragma unroll
    for (int m=0;m<4;m++)
      #pragma unroll
      for (int n=0;n<4;n++)
        acc[m][n] = __builtin_amdgcn_mfma_f32_16x16x32_bf16(af[m], bfv[n], acc[m][n], 0, 0, 0);
  }

  #pragma unroll
  for (int m=0;m<4;m++){
    #pragma unroll
    for (int j=0;j<4;j++){
      const int r = tm*128 + wm*64 + m*16 + fq*4 + j;
      if (r >= cnt) continue;
      const long crow = GATHER ? (long)r : (long)(rbase + r);
      #pragma unroll
      for (int n=0;n<4;n++){
        const int c = tn*128 + wn*64 + n*16 + fr;
        float vv = acc[m][n][j] + bias[c];
        if (RELU) vv = fmaxf(vv, 0.f);
        Cp[crow * N + c] = f2bf(vv);
      }
    }
  }
}

// ======================= layernorm / gate / moe plumbing =======================

__device__ __forceinline__ void block_reduce2(float& s1, float& s2){
  #pragma unroll
  for (int o = 32; o; o >>= 1){
    s1 += __shfl_xor(s1, o, 64);
    s2 += __shfl_xor(s2, o, 64);
  }
  __shared__ float r1[4], r2[4];
  const int wid = threadIdx.x >> 6;
  if ((threadIdx.x & 63) == 0){ r1[wid] = s1; r2[wid] = s2; }
  __syncthreads();
  s1 = r1[0] + r1[1] + r1[2] + r1[3];
  s2 = r2[0] + r2[1] + r2[2] + r2[3];
  __syncthreads();
}

__global__ __launch_bounds__(256)
void add_ln_kernel(const float* __restrict__ a, const float* __restrict__ r,
                   const float* __restrict__ g, const float* __restrict__ bb,
                   float* __restrict__ of, u16* __restrict__ ob)
{
  const long row = blockIdx.x;
  const int t = threadIdx.x;
  float y[4]; float sum = 0.f, sq = 0.f;
  #pragma unroll
  for (int i = 0; i < 4; ++i){
    const long idx = row*1024 + t + (i<<8);
    float vv = a[idx] + r[idx];
    y[i] = vv; sum += vv; sq += vv*vv;
  }
  block_reduce2(sum, sq);
  const float mu = sum * (1.f/1024.f);
  const float var = fmaxf(sq * (1.f/1024.f) - mu*mu, 0.f);
  const float rs = rsqrtf(var + 1e-5f);
  #pragma unroll
  for (int i = 0; i < 4; ++i){
    const int hcol = t + (i<<8);
    float o = (y[i] - mu) * rs * g[hcol] + bb[hcol];
    of[row*1024 + hcol] = o;
    ob[row*1024 + hcol] = f2bf(o);
  }
}

__global__ __launch_bounds__(256)
void gate_kernel(const float* __restrict__ x, const float* __restrict__ gw,
                 const float* __restrict__ gb, int* __restrict__ eidx,
                 float* __restrict__ esc, int* __restrict__ counts)
{
  const long row = blockIdx.x;
  const int t = threadIdx.x;
  float a[8];
  #pragma unroll
  for (int e=0;e<8;e++) a[e]=0.f;
  for (int hcol = t; hcol < 1024; hcol += 256){
    float xv = x[row*1024 + hcol];
    const float* gr = gw + hcol*8;
    #pragma unroll
    for (int e=0;e<8;e++) a[e] += xv * gr[e];
  }
  #pragma unroll
  for (int e=0;e<8;e++)
    #pragma unroll
    for (int o=32;o;o>>=1) a[e] += __shfl_xor(a[e], o, 64);
  __shared__ float red[4][8];
  const int wid = t >> 6;
  if ((t & 63)==0){
    #pragma unroll
    for (int e=0;e<8;e++) red[wid][e]=a[e];
  }
  __syncthreads();
  if (t == 0){
    float l[8];
    #pragma unroll
    for (int e=0;e<8;e++) l[e] = red[0][e]+red[1][e]+red[2][e]+red[3][e] + gb[e];
    int i0 = 0; float v0 = l[0];
    #pragma unroll
    for (int e=1;e<8;e++) if (l[e] > v0){ v0=l[e]; i0=e; }
    int i1 = -1; float v1 = -3.0e38f;
    #pragma unroll
    for (int e=0;e<8;e++) if (e != i0 && l[e] > v1){ v1=l[e]; i1=e; }
    float e1 = __expf(v1 - v0);
    float den = 1.f + e1;
    eidx[row*2+0]=i0; eidx[row*2+1]=i1;
    esc[row*2+0]=1.f/den; esc[row*2+1]=e1/den;
    atomicAdd(&counts[i0],1); atomicAdd(&counts[i1],1);
  }
}

__global__ void scan_kernel(const int* __restrict__ counts, int* __restrict__ offs,
                            int* __restrict__ curs)
{
  if (threadIdx.x == 0 && blockIdx.x == 0){
    int acc = 0;
    for (int e=0;e<8;e++){ offs[e]=acc; curs[e]=acc; acc += counts[e]; }
  }
}

__global__ __launch_bounds__(256)
void scatter_kernel(const int* __restrict__ eidx, int* __restrict__ curs,
                    int* __restrict__ stok, int* __restrict__ ppos)
{
  int id = blockIdx.x*256 + threadIdx.x;
  if (id >= 8192) return;
  int e = eidx[id];
  e = (e < 0) ? 0 : ((e > 7) ? 7 : e);
  int pos = atomicAdd(&curs[e], 1);
  pos = (pos < 0) ? 0 : ((pos > 8191) ? 8191 : pos);
  stok[pos] = id >> 1;
  ppos[id] = pos;
}

__global__ __launch_bounds__(256)
void moe_combine_ln(const float* __restrict__ h1, const u16* __restrict__ pout,
                    const float* __restrict__ esc, const int* __restrict__ ppos,
                    const float* __restrict__ mg, const float* __restrict__ mb,
                    const float* __restrict__ n2g, const float* __restrict__ n2b,
                    float* __restrict__ outp)
{
  const long row = blockIdx.x;
  const int t = threadIdx.x;
  int p0i = ppos[row*2+0], p1i = ppos[row*2+1];
  p0i = (p0i < 0) ? 0 : ((p0i > 8191) ? 8191 : p0i);
  p1i = (p1i < 0) ? 0 : ((p1i > 8191) ? 8191 : p1i);
  const long p0 = p0i, p1 = p1i;
  const float s0 = esc[row*2+0], s1 = esc[row*2+1];
  float x[4], y[4];
  float sum=0.f, sq=0.f;
  #pragma unroll
  for (int i=0;i<4;i++){
    const int hcol = t + (i<<8);
    const long idx = row*1024 + hcol;
    float xv = h1[idx];
    float m = s0 * bf2f(pout[p0*1024 + hcol]) + s1 * bf2f(pout[p1*1024 + hcol]);
    x[i]=xv; y[i]=xv+m; sum+=y[i]; sq+=y[i]*y[i];
  }
  block_reduce2(sum, sq);
  float mu = sum*(1.f/1024.f), var = fmaxf(sq*(1.f/1024.f)-mu*mu, 0.f), rs = rsqrtf(var+1e-5f);
  float zz[4]; float sum2=0.f, sq2=0.f;
  #pragma unroll
  for (int i=0;i<4;i++){
    const int hcol = t + (i<<8);
    float core = (y[i]-mu)*rs*mg[hcol]+mb[hcol];
    zz[i] = x[i] + core; sum2+=zz[i]; sq2+=zz[i]*zz[i];
  }
  block_reduce2(sum2, sq2);
  float mu2 = sum2*(1.f/1024.f), var2 = fmaxf(sq2*(1.f/1024.f)-mu2*mu2, 0.f), rs2 = rsqrtf(var2+1e-5f);
  #pragma unroll
  for (int i=0;i<4;i++){
    const int hcol = t + (i<<8);
    outp[row*1024 + hcol] = (zz[i]-mu2)*rs2*n2g[hcol]+n2b[hcol];
  }
}

// ======================= launcher =======================
// Workspace (peak 146 MB, proven envelope; metadata at offset 0) — same map as R7.

extern "C" void kernel_launch(void* const* d_in, const int* in_sizes, int n_in,
                              void* d_out, int out_size, void* d_ws, size_t ws_size,
                              hipStream_t stream)
{
  const float* h      = (const float*)d_in[0];
  const float* hc     = (const float*)d_in[1];
  const float* key_pe = (const float*)d_in[2];
  const float* wq     = (const float*)d_in[3];
  const float* wk     = (const float*)d_in[4];
  const float* wv     = (const float*)d_in[5];
  const float* wo     = (const float*)d_in[6];
  const float* n1g    = (const float*)d_in[7];
  const float* n1b    = (const float*)d_in[8];
  const float* n2g    = (const float*)d_in[9];
  const float* n2b    = (const float*)d_in[10];
  const float* mlg    = (const float*)d_in[11];
  const float* mlb    = (const float*)d_in[12];
  const float* gw     = (const float*)d_in[13];
  const float* gb     = (const float*)d_in[14];
  const float* ew1    = (const float*)d_in[15];
  const float* eb1    = (const float*)d_in[16];
  const float* ew2    = (const float*)d_in[17];
  const float* eb2    = (const float*)d_in[18];
  float* outp = (float*)d_out;

  const size_t MB = 1ull << 20;
  char* base = (char*)d_ws;
  int*   counts = (int*)(base);
  int*   offs   = (int*)(base + 256);
  int*   curs   = (int*)(base + 512);
  int*   eidx   = (int*)(base + 1024);
  float* esc    = (float*)(base + 64*1024);
  int*   stok   = (int*)(base + 128*1024);
  int*   ppos   = (int*)(base + 192*1024);
  u16*   peh    = (u16*)(base + 1*MB);
  u16*   pel    = (u16*)(base + 1*MB + 512*1024);
  u16*   hall_h = (u16*)(base + 2*MB);
  u16*   vt_h   = (u16*)(base + 2*MB);      // alias (after V gemm)
  u16*   h1b    = (u16*)(base + 2*MB);      // alias (after attn)
  u16*   w1Te   = (u16*)(base + 10*MB);     // alias (after attn)
  u16*   hall_l = (u16*)(base + 18*MB);
  u16*   vt_l   = (u16*)(base + 18*MB);     // alias (after V gemm)
  u16*   w2Te   = (u16*)(base + 18*MB);     // alias (after attn)
  u16*   pout   = (u16*)(base + 26*MB);     // alias (after attn; spills into dead wq pair)
  u16*   wqT_h  = (u16*)(base + 34*MB);
  u16*   wqT_l  = (u16*)(base + 36*MB);
  u16*   wkT_h  = (u16*)(base + 38*MB);
  u16*   wkT_l  = (u16*)(base + 40*MB);
  u16*   wvT_h  = (u16*)(base + 42*MB);
  u16*   wvT_l  = (u16*)(base + 44*MB);
  u16*   woT_h  = (u16*)(base + 46*MB);
  u16*   woT_l  = (u16*)(base + 48*MB);
  u16*   qh     = (u16*)(base + 50*MB);
  u16*   ql     = (u16*)(base + 58*MB);
  float* aproj  = (float*)(base + 50*MB);   // alias (after attn)
  u16*   kh     = (u16*)(base + 66*MB);
  float* h1     = (float*)(base + 66*MB);   // alias (after attn)
  u16*   kl     = (u16*)(base + 82*MB);
  u16*   xhid   = (u16*)(base + 82*MB);     // alias (after attn/WO; 82..146)
  float* vbuf   = (float*)(base + 98*MB);
  u16*   aout_h = (u16*)(base + 98*MB);     // alias (after V transpose)
  u16*   aout_l = (u16*)(base + 106*MB);

  zero8<<<1, 64, 0, stream>>>(counts);
  dim3 tb32(32, 8);

  // conversions
  cvt_split_hall<<<8192, 256, 0, stream>>>(hc, h, hall_h, hall_l);
  transpose_split<<<dim3(32,2),  tb32, 0, stream>>>(key_pe, peh, pel, 64, 1024);
  transpose_split<<<dim3(32,32), tb32, 0, stream>>>(wq, wqT_h, wqT_l, 1024, 1024);
  transpose_split<<<dim3(32,32), tb32, 0, stream>>>(wk, wkT_h, wkT_l, 1024, 1024);
  transpose_split<<<dim3(32,32), tb32, 0, stream>>>(wv, wvT_h, wvT_l, 1024, 1024);
  transpose_split<<<dim3(32,32), tb32, 0, stream>>>(wo, woT_h, woT_l, 1024, 1024);

  // QKV projections (split-f16 MFMA, f32-exact); Q/K emit split pairs, V emits f32
  gemm_sp<1,1><<<dim3(8,32), 256, 0, stream>>>(hall_h, hall_l, wqT_h, wqT_l, nullptr, qh, ql, 1024, 1024);
  gemm_sp<0,1><<<dim3(8,64), 256, 0, stream>>>(hall_h, hall_l, wkT_h, wkT_l, nullptr, kh, kl, 1024, 1024);
  gemm_sp<0,0><<<dim3(8,64), 256, 0, stream>>>(hall_h, hall_l, wvT_h, wvT_l, vbuf, nullptr, nullptr, 1024, 1024);

  // V^T split pair [1024 d][8192 keys] (hall region dead now)
  transpose_split<<<dim3(32,256), tb32, 0, stream>>>(vbuf, vt_h, vt_l, 8192, 1024);

  // MFMA attention (outputs split pair over dead vbuf)
  attn_mfma<<<dim3(64,16,4), 256, 0, stream>>>(qh, ql, kh, kl, vt_h, vt_l, peh, pel, aout_h, aout_l);

  // WO projection + residual LN
  gemm_sp<0,0><<<dim3(8,32), 256, 0, stream>>>(aout_h, aout_l, woT_h, woT_l, aproj, nullptr, nullptr, 1024, 1024);
  add_ln_kernel<<<4096, 256, 0, stream>>>(h, aproj, n1g, n1b, h1, h1b);

  // MoE gate + bucketing (f32 — exact top-2 vs reference)
  gate_kernel<<<4096, 256, 0, stream>>>(h1, gw, gb, eidx, esc, counts);
  scan_kernel<<<1, 64, 0, stream>>>(counts, offs, curs);
  scatter_kernel<<<32, 256, 0, stream>>>(eidx, curs, stok, ppos);

  // per-expert FFN: bf16 MFMA (downstream of gate; threshold-safe)
  for (int e = 0; e < 8; ++e){
    transpose_cvt<<<dim3(128,32), tb32, 0, stream>>>(ew1 + (long)e*1024*4096, w1Te, 1024, 4096);
    transpose_cvt<<<dim3(32,128), tb32, 0, stream>>>(ew2 + (long)e*4096*1024, w2Te, 4096, 1024);
    gemm_bt<true,  true ><<<dim3(32,64), 256, 0, stream>>>(h1b,  w1Te, xhid, eb1 + (long)e*4096,
                                                           4096, 1024, 4096, offs + e, counts + e, stok);
    gemm_bt<false, false><<<dim3(8,64),  256, 0, stream>>>(xhid, w2Te, pout, eb2 + (long)e*1024,
                                                           1024, 4096, 8192, offs + e, counts + e, nullptr);
  }

  // combine + the two trailing layernorms
  moe_combine_ln<<<4096, 256, 0, stream>>>(h1, pout, esc, ppos, mlg, mlb, n2g, n2b, outp);
}

// Round 9
// 1638.882 us; speedup vs baseline: 4.3811x; 1.1543x over previous
//
#include <hip/hip_runtime.h>

typedef unsigned short u16;
typedef unsigned int u32;
typedef __attribute__((ext_vector_type(8))) __bf16 bf16x8;
typedef __attribute__((ext_vector_type(8))) _Float16 f16x8;
typedef __attribute__((ext_vector_type(4))) float f32x4;

__device__ __forceinline__ u16 f2bf(float f){
  unsigned int u = __float_as_uint(f);
  u += 0x7FFFu + ((u >> 16) & 1u);     // RNE
  return (u16)(u >> 16);
}
__device__ __forceinline__ float bf2f(u16 s){
  return __uint_as_float(((unsigned int)s) << 16);
}
// split-f16: x = hi + lo with |x - hi - lo| <= 2^-24 |x|
__device__ __forceinline__ void fsplit(float x, u16& hi, u16& lo){
  _Float16 h = (_Float16)x;
  float r = x - (float)h;
  _Float16 l = (_Float16)r;
  hi = *(u16*)&h; lo = *(u16*)&l;
}
// async global->LDS, 16B per lane (wave-uniform LDS base; HW adds lane*16)
__device__ __forceinline__ void gll16(const u16* g, u16* lds){
  __builtin_amdgcn_global_load_lds(
      (const __attribute__((address_space(1))) u32*)g,
      (__attribute__((address_space(3))) u32*)(u32)(unsigned long long)lds,
      16, 0, 0);
}

// ======================= small utility kernels =======================

__global__ void zero8(int* c){ if (threadIdx.x < 8) c[threadIdx.x] = 0; }

// z-batched transpose + convert: in [Z][R][C] f32 -> out [Z][C][R] bf16
__global__ __launch_bounds__(256)
void transpose_cvt_z(const float* __restrict__ in, u16* __restrict__ outp,
                     int R, int C, long zin, long zout)
{
  __shared__ float tile[32][33];
  in  += (long)blockIdx.z * zin;
  outp+= (long)blockIdx.z * zout;
  const int c0 = blockIdx.x << 5, r0 = blockIdx.y << 5;
  const int tx = threadIdx.x, ty = threadIdx.y;
  #pragma unroll
  for (int i = ty; i < 32; i += 8)
    tile[i][tx] = in[(long)(r0 + i) * C + c0 + tx];
  __syncthreads();
  #pragma unroll
  for (int i = ty; i < 32; i += 8)
    outp[(long)(c0 + i) * R + r0 + tx] = f2bf(tile[tx][i]);
}

// transpose + split-f16: in [R][C] f32 -> outh/outl [C][R] f16
__global__ __launch_bounds__(256)
void transpose_split(const float* __restrict__ in, u16* __restrict__ oh, u16* __restrict__ ol,
                     int R, int C)
{
  __shared__ float tile[32][33];
  const int c0 = blockIdx.x << 5, r0 = blockIdx.y << 5;
  const int tx = threadIdx.x, ty = threadIdx.y;
  #pragma unroll
  for (int i = ty; i < 32; i += 8)
    tile[i][tx] = in[(long)(r0 + i) * C + c0 + tx];
  __syncthreads();
  #pragma unroll
  for (int i = ty; i < 32; i += 8){
    u16 hh, ll;
    fsplit(tile[tx][i], hh, ll);
    oh[(long)(c0 + i) * R + r0 + tx] = hh;
    ol[(long)(c0 + i) * R + r0 + tx] = ll;
  }
}

// h_all = concat(hc, h) per batch -> split-f16 pair [8192][1024]
__global__ __launch_bounds__(256)
void cvt_split_hall(const float* __restrict__ hc, const float* __restrict__ h,
                    u16* __restrict__ hi, u16* __restrict__ lo)
{
  long i4 = (long)blockIdx.x * 256 + threadIdx.x;
  long row = i4 >> 8;
  int c4 = (int)(i4 & 255);
  int b = (int)(row >> 11), tt = (int)(row & 2047);
  const float4* src = (const float4*)((tt < 1024) ? (hc + ((long)b*1024 + tt)*1024)
                                                  : (h  + ((long)b*1024 + (tt-1024))*1024));
  float4 v = src[c4];
  ushort4 h4, l4;
  fsplit(v.x, h4.x, l4.x); fsplit(v.y, h4.y, l4.y);
  fsplit(v.z, h4.z, l4.z); fsplit(v.w, h4.w, l4.w);
  ((ushort4*)hi)[i4] = h4;
  ((ushort4*)lo)[i4] = l4;
}

// ======================= split-f16 emulated-f32 MFMA GEMM =======================
// 128x128 tile, BK=32, linear LDS [128][32], global_load_lds staging.
// AMAP 1: A row r -> h_all row (r>>10)*2048 + 1024 + (r&1023)   (Q projection)
// EPI 0: C f32;  EPI 1: C as split-f16 pair (Ch, Cl)

template<int AMAP, int EPI>
__global__ __launch_bounds__(256)
void gemm_sp(const u16* __restrict__ Ah_, const u16* __restrict__ Al_,
             const u16* __restrict__ Bh_, const u16* __restrict__ Bl_,
             float* __restrict__ C, u16* __restrict__ Ch, u16* __restrict__ Cl,
             int N, int Kd)
{
  __shared__ __align__(16) u16 Ahs[4096];
  __shared__ __align__(16) u16 Als[4096];
  __shared__ __align__(16) u16 Bhs[4096];
  __shared__ __align__(16) u16 Bls[4096];
  const int tm = blockIdx.y, tn = blockIdx.x;
  const int t = threadIdx.x;
  const int lane = t & 63, wv = t >> 6;
  const int wm = wv >> 1, wn = wv & 1;
  const int fr = lane & 15, fq = lane >> 4;

  const int r0l = 32*wv + (lane >> 2);
  const int r1l = r0l + 16;
  const int colu = (lane & 3) << 3;
  auto amap = [](int r)->long{
    if (AMAP == 1){ int b = r >> 10, tt = r & 1023; return (long)b*2048 + 1024 + tt; }
    return (long)r;
  };
  const long ar0 = amap(tm*128 + r0l), ar1 = amap(tm*128 + r1l);
  const long br0 = (long)(tn*128 + r0l), br1 = (long)(tn*128 + r1l);
  const u16* pah0 = Ah_ + ar0*Kd + colu;  const u16* pah1 = Ah_ + ar1*Kd + colu;
  const u16* pal0 = Al_ + ar0*Kd + colu;  const u16* pal1 = Al_ + ar1*Kd + colu;
  const u16* pbh0 = Bh_ + br0*Kd + colu;  const u16* pbh1 = Bh_ + br1*Kd + colu;
  const u16* pbl0 = Bl_ + br0*Kd + colu;  const u16* pbl1 = Bl_ + br1*Kd + colu;
  u16* lAh0 = Ahs + 1024*wv;  u16* lAh1 = lAh0 + 512;
  u16* lAl0 = Als + 1024*wv;  u16* lAl1 = lAl0 + 512;
  u16* lBh0 = Bhs + 1024*wv;  u16* lBh1 = lBh0 + 512;
  u16* lBl0 = Bls + 1024*wv;  u16* lBl1 = lBl0 + 512;

  f32x4 acc[4][4];
  const f32x4 z4 = {0.f,0.f,0.f,0.f};
  #pragma unroll
  for (int m=0;m<4;m++)
    #pragma unroll
    for (int n=0;n<4;n++) acc[m][n] = z4;

  const int nk = Kd >> 5;
  for (int kt = 0; kt < nk; ++kt) {
    const int ko = kt << 5;
    __syncthreads();
    gll16(pah0 + ko, lAh0); gll16(pah1 + ko, lAh1);
    gll16(pal0 + ko, lAl0); gll16(pal1 + ko, lAl1);
    gll16(pbh0 + ko, lBh0); gll16(pbh1 + ko, lBh1);
    gll16(pbl0 + ko, lBl0); gll16(pbl1 + ko, lBl1);
    __syncthreads();
    f16x8 afh[4], afl[4], bfh[4], bfl[4];
    #pragma unroll
    for (int m=0;m<4;m++){
      afh[m] = *(const f16x8*)(Ahs + (wm*64 + m*16 + fr)*32 + fq*8);
      afl[m] = *(const f16x8*)(Als + (wm*64 + m*16 + fr)*32 + fq*8);
    }
    #pragma unroll
    for (int n=0;n<4;n++){
      bfh[n] = *(const f16x8*)(Bhs + (wn*64 + n*16 + fr)*32 + fq*8);
      bfl[n] = *(const f16x8*)(Bls + (wn*64 + n*16 + fr)*32 + fq*8);
    }
    #pragma unroll
    for (int m=0;m<4;m++)
      #pragma unroll
      for (int n=0;n<4;n++){
        acc[m][n] = __builtin_amdgcn_mfma_f32_16x16x32_f16(afl[m], bfh[n], acc[m][n], 0, 0, 0);
        acc[m][n] = __builtin_amdgcn_mfma_f32_16x16x32_f16(afh[m], bfl[n], acc[m][n], 0, 0, 0);
        acc[m][n] = __builtin_amdgcn_mfma_f32_16x16x32_f16(afh[m], bfh[n], acc[m][n], 0, 0, 0);
      }
  }

  // C/D layout: col = lane&15, row = (lane>>4)*4 + reg
  #pragma unroll
  for (int m=0;m<4;m++){
    #pragma unroll
    for (int j=0;j<4;j++){
      const long crow = (long)(tm*128 + wm*64 + m*16 + fq*4 + j);
      #pragma unroll
      for (int n=0;n<4;n++){
        const int c = tn*128 + wn*64 + n*16 + fr;
        float vv = acc[m][n][j];
        if (EPI == 0) C[crow * N + c] = vv;
        else {
          u16 hh, ll; fsplit(vv, hh, ll);
          Ch[crow * N + c] = hh;
          Cl[crow * N + c] = ll;
        }
      }
    }
  }
}

// ======================= MFMA split-f16 sliding-window attention =======================
// 8 q-rows per block (34.3 KB LDS -> 4 blocks/CU), 4 waves, 2-tile ILP.
// MFMA A-rows 8..15 compute garbage (masked at every write; rows never cross-contaminate).

#define SJP 1032

__global__ __launch_bounds__(256)
void attn_mfma(const u16* __restrict__ qh, const u16* __restrict__ ql,
               const u16* __restrict__ kh, const u16* __restrict__ kl,
               const u16* __restrict__ vth, const u16* __restrict__ vtl,
               const u16* __restrict__ peh, const u16* __restrict__ pel,
               u16* __restrict__ oh, u16* __restrict__ ol)
{
  __shared__ __align__(16) char smem[34304];
  float* Sj = (float*)smem;                  // [8][SJP] f32
  u16*   Ph = (u16*)smem;                    // [8][1064] u16 (overlay)
  u16*   Pl = (u16*)(smem + 17024);          // [8][1064] u16
  const int q0 = blockIdx.x << 3;
  const int hd = blockIdx.y, b = blockIdx.z;
  const int t = threadIdx.x, lane = t & 63, wid = t >> 6;
  const int fr = lane & 15, fq = lane >> 4;
  const long kbase = (long)b * 2048;

  // Q A-fragments (rows 8..15 read adjacent mapped ws -> garbage, discarded)
  f16x8 qfh[2], qfl[2];
  {
    const long qoff = ((long)(b*1024 + q0 + fr))*1024 + hd*64 + fq*8;
    qfh[0] = *(const f16x8*)(qh + qoff);
    qfh[1] = *(const f16x8*)(qh + qoff + 32);
    qfl[0] = *(const f16x8*)(ql + qoff);
    qfl[1] = *(const f16x8*)(ql + qoff + 32);
  }

  // ---- phase A: Sj = Q @ Kwin^T (65 col-tiles; pairs (ta, ta+4) for ILP) ----
  for (int base = 0; base < 65; base += 8){
    const int ta = base + wid;
    const int tb = base + wid + 4;
    const int tac = (ta < 65) ? ta : 64;
    const int tbc = (tb < 65) ? tb : 64;
    const int ca = tac*16 + fr, cb = tbc*16 + fr;
    const long koffA = (kbase + q0 + ca)*1024 + hd*64 + fq*8;
    const long koffB = (kbase + q0 + cb)*1024 + hd*64 + fq*8;
    f32x4 accA = {0.f,0.f,0.f,0.f}, accB = {0.f,0.f,0.f,0.f};
    #pragma unroll
    for (int ks = 0; ks < 2; ++ks){
      f16x8 bhA = *(const f16x8*)(kh + koffA + ks*32);
      f16x8 blA = *(const f16x8*)(kl + koffA + ks*32);
      f16x8 bhB = *(const f16x8*)(kh + koffB + ks*32);
      f16x8 blB = *(const f16x8*)(kl + koffB + ks*32);
      accA = __builtin_amdgcn_mfma_f32_16x16x32_f16(qfl[ks], bhA, accA, 0, 0, 0);
      accB = __builtin_amdgcn_mfma_f32_16x16x32_f16(qfl[ks], bhB, accB, 0, 0, 0);
      accA = __builtin_amdgcn_mfma_f32_16x16x32_f16(qfh[ks], blA, accA, 0, 0, 0);
      accB = __builtin_amdgcn_mfma_f32_16x16x32_f16(qfh[ks], blB, accB, 0, 0, 0);
      accA = __builtin_amdgcn_mfma_f32_16x16x32_f16(qfh[ks], bhA, accA, 0, 0, 0);
      accB = __builtin_amdgcn_mfma_f32_16x16x32_f16(qfh[ks], bhB, accB, 0, 0, 0);
    }
    if (ta < 65){
      #pragma unroll
      for (int jj = 0; jj < 4; ++jj){
        const int row = fq*4 + jj;
        const int j = ca - row;
        if (row < 8 && j >= 0 && j < 1024) Sj[row*SJP + j] = accA[jj];
      }
    }
    if (tb < 65){
      #pragma unroll
      for (int jj = 0; jj < 4; ++jj){
        const int row = fq*4 + jj;
        const int j = cb - row;
        if (row < 8 && j >= 0 && j < 1024) Sj[row*SJP + j] = accB[jj];
      }
    }
  }
  __syncthreads();

  // ---- phase A2: Sj += Q @ PE^T (64 tiles; pairs for ILP) ----
  for (int base = 0; base < 64; base += 8){
    const int ta = base + wid, tb = base + wid + 4;
    const long poffA = (long)(ta*16 + fr)*64 + fq*8;
    const long poffB = (long)(tb*16 + fr)*64 + fq*8;
    f32x4 accA = {0.f,0.f,0.f,0.f}, accB = {0.f,0.f,0.f,0.f};
    #pragma unroll
    for (int ks = 0; ks < 2; ++ks){
      f16x8 bhA = *(const f16x8*)(peh + poffA + ks*32);
      f16x8 blA = *(const f16x8*)(pel + poffA + ks*32);
      f16x8 bhB = *(const f16x8*)(peh + poffB + ks*32);
      f16x8 blB = *(const f16x8*)(pel + poffB + ks*32);
      accA = __builtin_amdgcn_mfma_f32_16x16x32_f16(qfl[ks], bhA, accA, 0, 0, 0);
      accB = __builtin_amdgcn_mfma_f32_16x16x32_f16(qfl[ks], bhB, accB, 0, 0, 0);
      accA = __builtin_amdgcn_mfma_f32_16x16x32_f16(qfh[ks], blA, accA, 0, 0, 0);
      accB = __builtin_amdgcn_mfma_f32_16x16x32_f16(qfh[ks], blB, accB, 0, 0, 0);
      accA = __builtin_amdgcn_mfma_f32_16x16x32_f16(qfh[ks], bhA, accA, 0, 0, 0);
      accB = __builtin_amdgcn_mfma_f32_16x16x32_f16(qfh[ks], bhB, accB, 0, 0, 0);
    }
    const int ja = ta*16 + fr, jb = tb*16 + fr;
    #pragma unroll
    for (int jj = 0; jj < 4; ++jj){
      const int row = fq*4 + jj;
      if (row < 8){
        Sj[row*SJP + ja] += accA[jj];
        Sj[row*SJP + jb] += accB[jj];
      }
    }
  }
  __syncthreads();

  // ---- softmax: lanes with r = t>>4 < 8 active; lane g = t&15 handles j = g + 16m ----
  {
    const int r = t >> 4, g = t & 15;
    const bool act = (r < 8);
    float sv[64];
    float inv = 0.f, mx = -3.0e38f;
    if (act){
      #pragma unroll
      for (int m = 0; m < 64; ++m){
        float x = Sj[r*SJP + g + (m<<4)] * 0.125f;
        sv[m] = x; mx = fmaxf(mx, x);
      }
      #pragma unroll
      for (int o = 8; o; o >>= 1) mx = fmaxf(mx, __shfl_xor(mx, o, 64));
      float sum = 0.f;
      #pragma unroll
      for (int m = 0; m < 64; ++m){ sv[m] = __expf(sv[m] - mx); sum += sv[m]; }
      #pragma unroll
      for (int o = 8; o; o >>= 1) sum += __shfl_xor(sum, o, 64);
      inv = 1.f / sum;
    }
    __syncthreads();                           // Sj fully consumed into registers
    for (int i = t; i < 8512; i += 256) ((unsigned*)smem)[i] = 0;   // zero Ph+Pl
    __syncthreads();
    if (act){
      #pragma unroll
      for (int m = 0; m < 64; ++m){
        float p = sv[m] * inv;
        u16 hh, ll; fsplit(p, hh, ll);
        const int c = r + g + (m<<4);          // band position (<= 1030)
        Ph[r*1064 + c] = hh;
        Pl[r*1064 + c] = ll;
      }
    }
  }
  __syncthreads();

  // ---- phase C: PV. wave wid owns d-tile wid (16 d); K-dim = 33x32 over c ----
  {
    f32x4 acc0 = {0.f,0.f,0.f,0.f}, acc1 = {0.f,0.f,0.f,0.f};
    const int pr = fr & 7;                     // A rows 8..15 duplicate 0..7 (discarded)
    const long vrow = (long)(hd*64 + wid*16 + fr) * 8192 + kbase;
    for (int ks = 0; ks < 33; ++ks){
      int st = q0 + ks*32 + fq*8;
      if (st > 2040) st = 2040;                // clamp (P' zero there)
      f16x8 vh = *(const f16x8*)(vth + vrow + st);
      f16x8 vl = *(const f16x8*)(vtl + vrow + st);
      f16x8 ah = *(const f16x8*)(Ph + pr*1064 + ks*32 + fq*8);
      f16x8 al = *(const f16x8*)(Pl + pr*1064 + ks*32 + fq*8);
      f32x4& a = (ks & 1) ? acc1 : acc0;
      a = __builtin_amdgcn_mfma_f32_16x16x32_f16(al, vh, a, 0, 0, 0);
      a = __builtin_amdgcn_mfma_f32_16x16x32_f16(ah, vl, a, 0, 0, 0);
      a = __builtin_amdgcn_mfma_f32_16x16x32_f16(ah, vh, a, 0, 0, 0);
    }
    #pragma unroll
    for (int jj = 0; jj < 4; ++jj){
      const int row = fq*4 + jj;
      if (row < 8){
        float v = acc0[jj] + acc1[jj];
        u16 hh, ll; fsplit(v, hh, ll);
        const long o = ((long)(b*1024 + q0 + row))*1024 + hd*64 + wid*16 + fr;
        oh[o] = hh; ol[o] = ll;
      }
    }
  }
}

// ======================= MFMA bf16 GEMM for MoE (z-batched experts) =======================
// Bt holds a GROUP of experts [z][N][K]; e = ebase + blockIdx.z; rows are GLOBAL slots.

template<bool GATHER, bool RELU>
__global__ __launch_bounds__(256)
void gemm_bt(const u16* __restrict__ A, const u16* __restrict__ Bt, u16* __restrict__ Cp,
             const float* __restrict__ bias, int N, int Kd, int maxA,
             const int* __restrict__ offs, const int* __restrict__ counts,
             const int* __restrict__ gather, int ebase)
{
  __shared__ __align__(16) u16 As[4096];
  __shared__ __align__(16) u16 Bs[4096];
  const int z = blockIdx.z;
  const int e = ebase + z;
  const int rbase = offs[e];
  const int cnt   = counts[e];
  const int tm = blockIdx.y, tn = blockIdx.x;
  if (tm * 128 >= cnt) return;
  const u16* BtE = Bt + (long)z * N * Kd;
  const float* biasE = bias + (long)e * N;

  const int t = threadIdx.x;
  const int lane = t & 63, wv = t >> 6;
  const int wm = wv >> 1, wn = wv & 1;
  const int fr = lane & 15, fq = lane >> 4;

  const int r0l = 32*wv + (lane >> 2);
  const int r1l = r0l + 16;
  const int colu = (lane & 3) << 3;
  auto amap = [&](int rl)->long{
    int r = tm*128 + rl;
    int rc = (r < cnt) ? r : (cnt - 1);
    if (GATHER){
      int gi = rbase + rc; gi = (gi < 0) ? 0 : ((gi > 8191) ? 8191 : gi);
      int tok = gather[gi];
      tok = (tok < 0) ? 0 : ((tok >= maxA) ? (maxA - 1) : tok);
      return (long)tok;
    }
    return (long)(rbase + rc);           // global slot (xhid)
  };
  const long ar0 = amap(r0l), ar1 = amap(r1l);
  const long br0 = (long)(tn*128 + r0l), br1 = (long)(tn*128 + r1l);
  const u16* pa0 = A + ar0*Kd + colu;    const u16* pa1 = A + ar1*Kd + colu;
  const u16* pb0 = BtE + br0*Kd + colu;  const u16* pb1 = BtE + br1*Kd + colu;
  u16* lA0 = As + 1024*wv;  u16* lA1 = lA0 + 512;
  u16* lB0 = Bs + 1024*wv;  u16* lB1 = lB0 + 512;

  f32x4 acc[4][4];
  const f32x4 z4 = {0.f,0.f,0.f,0.f};
  #pragma unroll
  for (int m=0;m<4;m++)
    #pragma unroll
    for (int n=0;n<4;n++) acc[m][n] = z4;

  const int nk = Kd >> 5;
  for (int kt = 0; kt < nk; ++kt) {
    const int ko = kt << 5;
    __syncthreads();
    gll16(pa0 + ko, lA0); gll16(pa1 + ko, lA1);
    gll16(pb0 + ko, lB0); gll16(pb1 + ko, lB1);
    __syncthreads();
    bf16x8 af[4], bfv[4];
    #pragma unroll
    for (int m=0;m<4;m++) af[m]  = *(const bf16x8*)(As + (wm*64 + m*16 + fr)*32 + fq*8);
    #pragma unroll
    for (int n=0;n<4;n++) bfv[n] = *(const bf16x8*)(Bs + (wn*64 + n*16 + fr)*32 + fq*8);
    #pragma unroll
    for (int m=0;m<4;m++)
      #pragma unroll
      for (int n=0;n<4;n++)
        acc[m][n] = __builtin_amdgcn_mfma_f32_16x16x32_bf16(af[m], bfv[n], acc[m][n], 0, 0, 0);
  }

  #pragma unroll
  for (int m=0;m<4;m++){
    #pragma unroll
    for (int j=0;j<4;j++){
      const int r = tm*128 + wm*64 + m*16 + fq*4 + j;
      if (r >= cnt) continue;
      const long crow = (long)(rbase + r);   // global slot
      #pragma unroll
      for (int n=0;n<4;n++){
        const int c = tn*128 + wn*64 + n*16 + fr;
        float vv = acc[m][n][j] + biasE[c];
        if (RELU) vv = fmaxf(vv, 0.f);
        Cp[crow * N + c] = f2bf(vv);
      }
    }
  }
}

// ======================= layernorm / gate / moe plumbing =======================

__device__ __forceinline__ void block_reduce2(float& s1, float& s2){
  #pragma unroll
  for (int o = 32; o; o >>= 1){
    s1 += __shfl_xor(s1, o, 64);
    s2 += __shfl_xor(s2, o, 64);
  }
  __shared__ float r1[4], r2[4];
  const int wid = threadIdx.x >> 6;
  if ((threadIdx.x & 63) == 0){ r1[wid] = s1; r2[wid] = s2; }
  __syncthreads();
  s1 = r1[0] + r1[1] + r1[2] + r1[3];
  s2 = r2[0] + r2[1] + r2[2] + r2[3];
  __syncthreads();
}

__global__ __launch_bounds__(256)
void add_ln_kernel(const float* __restrict__ a, const float* __restrict__ r,
                   const float* __restrict__ g, const float* __restrict__ bb,
                   float* __restrict__ of, u16* __restrict__ ob)
{
  const long row = blockIdx.x;
  const int t = threadIdx.x;
  float y[4]; float sum = 0.f, sq = 0.f;
  #pragma unroll
  for (int i = 0; i < 4; ++i){
    const long idx = row*1024 + t + (i<<8);
    float vv = a[idx] + r[idx];
    y[i] = vv; sum += vv; sq += vv*vv;
  }
  block_reduce2(sum, sq);
  const float mu = sum * (1.f/1024.f);
  const float var = fmaxf(sq * (1.f/1024.f) - mu*mu, 0.f);
  const float rs = rsqrtf(var + 1e-5f);
  #pragma unroll
  for (int i = 0; i < 4; ++i){
    const int hcol = t + (i<<8);
    float o = (y[i] - mu) * rs * g[hcol] + bb[hcol];
    of[row*1024 + hcol] = o;
    ob[row*1024 + hcol] = f2bf(o);
  }
}

__global__ __launch_bounds__(256)
void gate_kernel(const float* __restrict__ x, const float* __restrict__ gw,
                 const float* __restrict__ gb, int* __restrict__ eidx,
                 float* __restrict__ esc, int* __restrict__ counts)
{
  const long row = blockIdx.x;
  const int t = threadIdx.x;
  float a[8];
  #pragma unroll
  for (int e=0;e<8;e++) a[e]=0.f;
  for (int hcol = t; hcol < 1024; hcol += 256){
    float xv = x[row*1024 + hcol];
    const float* gr = gw + hcol*8;
    #pragma unroll
    for (int e=0;e<8;e++) a[e] += xv * gr[e];
  }
  #pragma unroll
  for (int e=0;e<8;e++)
    #pragma unroll
    for (int o=32;o;o>>=1) a[e] += __shfl_xor(a[e], o, 64);
  __shared__ float red[4][8];
  const int wid = t >> 6;
  if ((t & 63)==0){
    #pragma unroll
    for (int e=0;e<8;e++) red[wid][e]=a[e];
  }
  __syncthreads();
  if (t == 0){
    float l[8];
    #pragma unroll
    for (int e=0;e<8;e++) l[e] = red[0][e]+red[1][e]+red[2][e]+red[3][e] + gb[e];
    int i0 = 0; float v0 = l[0];
    #pragma unroll
    for (int e=1;e<8;e++) if (l[e] > v0){ v0=l[e]; i0=e; }
    int i1 = -1; float v1 = -3.0e38f;
    #pragma unroll
    for (int e=0;e<8;e++) if (e != i0 && l[e] > v1){ v1=l[e]; i1=e; }
    float e1 = __expf(v1 - v0);
    float den = 1.f + e1;
    eidx[row*2+0]=i0; eidx[row*2+1]=i1;
    esc[row*2+0]=1.f/den; esc[row*2+1]=e1/den;
    atomicAdd(&counts[i0],1); atomicAdd(&counts[i1],1);
  }
}

__global__ void scan_kernel(const int* __restrict__ counts, int* __restrict__ offs,
                            int* __restrict__ curs)
{
  if (threadIdx.x == 0 && blockIdx.x == 0){
    int acc = 0;
    for (int e=0;e<8;e++){ offs[e]=acc; curs[e]=acc; acc += counts[e]; }
  }
}

__global__ __launch_bounds__(256)
void scatter_kernel(const int* __restrict__ eidx, int* __restrict__ curs,
                    int* __restrict__ stok, int* __restrict__ ppos)
{
  int id = blockIdx.x*256 + threadIdx.x;
  if (id >= 8192) return;
  int e = eidx[id];
  e = (e < 0) ? 0 : ((e > 7) ? 7 : e);
  int pos = atomicAdd(&curs[e], 1);
  pos = (pos < 0) ? 0 : ((pos > 8191) ? 8191 : pos);
  stok[pos] = id >> 1;
  ppos[id] = pos;
}

__global__ __launch_bounds__(256)
void moe_combine_ln(const float* __restrict__ h1, const u16* __restrict__ pout,
                    const float* __restrict__ esc, const int* __restrict__ ppos,
                    const float* __restrict__ mg, const float* __restrict__ mb,
                    const float* __restrict__ n2g, const float* __restrict__ n2b,
                    float* __restrict__ outp)
{
  const long row = blockIdx.x;
  const int t = threadIdx.x;
  int p0i = ppos[row*2+0], p1i = ppos[row*2+1];
  p0i = (p0i < 0) ? 0 : ((p0i > 8191) ? 8191 : p0i);
  p1i = (p1i < 0) ? 0 : ((p1i > 8191) ? 8191 : p1i);
  const long p0 = p0i, p1 = p1i;
  const float s0 = esc[row*2+0], s1 = esc[row*2+1];
  float x[4], y[4];
  float sum=0.f, sq=0.f;
  #pragma unroll
  for (int i=0;i<4;i++){
    const int hcol = t + (i<<8);
    const long idx = row*1024 + hcol;
    float xv = h1[idx];
    float m = s0 * bf2f(pout[p0*1024 + hcol]) + s1 * bf2f(pout[p1*1024 + hcol]);
    x[i]=xv; y[i]=xv+m; sum+=y[i]; sq+=y[i]*y[i];
  }
  block_reduce2(sum, sq);
  float mu = sum*(1.f/1024.f), var = fmaxf(sq*(1.f/1024.f)-mu*mu, 0.f), rs = rsqrtf(var+1e-5f);
  float zz[4]; float sum2=0.f, sq2=0.f;
  #pragma unroll
  for (int i=0;i<4;i++){
    const int hcol = t + (i<<8);
    float core = (y[i]-mu)*rs*mg[hcol]+mb[hcol];
    zz[i] = x[i] + core; sum2+=zz[i]; sq2+=zz[i]*zz[i];
  }
  block_reduce2(sum2, sq2);
  float mu2 = sum2*(1.f/1024.f), var2 = fmaxf(sq2*(1.f/1024.f)-mu2*mu2, 0.f), rs2 = rsqrtf(var2+1e-5f);
  #pragma unroll
  for (int i=0;i<4;i++){
    const int hcol = t + (i<<8);
    outp[row*1024 + hcol] = (zz[i]-mu2)*rs2*n2g[hcol]+n2b[hcol];
  }
}

// ======================= launcher =======================
// Workspace (peak 146 MB, proven envelope; metadata at offset 0):
//  0..1    : metadata     1..2 : peh/pel
//  2..18   : hall_h  -> vt_h (after V gemm) -> h1b 2..10 (after attn) -> pout 2..18 (after MoE gemm1)
//  18..34  : hall_l  -> vt_l (after V gemm)
//  34..50  : wqT/wkT/wvT/woT h+l pairs -> wTg group weights 34..66 (after add_ln)
//  50..66  : qh/ql   -> aproj f32 (after attn)
//  66..82  : kh      -> h1 f32 (after attn)
//  82..98  : kl      -> xhid 82..146 (after attn/WO)
//  98..130 : vbuf f32 -> aout_h 98..106, aout_l 106..114 (after V transpose)

extern "C" void kernel_launch(void* const* d_in, const int* in_sizes, int n_in,
                              void* d_out, int out_size, void* d_ws, size_t ws_size,
                              hipStream_t stream)
{
  const float* h      = (const float*)d_in[0];
  const float* hc     = (const float*)d_in[1];
  const float* key_pe = (const float*)d_in[2];
  const float* wq     = (const float*)d_in[3];
  const float* wk     = (const float*)d_in[4];
  const float* wv     = (const float*)d_in[5];
  const float* wo     = (const float*)d_in[6];
  const float* n1g    = (const float*)d_in[7];
  const float* n1b    = (const float*)d_in[8];
  const float* n2g    = (const float*)d_in[9];
  const float* n2b    = (const float*)d_in[10];
  const float* mlg    = (const float*)d_in[11];
  const float* mlb    = (const float*)d_in[12];
  const float* gw     = (const float*)d_in[13];
  const float* gb     = (const float*)d_in[14];
  const float* ew1    = (const float*)d_in[15];
  const float* eb1    = (const float*)d_in[16];
  const float* ew2    = (const float*)d_in[17];
  const float* eb2    = (const float*)d_in[18];
  float* outp = (float*)d_out;

  const size_t MB = 1ull << 20;
  char* base = (char*)d_ws;
  int*   counts = (int*)(base);
  int*   offs   = (int*)(base + 256);
  int*   curs   = (int*)(base + 512);
  int*   eidx   = (int*)(base + 1024);
  float* esc    = (float*)(base + 64*1024);
  int*   stok   = (int*)(base + 128*1024);
  int*   ppos   = (int*)(base + 192*1024);
  u16*   peh    = (u16*)(base + 1*MB);
  u16*   pel    = (u16*)(base + 1*MB + 512*1024);
  u16*   hall_h = (u16*)(base + 2*MB);
  u16*   vt_h   = (u16*)(base + 2*MB);      // alias (after V gemm)
  u16*   h1b    = (u16*)(base + 2*MB);      // alias (after attn)
  u16*   pout   = (u16*)(base + 2*MB);      // alias (after MoE gemm1; h1b dead)
  u16*   hall_l = (u16*)(base + 18*MB);
  u16*   vt_l   = (u16*)(base + 18*MB);     // alias (after V gemm)
  u16*   wqT_h  = (u16*)(base + 34*MB);
  u16*   wqT_l  = (u16*)(base + 36*MB);
  u16*   wkT_h  = (u16*)(base + 38*MB);
  u16*   wkT_l  = (u16*)(base + 40*MB);
  u16*   wvT_h  = (u16*)(base + 42*MB);
  u16*   wvT_l  = (u16*)(base + 44*MB);
  u16*   woT_h  = (u16*)(base + 46*MB);
  u16*   woT_l  = (u16*)(base + 48*MB);
  u16*   wTg    = (u16*)(base + 34*MB);     // alias (after add_ln; 4 experts x 8MB = 32MB)
  u16*   qh     = (u16*)(base + 50*MB);
  u16*   ql     = (u16*)(base + 58*MB);
  float* aproj  = (float*)(base + 50*MB);   // alias (after attn)
  u16*   kh     = (u16*)(base + 66*MB);
  float* h1     = (float*)(base + 66*MB);   // alias (after attn)
  u16*   kl     = (u16*)(base + 82*MB);
  u16*   xhid   = (u16*)(base + 82*MB);     // alias (after attn/WO; 82..146)
  float* vbuf   = (float*)(base + 98*MB);
  u16*   aout_h = (u16*)(base + 98*MB);     // alias (after V transpose)
  u16*   aout_l = (u16*)(base + 106*MB);

  zero8<<<1, 64, 0, stream>>>(counts);
  dim3 tb32(32, 8);

  // conversions
  cvt_split_hall<<<8192, 256, 0, stream>>>(hc, h, hall_h, hall_l);
  transpose_split<<<dim3(32,2),  tb32, 0, stream>>>(key_pe, peh, pel, 64, 1024);
  transpose_split<<<dim3(32,32), tb32, 0, stream>>>(wq, wqT_h, wqT_l, 1024, 1024);
  transpose_split<<<dim3(32,32), tb32, 0, stream>>>(wk, wkT_h, wkT_l, 1024, 1024);
  transpose_split<<<dim3(32,32), tb32, 0, stream>>>(wv, wvT_h, wvT_l, 1024, 1024);
  transpose_split<<<dim3(32,32), tb32, 0, stream>>>(wo, woT_h, woT_l, 1024, 1024);

  // QKV projections (split-f16 MFMA, f32-exact); Q/K emit split pairs, V emits f32
  gemm_sp<1,1><<<dim3(8,32), 256, 0, stream>>>(hall_h, hall_l, wqT_h, wqT_l, nullptr, qh, ql, 1024, 1024);
  gemm_sp<0,1><<<dim3(8,64), 256, 0, stream>>>(hall_h, hall_l, wkT_h, wkT_l, nullptr, kh, kl, 1024, 1024);
  gemm_sp<0,0><<<dim3(8,64), 256, 0, stream>>>(hall_h, hall_l, wvT_h, wvT_l, vbuf, nullptr, nullptr, 1024, 1024);

  // V^T split pair [1024 d][8192 keys] (hall region dead now)
  transpose_split<<<dim3(32,256), tb32, 0, stream>>>(vbuf, vt_h, vt_l, 8192, 1024);

  // MFMA attention, 8 q-rows/block (outputs split pair over dead vbuf)
  attn_mfma<<<dim3(128,16,4), 256, 0, stream>>>(qh, ql, kh, kl, vt_h, vt_l, peh, pel, aout_h, aout_l);

  // WO projection + residual LN
  gemm_sp<0,0><<<dim3(8,32), 256, 0, stream>>>(aout_h, aout_l, woT_h, woT_l, aproj, nullptr, nullptr, 1024, 1024);
  add_ln_kernel<<<4096, 256, 0, stream>>>(h, aproj, n1g, n1b, h1, h1b);

  // MoE gate + bucketing (f32 — exact top-2 vs reference)
  gate_kernel<<<4096, 256, 0, stream>>>(h1, gw, gb, eidx, esc, counts);
  scan_kernel<<<1, 64, 0, stream>>>(counts, offs, curs);
  scatter_kernel<<<32, 256, 0, stream>>>(eidx, curs, stok, ppos);

  // per-group (4 experts) FFN: z-batched transposes + gemms (bf16, post-gate)
  for (int g = 0; g < 2; ++g){
    transpose_cvt_z<<<dim3(128,32,4), tb32, 0, stream>>>(
        ew1 + (long)g*4*1024*4096, wTg, 1024, 4096, 4096L*1024, 4096L*1024);
    gemm_bt<true, true ><<<dim3(32,64,4), 256, 0, stream>>>(
        h1b, wTg, xhid, eb1, 4096, 1024, 4096, offs, counts, stok, g*4);
  }
  for (int g = 0; g < 2; ++g){
    transpose_cvt_z<<<dim3(32,128,4), tb32, 0, stream>>>(
        ew2 + (long)g*4*4096*1024, wTg, 4096, 1024, 4096L*1024, 4096L*1024);
    gemm_bt<false, false><<<dim3(8,64,4), 256, 0, stream>>>(
        xhid, wTg, pout, eb2, 1024, 4096, 8192, offs, counts, nullptr, g*4);
  }

  // combine + the two trailing layernorms
  moe_combine_ln<<<4096, 256, 0, stream>>>(h1, pout, esc, ppos, mlg, mlb, n2g, n2b, outp);
}

// Round 11
// 1143.734 us; speedup vs baseline: 6.2778x; 1.4329x over previous
//
#include <hip/hip_runtime.h>

typedef unsigned short u16;
typedef unsigned int u32;
typedef __attribute__((ext_vector_type(8))) __bf16 bf16x8;
typedef __attribute__((ext_vector_type(8))) _Float16 f16x8;
typedef __attribute__((ext_vector_type(4))) float f32x4;

__device__ __forceinline__ u16 f2bf(float f){
  unsigned int u = __float_as_uint(f);
  u += 0x7FFFu + ((u >> 16) & 1u);     // RNE
  return (u16)(u >> 16);
}
__device__ __forceinline__ float bf2f(u16 s){
  return __uint_as_float(((unsigned int)s) << 16);
}
// split-f16: x = hi + lo with |x - hi - lo| <= 2^-24 |x|
__device__ __forceinline__ void fsplit(float x, u16& hi, u16& lo){
  _Float16 h = (_Float16)x;
  float r = x - (float)h;
  _Float16 l = (_Float16)r;
  hi = *(u16*)&h; lo = *(u16*)&l;
}
// async global->LDS, 16B per lane (wave-uniform LDS base; HW adds lane*16)
__device__ __forceinline__ void gll16(const u16* g, u16* lds){
  __builtin_amdgcn_global_load_lds(
      (const __attribute__((address_space(1))) u32*)g,
      (__attribute__((address_space(3))) u32*)(u32)(unsigned long long)lds,
      16, 0, 0);
}

// ======================= small utility kernels =======================

__global__ void zero8(int* c){ if (threadIdx.x < 8) c[threadIdx.x] = 0; }

// z-batched transpose + convert: in [Z][R][C] f32 -> out [Z][C][R] bf16
__global__ __launch_bounds__(256)
void transpose_cvt_z(const float* __restrict__ in, u16* __restrict__ outp,
                     int R, int C, long zin, long zout)
{
  __shared__ float tile[32][33];
  in  += (long)blockIdx.z * zin;
  outp+= (long)blockIdx.z * zout;
  const int c0 = blockIdx.x << 5, r0 = blockIdx.y << 5;
  const int tx = threadIdx.x, ty = threadIdx.y;
  #pragma unroll
  for (int i = ty; i < 32; i += 8)
    tile[i][tx] = in[(long)(r0 + i) * C + c0 + tx];
  __syncthreads();
  #pragma unroll
  for (int i = ty; i < 32; i += 8)
    outp[(long)(c0 + i) * R + r0 + tx] = f2bf(tile[tx][i]);
}

// transpose + split-f16: in [R][C] f32 -> outh/outl [C][R] f16
__global__ __launch_bounds__(256)
void transpose_split(const float* __restrict__ in, u16* __restrict__ oh, u16* __restrict__ ol,
                     int R, int C)
{
  __shared__ float tile[32][33];
  const int c0 = blockIdx.x << 5, r0 = blockIdx.y << 5;
  const int tx = threadIdx.x, ty = threadIdx.y;
  #pragma unroll
  for (int i = ty; i < 32; i += 8)
    tile[i][tx] = in[(long)(r0 + i) * C + c0 + tx];
  __syncthreads();
  #pragma unroll
  for (int i = ty; i < 32; i += 8){
    u16 hh, ll;
    fsplit(tile[tx][i], hh, ll);
    oh[(long)(c0 + i) * R + r0 + tx] = hh;
    ol[(long)(c0 + i) * R + r0 + tx] = ll;
  }
}

// h_all = concat(hc, h) per batch -> split-f16 pair [8192][1024]
__global__ __launch_bounds__(256)
void cvt_split_hall(const float* __restrict__ hc, const float* __restrict__ h,
                    u16* __restrict__ hi, u16* __restrict__ lo)
{
  long i4 = (long)blockIdx.x * 256 + threadIdx.x;
  long row = i4 >> 8;
  int c4 = (int)(i4 & 255);
  int b = (int)(row >> 11), tt = (int)(row & 2047);
  const float4* src = (const float4*)((tt < 1024) ? (hc + ((long)b*1024 + tt)*1024)
                                                  : (h  + ((long)b*1024 + (tt-1024))*1024));
  float4 v = src[c4];
  ushort4 h4, l4;
  fsplit(v.x, h4.x, l4.x); fsplit(v.y, h4.y, l4.y);
  fsplit(v.z, h4.z, l4.z); fsplit(v.w, h4.w, l4.w);
  ((ushort4*)hi)[i4] = h4;
  ((ushort4*)lo)[i4] = l4;
}

// pack key_pe [64][1024] f32 -> PEp[jt][ks][lane][8] split-f16 (fragment-contiguous)
__global__ __launch_bounds__(128)
void pack_pe(const float* __restrict__ pe, u16* __restrict__ PEh, u16* __restrict__ PEl)
{
  const int jt = blockIdx.x;           // 0..63
  const int t = threadIdx.x;           // 0..127
  const int ks = t >> 6, lane = t & 63;
  const int fq = lane >> 4, fr = lane & 15;
  const long o = ((long)(jt*2 + ks)*64 + lane)*8;
  #pragma unroll
  for (int e = 0; e < 8; ++e){
    float v = pe[(long)(ks*32 + fq*8 + e)*1024 + jt*16 + fr];
    u16 hh, ll; fsplit(v, hh, ll);
    PEh[o+e] = hh; PEl[o+e] = ll;
  }
}

// ======================= split-f16 emulated-f32 MFMA GEMM =======================
// 128x128 tile, BK=32, linear LDS [128][32], global_load_lds staging.
// AMAP 1: A row r -> h_all row (r>>10)*2048 + 1024 + (r&1023)   (Q projection)
// EPI 0: C f32
// EPI 1: C as split-f16 pair, row-major
// EPI 2: C as split-f16 pair, K-fragment-packed  Kp[b][hd][kt][ks][lane][8]
// EPI 3: C as split-f16 pair, V-fragment-packed  Vp[b][hd][kc16][dt][q][16][8]

template<int AMAP, int EPI>
__global__ __launch_bounds__(256)
void gemm_sp(const u16* __restrict__ Ah_, const u16* __restrict__ Al_,
             const u16* __restrict__ Bh_, const u16* __restrict__ Bl_,
             float* __restrict__ C, u16* __restrict__ Ch, u16* __restrict__ Cl,
             int N, int Kd)
{
  __shared__ __align__(16) u16 Ahs[4096];
  __shared__ __align__(16) u16 Als[4096];
  __shared__ __align__(16) u16 Bhs[4096];
  __shared__ __align__(16) u16 Bls[4096];
  const int tm = blockIdx.y, tn = blockIdx.x;
  const int t = threadIdx.x;
  const int lane = t & 63, wv = t >> 6;
  const int wm = wv >> 1, wn = wv & 1;
  const int fr = lane & 15, fq = lane >> 4;

  const int r0l = 32*wv + (lane >> 2);
  const int r1l = r0l + 16;
  const int colu = (lane & 3) << 3;
  auto amap = [](int r)->long{
    if (AMAP == 1){ int b = r >> 10, tt = r & 1023; return (long)b*2048 + 1024 + tt; }
    return (long)r;
  };
  const long ar0 = amap(tm*128 + r0l), ar1 = amap(tm*128 + r1l);
  const long br0 = (long)(tn*128 + r0l), br1 = (long)(tn*128 + r1l);
  const u16* pah0 = Ah_ + ar0*Kd + colu;  const u16* pah1 = Ah_ + ar1*Kd + colu;
  const u16* pal0 = Al_ + ar0*Kd + colu;  const u16* pal1 = Al_ + ar1*Kd + colu;
  const u16* pbh0 = Bh_ + br0*Kd + colu;  const u16* pbh1 = Bh_ + br1*Kd + colu;
  const u16* pbl0 = Bl_ + br0*Kd + colu;  const u16* pbl1 = Bl_ + br1*Kd + colu;
  u16* lAh0 = Ahs + 1024*wv;  u16* lAh1 = lAh0 + 512;
  u16* lAl0 = Als + 1024*wv;  u16* lAl1 = lAl0 + 512;
  u16* lBh0 = Bhs + 1024*wv;  u16* lBh1 = lBh0 + 512;
  u16* lBl0 = Bls + 1024*wv;  u16* lBl1 = lBl0 + 512;

  f32x4 acc[4][4];
  const f32x4 z4 = {0.f,0.f,0.f,0.f};
  #pragma unroll
  for (int m=0;m<4;m++)
    #pragma unroll
    for (int n=0;n<4;n++) acc[m][n] = z4;

  const int nk = Kd >> 5;
  for (int kt = 0; kt < nk; ++kt) {
    const int ko = kt << 5;
    __syncthreads();
    gll16(pah0 + ko, lAh0); gll16(pah1 + ko, lAh1);
    gll16(pal0 + ko, lAl0); gll16(pal1 + ko, lAl1);
    gll16(pbh0 + ko, lBh0); gll16(pbh1 + ko, lBh1);
    gll16(pbl0 + ko, lBl0); gll16(pbl1 + ko, lBl1);
    __syncthreads();
    f16x8 afh[4], afl[4], bfh[4], bfl[4];
    #pragma unroll
    for (int m=0;m<4;m++){
      afh[m] = *(const f16x8*)(Ahs + (wm*64 + m*16 + fr)*32 + fq*8);
      afl[m] = *(const f16x8*)(Als + (wm*64 + m*16 + fr)*32 + fq*8);
    }
    #pragma unroll
    for (int n=0;n<4;n++){
      bfh[n] = *(const f16x8*)(Bhs + (wn*64 + n*16 + fr)*32 + fq*8);
      bfl[n] = *(const f16x8*)(Bls + (wn*64 + n*16 + fr)*32 + fq*8);
    }
    #pragma unroll
    for (int m=0;m<4;m++)
      #pragma unroll
      for (int n=0;n<4;n++){
        acc[m][n] = __builtin_amdgcn_mfma_f32_16x16x32_f16(afl[m], bfh[n], acc[m][n], 0, 0, 0);
        acc[m][n] = __builtin_amdgcn_mfma_f32_16x16x32_f16(afh[m], bfl[n], acc[m][n], 0, 0, 0);
        acc[m][n] = __builtin_amdgcn_mfma_f32_16x16x32_f16(afh[m], bfh[n], acc[m][n], 0, 0, 0);
      }
  }

  // C/D layout: col = lane&15, row = (lane>>4)*4 + reg
  #pragma unroll
  for (int m=0;m<4;m++){
    #pragma unroll
    for (int j=0;j<4;j++){
      const long crow = (long)(tm*128 + wm*64 + m*16 + fq*4 + j);
      #pragma unroll
      for (int n=0;n<4;n++){
        const int c = tn*128 + wn*64 + n*16 + fr;
        float vv = acc[m][n][j];
        if (EPI == 0){
          C[crow * N + c] = vv;
        } else if (EPI == 1){
          u16 hh, ll; fsplit(vv, hh, ll);
          Ch[crow * N + c] = hh;
          Cl[crow * N + c] = ll;
        } else if (EPI == 2){
          // Kp: plane (b,hd) of 131072; [kt][ks][fq2*16+fr2][8]
          const int b2 = (int)(crow >> 11), key = (int)(crow & 2047);
          const int hd2 = c >> 6, dd = c & 63;
          const long addr = ((long)(b2*16 + hd2))*131072
                          + ((long)((key>>4)*2 + (dd>>5)))*512
                          + (((dd>>3)&3)*16 + (key&15))*8 + (dd&7);
          u16 hh, ll; fsplit(vv, hh, ll);
          Ch[addr] = hh; Cl[addr] = ll;
        } else {
          // Vp: plane (b,hd) of 131072; [kc16][dt][q][fr2][8]
          const int b2 = (int)(crow >> 11), key = (int)(crow & 2047);
          const int hd2 = c >> 6, dd = c & 63;
          const long addr = ((long)(b2*16 + hd2))*131072
                          + ((((long)(key>>4)*4 + (dd>>4))*2 + ((key>>3)&1)))*128
                          + (dd&15)*8 + (key&7);
          u16 hh, ll; fsplit(vv, hh, ll);
          Ch[addr] = hh; Cl[addr] = ll;
        }
      }
    }
  }
}

// ======================= MFMA split-f16 sliding-window attention =======================
// 16 q-rows per block, 4 waves, 2-tile ILP. All B-operands fragment-packed:
// K/PE loads = one contiguous 1KB per wave; V loads = 2x512B segments.

#define SJP 1032

__global__ __launch_bounds__(256)
void attn_mfma(const u16* __restrict__ qh, const u16* __restrict__ ql,
               const u16* __restrict__ Kph, const u16* __restrict__ Kpl,
               const u16* __restrict__ Vph, const u16* __restrict__ Vpl,
               const u16* __restrict__ PEh, const u16* __restrict__ PEl,
               u16* __restrict__ oh, u16* __restrict__ ol)
{
  __shared__ __align__(16) char smem[68608];
  float* Sj = (float*)smem;                  // [16][SJP] f32
  u16*   Ph = (u16*)smem;                    // [16][1064] u16 (overlay)
  u16*   Pl = (u16*)(smem + 34048);          // [16][1064] u16
  const int bx = blockIdx.x;
  const int q0 = bx << 4;
  const int hd = blockIdx.y, b = blockIdx.z;
  const int t = threadIdx.x, lane = t & 63, wid = t >> 6;
  const int fr = lane & 15, fq = lane >> 4;
  const long plane = ((long)(b*16 + hd)) * 131072;

  // Q A-fragments
  f16x8 qfh[2], qfl[2];
  {
    const long qoff = ((long)(b*1024 + q0 + fr))*1024 + hd*64 + fq*8;
    qfh[0] = *(const f16x8*)(qh + qoff);
    qfh[1] = *(const f16x8*)(qh + qoff + 32);
    qfl[0] = *(const f16x8*)(ql + qoff);
    qfl[1] = *(const f16x8*)(ql + qoff + 32);
  }

  // ---- phase A: Sj = Q @ Kwin^T (65 col-tiles; pairs (ta, ta+4) for ILP) ----
  for (int base = 0; base < 65; base += 8){
    const int ta = base + wid;
    const int tb = base + wid + 4;
    const int tac = (ta < 65) ? ta : 64;
    const int tbc = (tb < 65) ? tb : 64;
    const u16* fA = Kph + plane + ((long)(bx + tac))*1024 + lane*8;
    const u16* fAl= Kpl + plane + ((long)(bx + tac))*1024 + lane*8;
    const u16* fB = Kph + plane + ((long)(bx + tbc))*1024 + lane*8;
    const u16* fBl= Kpl + plane + ((long)(bx + tbc))*1024 + lane*8;
    f32x4 accA = {0.f,0.f,0.f,0.f}, accB = {0.f,0.f,0.f,0.f};
    #pragma unroll
    for (int ks = 0; ks < 2; ++ks){
      f16x8 bhA = *(const f16x8*)(fA  + ks*512);
      f16x8 blA = *(const f16x8*)(fAl + ks*512);
      f16x8 bhB = *(const f16x8*)(fB  + ks*512);
      f16x8 blB = *(const f16x8*)(fBl + ks*512);
      accA = __builtin_amdgcn_mfma_f32_16x16x32_f16(qfl[ks], bhA, accA, 0, 0, 0);
      accB = __builtin_amdgcn_mfma_f32_16x16x32_f16(qfl[ks], bhB, accB, 0, 0, 0);
      accA = __builtin_amdgcn_mfma_f32_16x16x32_f16(qfh[ks], blA, accA, 0, 0, 0);
      accB = __builtin_amdgcn_mfma_f32_16x16x32_f16(qfh[ks], blB, accB, 0, 0, 0);
      accA = __builtin_amdgcn_mfma_f32_16x16x32_f16(qfh[ks], bhA, accA, 0, 0, 0);
      accB = __builtin_amdgcn_mfma_f32_16x16x32_f16(qfh[ks], bhB, accB, 0, 0, 0);
    }
    if (ta < 65){
      const int ca = tac*16 + fr;
      #pragma unroll
      for (int jj = 0; jj < 4; ++jj){
        const int row = fq*4 + jj;
        const int j = ca - row;
        if (j >= 0 && j < 1024) Sj[row*SJP + j] = accA[jj];
      }
    }
    if (tb < 65){
      const int cb = tbc*16 + fr;
      #pragma unroll
      for (int jj = 0; jj < 4; ++jj){
        const int row = fq*4 + jj;
        const int j = cb - row;
        if (j >= 0 && j < 1024) Sj[row*SJP + j] = accB[jj];
      }
    }
  }
  __syncthreads();

  // ---- phase A2: Sj += Q @ PE^T (64 j-tiles; pairs for ILP) ----
  for (int base = 0; base < 64; base += 8){
    const int ta = base + wid, tb = base + wid + 4;
    const u16* fA = PEh + ((long)ta)*1024 + lane*8;
    const u16* fAl= PEl + ((long)ta)*1024 + lane*8;
    const u16* fB = PEh + ((long)tb)*1024 + lane*8;
    const u16* fBl= PEl + ((long)tb)*1024 + lane*8;
    f32x4 accA = {0.f,0.f,0.f,0.f}, accB = {0.f,0.f,0.f,0.f};
    #pragma unroll
    for (int ks = 0; ks < 2; ++ks){
      f16x8 bhA = *(const f16x8*)(fA  + ks*512);
      f16x8 blA = *(const f16x8*)(fAl + ks*512);
      f16x8 bhB = *(const f16x8*)(fB  + ks*512);
      f16x8 blB = *(const f16x8*)(fBl + ks*512);
      accA = __builtin_amdgcn_mfma_f32_16x16x32_f16(qfl[ks], bhA, accA, 0, 0, 0);
      accB = __builtin_amdgcn_mfma_f32_16x16x32_f16(qfl[ks], bhB, accB, 0, 0, 0);
      accA = __builtin_amdgcn_mfma_f32_16x16x32_f16(qfh[ks], blA, accA, 0, 0, 0);
      accB = __builtin_amdgcn_mfma_f32_16x16x32_f16(qfh[ks], blB, accB, 0, 0, 0);
      accA = __builtin_amdgcn_mfma_f32_16x16x32_f16(qfh[ks], bhA, accA, 0, 0, 0);
      accB = __builtin_amdgcn_mfma_f32_16x16x32_f16(qfh[ks], bhB, accB, 0, 0, 0);
    }
    const int ja = ta*16 + fr, jb = tb*16 + fr;
    #pragma unroll
    for (int jj = 0; jj < 4; ++jj){
      const int row = fq*4 + jj;
      Sj[row*SJP + ja] += accA[jj];
      Sj[row*SJP + jb] += accB[jj];
    }
  }
  __syncthreads();

  // ---- softmax: row r = t>>4, lane g = t&15 handles j = g + 16m ----
  {
    const int r = t >> 4, g = t & 15;
    float sv[64];
    float mx = -3.0e38f;
    #pragma unroll
    for (int m = 0; m < 64; ++m){
      float x = Sj[r*SJP + g + (m<<4)] * 0.125f;
      sv[m] = x; mx = fmaxf(mx, x);
    }
    #pragma unroll
    for (int o = 8; o; o >>= 1) mx = fmaxf(mx, __shfl_xor(mx, o, 64));
    float sum = 0.f;
    #pragma unroll
    for (int m = 0; m < 64; ++m){ sv[m] = __expf(sv[m] - mx); sum += sv[m]; }
    #pragma unroll
    for (int o = 8; o; o >>= 1) sum += __shfl_xor(sum, o, 64);
    const float inv = 1.f / sum;
    __syncthreads();                           // Sj fully consumed into registers
    for (int i = t; i < 17024; i += 256) ((unsigned*)smem)[i] = 0;   // zero Ph+Pl
    __syncthreads();
    #pragma unroll
    for (int m = 0; m < 64; ++m){
      float p = sv[m] * inv;
      u16 hh, ll; fsplit(p, hh, ll);
      const int c = r + g + (m<<4);            // band position (<= 1038)
      Ph[r*1064 + c] = hh;
      Pl[r*1064 + c] = ll;
    }
  }
  __syncthreads();

  // ---- phase C: PV. wave wid owns d-tile wid (16 d); K-dim = 33x32 over c ----
  {
    f32x4 acc0 = {0.f,0.f,0.f,0.f}, acc1 = {0.f,0.f,0.f,0.f};
    const int qq = fq & 1;
    for (int ks = 0; ks < 33; ++ks){
      int kc16 = bx + 2*ks + (fq >> 1);
      if (kc16 > 127) kc16 = 127;              // OOB keys: P' zero there
      const long vo = plane + (((long)kc16*4 + wid)*2 + qq)*128 + fr*8;
      f16x8 vh = *(const f16x8*)(Vph + vo);
      f16x8 vl = *(const f16x8*)(Vpl + vo);
      f16x8 ah = *(const f16x8*)(Ph + fr*1064 + ks*32 + fq*8);
      f16x8 al = *(const f16x8*)(Pl + fr*1064 + ks*32 + fq*8);
      f32x4& a = (ks & 1) ? acc1 : acc0;
      a = __builtin_amdgcn_mfma_f32_16x16x32_f16(al, vh, a, 0, 0, 0);
      a = __builtin_amdgcn_mfma_f32_16x16x32_f16(ah, vl, a, 0, 0, 0);
      a = __builtin_amdgcn_mfma_f32_16x16x32_f16(ah, vh, a, 0, 0, 0);
    }
    #pragma unroll
    for (int jj = 0; jj < 4; ++jj){
      float v = acc0[jj] + acc1[jj];
      u16 hh, ll; fsplit(v, hh, ll);
      const int row = fq*4 + jj;
      const long o = ((long)(b*1024 + q0 + row))*1024 + hd*64 + wid*16 + fr;
      oh[o] = hh; ol[o] = ll;
    }
  }
}

// ======================= MFMA bf16 GEMM for MoE (z-batched experts) =======================

template<bool GATHER, bool RELU>
__global__ __launch_bounds__(256)
void gemm_bt(const u16* __restrict__ A, const u16* __restrict__ Bt, u16* __restrict__ Cp,
             const float* __restrict__ bias, int N, int Kd, int maxA,
             const int* __restrict__ offs, const int* __restrict__ counts,
             const int* __restrict__ gather, int ebase)
{
  __shared__ __align__(16) u16 As[4096];
  __shared__ __align__(16) u16 Bs[4096];
  const int z = blockIdx.z;
  const int e = ebase + z;
  const int rbase = offs[e];
  const int cnt   = counts[e];
  const int tm = blockIdx.y, tn = blockIdx.x;
  if (tm * 128 >= cnt) return;
  const u16* BtE = Bt + (long)z * N * Kd;
  const float* biasE = bias + (long)e * N;

  const int t = threadIdx.x;
  const int lane = t & 63, wv = t >> 6;
  const int wm = wv >> 1, wn = wv & 1;
  const int fr = lane & 15, fq = lane >> 4;

  const int r0l = 32*wv + (lane >> 2);
  const int r1l = r0l + 16;
  const int colu = (lane & 3) << 3;
  auto amap = [&](int rl)->long{
    int r = tm*128 + rl;
    int rc = (r < cnt) ? r : (cnt - 1);
    if (GATHER){
      int gi = rbase + rc; gi = (gi < 0) ? 0 : ((gi > 8191) ? 8191 : gi);
      int tok = gather[gi];
      tok = (tok < 0) ? 0 : ((tok >= maxA) ? (maxA - 1) : tok);
      return (long)tok;
    }
    return (long)(rbase + rc);
  };
  const long ar0 = amap(r0l), ar1 = amap(r1l);
  const long br0 = (long)(tn*128 + r0l), br1 = (long)(tn*128 + r1l);
  const u16* pa0 = A + ar0*Kd + colu;    const u16* pa1 = A + ar1*Kd + colu;
  const u16* pb0 = BtE + br0*Kd + colu;  const u16* pb1 = BtE + br1*Kd + colu;
  u16* lA0 = As + 1024*wv;  u16* lA1 = lA0 + 512;
  u16* lB0 = Bs + 1024*wv;  u16* lB1 = lB0 + 512;

  f32x4 acc[4][4];
  const f32x4 z4 = {0.f,0.f,0.f,0.f};
  #pragma unroll
  for (int m=0;m<4;m++)
    #pragma unroll
    for (int n=0;n<4;n++) acc[m][n] = z4;

  const int nk = Kd >> 5;
  for (int kt = 0; kt < nk; ++kt) {
    const int ko = kt << 5;
    __syncthreads();
    gll16(pa0 + ko, lA0); gll16(pa1 + ko, lA1);
    gll16(pb0 + ko, lB0); gll16(pb1 + ko, lB1);
    __syncthreads();
    bf16x8 af[4], bfv[4];
    #pragma unroll
    for (int m=0;m<4;m++) af[m]  = *(const bf16x8*)(As + (wm*64 + m*16 + fr)*32 + fq*8);
    #pragma unroll
    for (int n=0;n<4;n++) bfv[n] = *(const bf16x8*)(Bs + (wn*64 + n*16 + fr)*32 + fq*8);
    #pragma unroll
    for (int m=0;m<4;m++)
      #pragma unroll
      for (int n=0;n<4;n++)
        acc[m][n] = __builtin_amdgcn_mfma_f32_16x16x32_bf16(af[m], bfv[n], acc[m][n], 0, 0, 0);
  }

  #pragma unroll
  for (int m=0;m<4;m++){
    #pragma unroll
    for (int j=0;j<4;j++){
      const int r = tm*128 + wm*64 + m*16 + fq*4 + j;
      if (r >= cnt) continue;
      const long crow = (long)(rbase + r);
      #pragma unroll
      for (int n=0;n<4;n++){
        const int c = tn*128 + wn*64 + n*16 + fr;
        float vv = acc[m][n][j] + biasE[c];
        if (RELU) vv = fmaxf(vv, 0.f);
        Cp[crow * N + c] = f2bf(vv);
      }
    }
  }
}

// ======================= layernorm / gate / moe plumbing =======================

__device__ __forceinline__ void block_reduce2(float& s1, float& s2){
  #pragma unroll
  for (int o = 32; o; o >>= 1){
    s1 += __shfl_xor(s1, o, 64);
    s2 += __shfl_xor(s2, o, 64);
  }
  __shared__ float r1[4], r2[4];
  const int wid = threadIdx.x >> 6;
  if ((threadIdx.x & 63) == 0){ r1[wid] = s1; r2[wid] = s2; }
  __syncthreads();
  s1 = r1[0] + r1[1] + r1[2] + r1[3];
  s2 = r2[0] + r2[1] + r2[2] + r2[3];
  __syncthreads();
}

__global__ __launch_bounds__(256)
void add_ln_kernel(const float* __restrict__ a, const float* __restrict__ r,
                   const float* __restrict__ g, const float* __restrict__ bb,
                   float* __restrict__ of, u16* __restrict__ ob)
{
  const long row = blockIdx.x;
  const int t = threadIdx.x;
  float y[4]; float sum = 0.f, sq = 0.f;
  #pragma unroll
  for (int i = 0; i < 4; ++i){
    const long idx = row*1024 + t + (i<<8);
    float vv = a[idx] + r[idx];
    y[i] = vv; sum += vv; sq += vv*vv;
  }
  block_reduce2(sum, sq);
  const float mu = sum * (1.f/1024.f);
  const float var = fmaxf(sq * (1.f/1024.f) - mu*mu, 0.f);
  const float rs = rsqrtf(var + 1e-5f);
  #pragma unroll
  for (int i = 0; i < 4; ++i){
    const int hcol = t + (i<<8);
    float o = (y[i] - mu) * rs * g[hcol] + bb[hcol];
    of[row*1024 + hcol] = o;
    ob[row*1024 + hcol] = f2bf(o);
  }
}

__global__ __launch_bounds__(256)
void gate_kernel(const float* __restrict__ x, const float* __restrict__ gw,
                 const float* __restrict__ gb, int* __restrict__ eidx,
                 float* __restrict__ esc, int* __restrict__ counts)
{
  const long row = blockIdx.x;
  const int t = threadIdx.x;
  float a[8];
  #pragma unroll
  for (int e=0;e<8;e++) a[e]=0.f;
  for (int hcol = t; hcol < 1024; hcol += 256){
    float xv = x[row*1024 + hcol];
    const float* gr = gw + hcol*8;
    #pragma unroll
    for (int e=0;e<8;e++) a[e] += xv * gr[e];
  }
  #pragma unroll
  for (int e=0;e<8;e++)
    #pragma unroll
    for (int o=32;o;o>>=1) a[e] += __shfl_xor(a[e], o, 64);
  __shared__ float red[4][8];
  const int wid = t >> 6;
  if ((t & 63)==0){
    #pragma unroll
    for (int e=0;e<8;e++) red[wid][e]=a[e];
  }
  __syncthreads();
  if (t == 0){
    float l[8];
    #pragma unroll
    for (int e=0;e<8;e++) l[e] = red[0][e]+red[1][e]+red[2][e]+red[3][e] + gb[e];
    int i0 = 0; float v0 = l[0];
    #pragma unroll
    for (int e=1;e<8;e++) if (l[e] > v0){ v0=l[e]; i0=e; }
    int i1 = -1; float v1 = -3.0e38f;
    #pragma unroll
    for (int e=0;e<8;e++) if (e != i0 && l[e] > v1){ v1=l[e]; i1=e; }
    float e1 = __expf(v1 - v0);
    float den = 1.f + e1;
    eidx[row*2+0]=i0; eidx[row*2+1]=i1;
    esc[row*2+0]=1.f/den; esc[row*2+1]=e1/den;
    atomicAdd(&counts[i0],1); atomicAdd(&counts[i1],1);
  }
}

__global__ void scan_kernel(const int* __restrict__ counts, int* __restrict__ offs,
                            int* __restrict__ curs)
{
  if (threadIdx.x == 0 && blockIdx.x == 0){
    int acc = 0;
    for (int e=0;e<8;e++){ offs[e]=acc; curs[e]=acc; acc += counts[e]; }
  }
}

__global__ __launch_bounds__(256)
void scatter_kernel(const int* __restrict__ eidx, int* __restrict__ curs,
                    int* __restrict__ stok, int* __restrict__ ppos)
{
  int id = blockIdx.x*256 + threadIdx.x;
  if (id >= 8192) return;
  int e = eidx[id];
  e = (e < 0) ? 0 : ((e > 7) ? 7 : e);
  int pos = atomicAdd(&curs[e], 1);
  pos = (pos < 0) ? 0 : ((pos > 8191) ? 8191 : pos);
  stok[pos] = id >> 1;
  ppos[id] = pos;
}

__global__ __launch_bounds__(256)
void moe_combine_ln(const float* __restrict__ h1, const u16* __restrict__ pout,
                    const float* __restrict__ esc, const int* __restrict__ ppos,
                    const float* __restrict__ mg, const float* __restrict__ mb,
                    const float* __restrict__ n2g, const float* __restrict__ n2b,
                    float* __restrict__ outp)
{
  const long row = blockIdx.x;
  const int t = threadIdx.x;
  int p0i = ppos[row*2+0], p1i = ppos[row*2+1];
  p0i = (p0i < 0) ? 0 : ((p0i > 8191) ? 8191 : p0i);
  p1i = (p1i < 0) ? 0 : ((p1i > 8191) ? 8191 : p1i);
  const long p0 = p0i, p1 = p1i;
  const float s0 = esc[row*2+0], s1 = esc[row*2+1];
  float x[4], y[4];
  float sum=0.f, sq=0.f;
  #pragma unroll
  for (int i=0;i<4;i++){
    const int hcol = t + (i<<8);
    const long idx = row*1024 + hcol;
    float xv = h1[idx];
    float m = s0 * bf2f(pout[p0*1024 + hcol]) + s1 * bf2f(pout[p1*1024 + hcol]);
    x[i]=xv; y[i]=xv+m; sum+=y[i]; sq+=y[i]*y[i];
  }
  block_reduce2(sum, sq);
  float mu = sum*(1.f/1024.f), var = fmaxf(sq*(1.f/1024.f)-mu*mu, 0.f), rs = rsqrtf(var+1e-5f);
  float zz[4]; float sum2=0.f, sq2=0.f;
  #pragma unroll
  for (int i=0;i<4;i++){
    const int hcol = t + (i<<8);
    float core = (y[i]-mu)*rs*mg[hcol]+mb[hcol];
    zz[i] = x[i] + core; sum2+=zz[i]; sq2+=zz[i]*zz[i];
  }
  block_reduce2(sum2, sq2);
  float mu2 = sum2*(1.f/1024.f), var2 = fmaxf(sq2*(1.f/1024.f)-mu2*mu2, 0.f), rs2 = rsqrtf(var2+1e-5f);
  #pragma unroll
  for (int i=0;i<4;i++){
    const int hcol = t + (i<<8);
    outp[row*1024 + hcol] = (zz[i]-mu2)*rs2*n2g[hcol]+n2b[hcol];
  }
}

// ======================= launcher =======================
// Workspace (peak 146 MB; metadata at offset 0). SIZE-CORRECTED (R10 bug: Kp/Vp are
// 16 MB each — 64 planes x 256 KB — but were given 8 MB slots; Kp_l clobbered Kp_h).
//  0..1     metadata
//  1..1.5   PEp_h (1..1.125), PEp_l (1.25..1.375)
//  2..18    hall_h   -> h1 f32 (post add_ln input... written by add_ln, read by combine)
//  18..34   hall_l   -> h1b bf16 18..26 (post-QKV)
//  34..50   w pairs (wq_h 34, wq_l 36, wk_h 38, wk_l 40, wv_h 42, wv_l 44, wo_h 46, wo_l 48)
//           -> wTg 34..66 (post add_ln)
//  50..66   qh 50..58, ql 58..66   -> aproj f32 50..66 (post-attn)
//  66..82   Kp_h     -> xhid 66..130 (post-attn)
//  82..98   Kp_l
//  98..114  Vp_h
//  114..130 Vp_l
//  130..138 aout_h   -> pout 130..146 (post-WO)
//  138..146 aout_l

extern "C" void kernel_launch(void* const* d_in, const int* in_sizes, int n_in,
                              void* d_out, int out_size, void* d_ws, size_t ws_size,
                              hipStream_t stream)
{
  const float* h      = (const float*)d_in[0];
  const float* hc     = (const float*)d_in[1];
  const float* key_pe = (const float*)d_in[2];
  const float* wq     = (const float*)d_in[3];
  const float* wk     = (const float*)d_in[4];
  const float* wv     = (const float*)d_in[5];
  const float* wo     = (const float*)d_in[6];
  const float* n1g    = (const float*)d_in[7];
  const float* n1b    = (const float*)d_in[8];
  const float* n2g    = (const float*)d_in[9];
  const float* n2b    = (const float*)d_in[10];
  const float* mlg    = (const float*)d_in[11];
  const float* mlb    = (const float*)d_in[12];
  const float* gw     = (const float*)d_in[13];
  const float* gb     = (const float*)d_in[14];
  const float* ew1    = (const float*)d_in[15];
  const float* eb1    = (const float*)d_in[16];
  const float* ew2    = (const float*)d_in[17];
  const float* eb2    = (const float*)d_in[18];
  float* outp = (float*)d_out;

  const size_t MB = 1ull << 20;
  char* base = (char*)d_ws;
  int*   counts = (int*)(base);
  int*   offs   = (int*)(base + 256);
  int*   curs   = (int*)(base + 512);
  int*   eidx   = (int*)(base + 1024);
  float* esc    = (float*)(base + 64*1024);
  int*   stok   = (int*)(base + 128*1024);
  int*   ppos   = (int*)(base + 192*1024);
  u16*   PEp_h  = (u16*)(base + 1*MB);
  u16*   PEp_l  = (u16*)(base + 1*MB + 256*1024);
  u16*   hall_h = (u16*)(base + 2*MB);      // 16MB
  float* h1     = (float*)(base + 2*MB);    //   alias (post-QKV; hall_h dead)
  u16*   hall_l = (u16*)(base + 18*MB);     // 16MB
  u16*   h1b    = (u16*)(base + 18*MB);     //   alias (post-QKV; 18..26)
  u16*   wqT_h  = (u16*)(base + 34*MB);
  u16*   wqT_l  = (u16*)(base + 36*MB);
  u16*   wkT_h  = (u16*)(base + 38*MB);
  u16*   wkT_l  = (u16*)(base + 40*MB);
  u16*   wvT_h  = (u16*)(base + 42*MB);
  u16*   wvT_l  = (u16*)(base + 44*MB);
  u16*   woT_h  = (u16*)(base + 46*MB);
  u16*   woT_l  = (u16*)(base + 48*MB);
  u16*   wTg    = (u16*)(base + 34*MB);     //   alias (post add_ln; 34..66)
  u16*   qh     = (u16*)(base + 50*MB);     // 8MB
  u16*   ql     = (u16*)(base + 58*MB);     // 8MB
  float* aproj  = (float*)(base + 50*MB);   //   alias (post-attn; 50..66)
  u16*   Kp_h   = (u16*)(base + 66*MB);     // 16MB
  u16*   Kp_l   = (u16*)(base + 82*MB);     // 16MB
  u16*   Vp_h   = (u16*)(base + 98*MB);     // 16MB
  u16*   Vp_l   = (u16*)(base + 114*MB);    // 16MB
  u16*   xhid   = (u16*)(base + 66*MB);     //   alias (post-attn; 66..130)
  u16*   aout_h = (u16*)(base + 130*MB);    // 8MB
  u16*   aout_l = (u16*)(base + 138*MB);    // 8MB
  u16*   pout   = (u16*)(base + 130*MB);    //   alias (post-WO; 130..146)

  zero8<<<1, 64, 0, stream>>>(counts);
  dim3 tb32(32, 8);

  // conversions
  cvt_split_hall<<<8192, 256, 0, stream>>>(hc, h, hall_h, hall_l);
  pack_pe<<<64, 128, 0, stream>>>(key_pe, PEp_h, PEp_l);
  transpose_split<<<dim3(32,32), tb32, 0, stream>>>(wq, wqT_h, wqT_l, 1024, 1024);
  transpose_split<<<dim3(32,32), tb32, 0, stream>>>(wk, wkT_h, wkT_l, 1024, 1024);
  transpose_split<<<dim3(32,32), tb32, 0, stream>>>(wv, wvT_h, wvT_l, 1024, 1024);
  transpose_split<<<dim3(32,32), tb32, 0, stream>>>(wo, woT_h, woT_l, 1024, 1024);

  // QKV projections (split-f16 MFMA, f32-exact)
  // Q row-major pair; K fragment-packed Kp; V fragment-packed Vp
  gemm_sp<1,1><<<dim3(8,32), 256, 0, stream>>>(hall_h, hall_l, wqT_h, wqT_l, nullptr, qh, ql, 1024, 1024);
  gemm_sp<0,2><<<dim3(8,64), 256, 0, stream>>>(hall_h, hall_l, wkT_h, wkT_l, nullptr, Kp_h, Kp_l, 1024, 1024);
  gemm_sp<0,3><<<dim3(8,64), 256, 0, stream>>>(hall_h, hall_l, wvT_h, wvT_l, nullptr, Vp_h, Vp_l, 1024, 1024);

  // MFMA attention (16 q-rows/block, fragment-packed operands)
  attn_mfma<<<dim3(64,16,4), 256, 0, stream>>>(qh, ql, Kp_h, Kp_l, Vp_h, Vp_l, PEp_h, PEp_l, aout_h, aout_l);

  // WO projection + residual LN
  gemm_sp<0,0><<<dim3(8,32), 256, 0, stream>>>(aout_h, aout_l, woT_h, woT_l, aproj, nullptr, nullptr, 1024, 1024);
  add_ln_kernel<<<4096, 256, 0, stream>>>(h, aproj, n1g, n1b, h1, h1b);

  // MoE gate + bucketing (f32 — exact top-2 vs reference)
  gate_kernel<<<4096, 256, 0, stream>>>(h1, gw, gb, eidx, esc, counts);
  scan_kernel<<<1, 64, 0, stream>>>(counts, offs, curs);
  scatter_kernel<<<32, 256, 0, stream>>>(eidx, curs, stok, ppos);

  // per-group (4 experts) FFN: z-batched transposes + gemms (bf16, post-gate)
  for (int g = 0; g < 2; ++g){
    transpose_cvt_z<<<dim3(128,32,4), tb32, 0, stream>>>(
        ew1 + (long)g*4*1024*4096, wTg, 1024, 4096, 4096L*1024, 4096L*1024);
    gemm_bt<true, true ><<<dim3(32,64,4), 256, 0, stream>>>(
        h1b, wTg, xhid, eb1, 4096, 1024, 4096, offs, counts, stok, g*4);
  }
  for (int g = 0; g < 2; ++g){
    transpose_cvt_z<<<dim3(32,128,4), tb32, 0, stream>>>(
        ew2 + (long)g*4*4096*1024, wTg, 4096, 1024, 4096L*1024, 4096L*1024);
    gemm_bt<false, false><<<dim3(8,64,4), 256, 0, stream>>>(
        xhid, wTg, pout, eb2, 1024, 4096, 8192, offs, counts, nullptr, g*4);
  }

  // combine + the two trailing layernorms
  moe_combine_ln<<<4096, 256, 0, stream>>>(h1, pout, esc, ppos, mlg, mlb, n2g, n2b, outp);
}

// Round 12
// 1072.841 us; speedup vs baseline: 6.6926x; 1.0661x over previous
//
#include <hip/hip_runtime.h>

typedef unsigned short u16;
typedef unsigned int u32;
typedef __attribute__((ext_vector_type(8))) __bf16 bf16x8;
typedef __attribute__((ext_vector_type(8))) _Float16 f16x8;
typedef __attribute__((ext_vector_type(4))) float f32x4;

__device__ __forceinline__ u16 f2bf(float f){
  unsigned int u = __float_as_uint(f);
  u += 0x7FFFu + ((u >> 16) & 1u);     // RNE
  return (u16)(u >> 16);
}
__device__ __forceinline__ float bf2f(u16 s){
  return __uint_as_float(((unsigned int)s) << 16);
}
// split-f16: x = hi + lo with |x - hi - lo| <= 2^-24 |x|
__device__ __forceinline__ void fsplit(float x, u16& hi, u16& lo){
  _Float16 h = (_Float16)x;
  float r = x - (float)h;
  _Float16 l = (_Float16)r;
  hi = *(u16*)&h; lo = *(u16*)&l;
}
// async global->LDS, 16B per lane (wave-uniform LDS base; HW adds lane*16)
__device__ __forceinline__ void gll16(const u16* g, u16* lds){
  __builtin_amdgcn_global_load_lds(
      (const __attribute__((address_space(1))) u32*)g,
      (__attribute__((address_space(3))) u32*)(u32)(unsigned long long)lds,
      16, 0, 0);
}

// ======================= small utility kernels =======================

__global__ void zero8(int* c){ if (threadIdx.x < 8) c[threadIdx.x] = 0; }

// z-batched transpose + convert: in [Z][R][C] f32 -> out [Z][C][R] bf16
__global__ __launch_bounds__(256)
void transpose_cvt_z(const float* __restrict__ in, u16* __restrict__ outp,
                     int R, int C, long zin, long zout)
{
  __shared__ float tile[32][33];
  in  += (long)blockIdx.z * zin;
  outp+= (long)blockIdx.z * zout;
  const int c0 = blockIdx.x << 5, r0 = blockIdx.y << 5;
  const int tx = threadIdx.x, ty = threadIdx.y;
  #pragma unroll
  for (int i = ty; i < 32; i += 8)
    tile[i][tx] = in[(long)(r0 + i) * C + c0 + tx];
  __syncthreads();
  #pragma unroll
  for (int i = ty; i < 32; i += 8)
    outp[(long)(c0 + i) * R + r0 + tx] = f2bf(tile[tx][i]);
}

// 4-way z-batched 1024x1024 transpose+split: z 0..2 -> wall (wk|wv|wq), z=3 -> wo
__global__ __launch_bounds__(256)
void transpose_split4(const float* __restrict__ s0, const float* __restrict__ s1,
                      const float* __restrict__ s2, const float* __restrict__ s3,
                      u16* __restrict__ wall_h, u16* __restrict__ wall_l,
                      u16* __restrict__ wo_h, u16* __restrict__ wo_l)
{
  __shared__ float tile[32][33];
  const int z = blockIdx.z;
  const float* in = (z==0)?s0:(z==1)?s1:(z==2)?s2:s3;
  u16* oh = (z<3) ? (wall_h + (long)z*1024*1024) : wo_h;
  u16* ol = (z<3) ? (wall_l + (long)z*1024*1024) : wo_l;
  const int c0 = blockIdx.x << 5, r0 = blockIdx.y << 5;
  const int tx = threadIdx.x, ty = threadIdx.y;
  #pragma unroll
  for (int i = ty; i < 32; i += 8)
    tile[i][tx] = in[(long)(r0 + i) * 1024 + c0 + tx];
  __syncthreads();
  #pragma unroll
  for (int i = ty; i < 32; i += 8){
    u16 hh, ll;
    fsplit(tile[tx][i], hh, ll);
    oh[(long)(c0 + i) * 1024 + r0 + tx] = hh;
    ol[(long)(c0 + i) * 1024 + r0 + tx] = ll;
  }
}

// h_all = concat(hc, h) per batch -> split-f16 pair [8192][1024]
__global__ __launch_bounds__(256)
void cvt_split_hall(const float* __restrict__ hc, const float* __restrict__ h,
                    u16* __restrict__ hi, u16* __restrict__ lo)
{
  long i4 = (long)blockIdx.x * 256 + threadIdx.x;
  long row = i4 >> 8;
  int c4 = (int)(i4 & 255);
  int b = (int)(row >> 11), tt = (int)(row & 2047);
  const float4* src = (const float4*)((tt < 1024) ? (hc + ((long)b*1024 + tt)*1024)
                                                  : (h  + ((long)b*1024 + (tt-1024))*1024));
  float4 v = src[c4];
  ushort4 h4, l4;
  fsplit(v.x, h4.x, l4.x); fsplit(v.y, h4.y, l4.y);
  fsplit(v.z, h4.z, l4.z); fsplit(v.w, h4.w, l4.w);
  ((ushort4*)hi)[i4] = h4;
  ((ushort4*)lo)[i4] = l4;
}

// pack key_pe [64][1024] f32 -> PEp[jt][ks][lane][8] split-f16 (fragment-contiguous)
__global__ __launch_bounds__(128)
void pack_pe(const float* __restrict__ pe, u16* __restrict__ PEh, u16* __restrict__ PEl)
{
  const int jt = blockIdx.x;           // 0..63
  const int t = threadIdx.x;           // 0..127
  const int ks = t >> 6, lane = t & 63;
  const int fq = lane >> 4, fr = lane & 15;
  const long o = ((long)(jt*2 + ks)*64 + lane)*8;
  #pragma unroll
  for (int e = 0; e < 8; ++e){
    float v = pe[(long)(ks*32 + fq*8 + e)*1024 + jt*16 + fr];
    u16 hh, ll; fsplit(v, hh, ll);
    PEh[o+e] = hh; PEl[o+e] = ll;
  }
}

// ======================= split-f16 emulated-f32 MFMA GEMM =======================
// 128x128 tile, BK=32, linear LDS [128][32], global_load_lds staging.
// EPI 0: C f32
// EPI 4: fused QKV: c<1024 -> Kp pack, c<2048 -> Vp pack, else Q (h rows only)

template<int EPI>
__global__ __launch_bounds__(256)
void gemm_sp(const u16* __restrict__ Ah_, const u16* __restrict__ Al_,
             const u16* __restrict__ Bh_, const u16* __restrict__ Bl_,
             float* __restrict__ C,
             u16* __restrict__ Kh, u16* __restrict__ Kl,
             u16* __restrict__ Vh, u16* __restrict__ Vl,
             u16* __restrict__ Qh, u16* __restrict__ Ql,
             int N, int Kd)
{
  __shared__ __align__(16) u16 Ahs[4096];
  __shared__ __align__(16) u16 Als[4096];
  __shared__ __align__(16) u16 Bhs[4096];
  __shared__ __align__(16) u16 Bls[4096];
  const int tm = blockIdx.y, tn = blockIdx.x;
  const int t = threadIdx.x;
  const int lane = t & 63, wv = t >> 6;
  const int wm = wv >> 1, wn = wv & 1;
  const int fr = lane & 15, fq = lane >> 4;

  const int r0l = 32*wv + (lane >> 2);
  const int r1l = r0l + 16;
  const int colu = (lane & 3) << 3;
  const long ar0 = (long)(tm*128 + r0l), ar1 = (long)(tm*128 + r1l);
  const long br0 = (long)(tn*128 + r0l), br1 = (long)(tn*128 + r1l);
  const u16* pah0 = Ah_ + ar0*Kd + colu;  const u16* pah1 = Ah_ + ar1*Kd + colu;
  const u16* pal0 = Al_ + ar0*Kd + colu;  const u16* pal1 = Al_ + ar1*Kd + colu;
  const u16* pbh0 = Bh_ + br0*Kd + colu;  const u16* pbh1 = Bh_ + br1*Kd + colu;
  const u16* pbl0 = Bl_ + br0*Kd + colu;  const u16* pbl1 = Bl_ + br1*Kd + colu;
  u16* lAh0 = Ahs + 1024*wv;  u16* lAh1 = lAh0 + 512;
  u16* lAl0 = Als + 1024*wv;  u16* lAl1 = lAl0 + 512;
  u16* lBh0 = Bhs + 1024*wv;  u16* lBh1 = lBh0 + 512;
  u16* lBl0 = Bls + 1024*wv;  u16* lBl1 = lBl0 + 512;

  f32x4 acc[4][4];
  const f32x4 z4 = {0.f,0.f,0.f,0.f};
  #pragma unroll
  for (int m=0;m<4;m++)
    #pragma unroll
    for (int n=0;n<4;n++) acc[m][n] = z4;

  const int nk = Kd >> 5;
  for (int kt = 0; kt < nk; ++kt) {
    const int ko = kt << 5;
    __syncthreads();
    gll16(pah0 + ko, lAh0); gll16(pah1 + ko, lAh1);
    gll16(pal0 + ko, lAl0); gll16(pal1 + ko, lAl1);
    gll16(pbh0 + ko, lBh0); gll16(pbh1 + ko, lBh1);
    gll16(pbl0 + ko, lBl0); gll16(pbl1 + ko, lBl1);
    __syncthreads();
    f16x8 afh[4], afl[4], bfh[4], bfl[4];
    #pragma unroll
    for (int m=0;m<4;m++){
      afh[m] = *(const f16x8*)(Ahs + (wm*64 + m*16 + fr)*32 + fq*8);
      afl[m] = *(const f16x8*)(Als + (wm*64 + m*16 + fr)*32 + fq*8);
    }
    #pragma unroll
    for (int n=0;n<4;n++){
      bfh[n] = *(const f16x8*)(Bhs + (wn*64 + n*16 + fr)*32 + fq*8);
      bfl[n] = *(const f16x8*)(Bls + (wn*64 + n*16 + fr)*32 + fq*8);
    }
    #pragma unroll
    for (int m=0;m<4;m++)
      #pragma unroll
      for (int n=0;n<4;n++){
        acc[m][n] = __builtin_amdgcn_mfma_f32_16x16x32_f16(afl[m], bfh[n], acc[m][n], 0, 0, 0);
        acc[m][n] = __builtin_amdgcn_mfma_f32_16x16x32_f16(afh[m], bfl[n], acc[m][n], 0, 0, 0);
        acc[m][n] = __builtin_amdgcn_mfma_f32_16x16x32_f16(afh[m], bfh[n], acc[m][n], 0, 0, 0);
      }
  }

  // C/D layout: col = lane&15, row = (lane>>4)*4 + reg
  #pragma unroll
  for (int m=0;m<4;m++){
    #pragma unroll
    for (int j=0;j<4;j++){
      const long crow = (long)(tm*128 + wm*64 + m*16 + fq*4 + j);
      #pragma unroll
      for (int n=0;n<4;n++){
        const int c = tn*128 + wn*64 + n*16 + fr;
        float vv = acc[m][n][j];
        if (EPI == 0){
          C[crow * N + c] = vv;
        } else {
          const int b2 = (int)(crow >> 11), key = (int)(crow & 2047);
          u16 hh, ll; fsplit(vv, hh, ll);
          if (c < 1024){
            // Kp: plane (b,hd) of 131072; [kt][ks][fq2*16+fr2][8]
            const int hd2 = c >> 6, dd = c & 63;
            const long addr = ((long)(b2*16 + hd2))*131072
                            + ((long)((key>>4)*2 + (dd>>5)))*512
                            + (((dd>>3)&3)*16 + (key&15))*8 + (dd&7);
            Kh[addr] = hh; Kl[addr] = ll;
          } else if (c < 2048){
            // Vp: plane (b,hd) of 131072; [kc16][dt][q][fr2][8]
            const int c2 = c - 1024;
            const int hd2 = c2 >> 6, dd = c2 & 63;
            const long addr = ((long)(b2*16 + hd2))*131072
                            + ((((long)(key>>4)*4 + (dd>>4))*2 + ((key>>3)&1)))*128
                            + (dd&15)*8 + (key&7);
            Vh[addr] = hh; Vl[addr] = ll;
          } else if (key >= 1024){
            // Q row-major (h rows only; cache-row results discarded)
            const int c2 = c - 2048;
            const long qrow = (long)b2*1024 + (key - 1024);
            Qh[qrow*1024 + c2] = hh;
            Ql[qrow*1024 + c2] = ll;
          }
        }
      }
    }
  }
}

// ======================= MFMA split-f16 sliding-window attention =======================
// 16 q-rows per block, 4 waves, 2-tile ILP. All B-operands fragment-packed:
// K/PE loads = one contiguous 1KB per wave; V loads = 2x512B segments.

#define SJP 1032

__global__ __launch_bounds__(256)
void attn_mfma(const u16* __restrict__ qh, const u16* __restrict__ ql,
               const u16* __restrict__ Kph, const u16* __restrict__ Kpl,
               const u16* __restrict__ Vph, const u16* __restrict__ Vpl,
               const u16* __restrict__ PEh, const u16* __restrict__ PEl,
               u16* __restrict__ oh, u16* __restrict__ ol)
{
  __shared__ __align__(16) char smem[68608];
  float* Sj = (float*)smem;                  // [16][SJP] f32
  u16*   Ph = (u16*)smem;                    // [16][1064] u16 (overlay)
  u16*   Pl = (u16*)(smem + 34048);          // [16][1064] u16
  const int bx = blockIdx.x;
  const int q0 = bx << 4;
  const int hd = blockIdx.y, b = blockIdx.z;
  const int t = threadIdx.x, lane = t & 63, wid = t >> 6;
  const int fr = lane & 15, fq = lane >> 4;
  const long plane = ((long)(b*16 + hd)) * 131072;

  // Q A-fragments
  f16x8 qfh[2], qfl[2];
  {
    const long qoff = ((long)(b*1024 + q0 + fr))*1024 + hd*64 + fq*8;
    qfh[0] = *(const f16x8*)(qh + qoff);
    qfh[1] = *(const f16x8*)(qh + qoff + 32);
    qfl[0] = *(const f16x8*)(ql + qoff);
    qfl[1] = *(const f16x8*)(ql + qoff + 32);
  }

  // ---- phase A: Sj = Q @ Kwin^T (65 col-tiles; pairs (ta, ta+4) for ILP) ----
  for (int base = 0; base < 65; base += 8){
    const int ta = base + wid;
    const int tb = base + wid + 4;
    const int tac = (ta < 65) ? ta : 64;
    const int tbc = (tb < 65) ? tb : 64;
    const u16* fA = Kph + plane + ((long)(bx + tac))*1024 + lane*8;
    const u16* fAl= Kpl + plane + ((long)(bx + tac))*1024 + lane*8;
    const u16* fB = Kph + plane + ((long)(bx + tbc))*1024 + lane*8;
    const u16* fBl= Kpl + plane + ((long)(bx + tbc))*1024 + lane*8;
    f32x4 accA = {0.f,0.f,0.f,0.f}, accB = {0.f,0.f,0.f,0.f};
    #pragma unroll
    for (int ks = 0; ks < 2; ++ks){
      f16x8 bhA = *(const f16x8*)(fA  + ks*512);
      f16x8 blA = *(const f16x8*)(fAl + ks*512);
      f16x8 bhB = *(const f16x8*)(fB  + ks*512);
      f16x8 blB = *(const f16x8*)(fBl + ks*512);
      accA = __builtin_amdgcn_mfma_f32_16x16x32_f16(qfl[ks], bhA, accA, 0, 0, 0);
      accB = __builtin_amdgcn_mfma_f32_16x16x32_f16(qfl[ks], bhB, accB, 0, 0, 0);
      accA = __builtin_amdgcn_mfma_f32_16x16x32_f16(qfh[ks], blA, accA, 0, 0, 0);
      accB = __builtin_amdgcn_mfma_f32_16x16x32_f16(qfh[ks], blB, accB, 0, 0, 0);
      accA = __builtin_amdgcn_mfma_f32_16x16x32_f16(qfh[ks], bhA, accA, 0, 0, 0);
      accB = __builtin_amdgcn_mfma_f32_16x16x32_f16(qfh[ks], bhB, accB, 0, 0, 0);
    }
    if (ta < 65){
      const int ca = tac*16 + fr;
      #pragma unroll
      for (int jj = 0; jj < 4; ++jj){
        const int row = fq*4 + jj;
        const int j = ca - row;
        if (j >= 0 && j < 1024) Sj[row*SJP + j] = accA[jj];
      }
    }
    if (tb < 65){
      const int cb = tbc*16 + fr;
      #pragma unroll
      for (int jj = 0; jj < 4; ++jj){
        const int row = fq*4 + jj;
        const int j = cb - row;
        if (j >= 0 && j < 1024) Sj[row*SJP + j] = accB[jj];
      }
    }
  }
  __syncthreads();

  // ---- phase A2: Sj += Q @ PE^T (64 j-tiles; pairs for ILP) ----
  for (int base = 0; base < 64; base += 8){
    const int ta = base + wid, tb = base + wid + 4;
    const u16* fA = PEh + ((long)ta)*1024 + lane*8;
    const u16* fAl= PEl + ((long)ta)*1024 + lane*8;
    const u16* fB = PEh + ((long)tb)*1024 + lane*8;
    const u16* fBl= PEl + ((long)tb)*1024 + lane*8;
    f32x4 accA = {0.f,0.f,0.f,0.f}, accB = {0.f,0.f,0.f,0.f};
    #pragma unroll
    for (int ks = 0; ks < 2; ++ks){
      f16x8 bhA = *(const f16x8*)(fA  + ks*512);
      f16x8 blA = *(const f16x8*)(fAl + ks*512);
      f16x8 bhB = *(const f16x8*)(fB  + ks*512);
      f16x8 blB = *(const f16x8*)(fBl + ks*512);
      accA = __builtin_amdgcn_mfma_f32_16x16x32_f16(qfl[ks], bhA, accA, 0, 0, 0);
      accB = __builtin_amdgcn_mfma_f32_16x16x32_f16(qfl[ks], bhB, accB, 0, 0, 0);
      accA = __builtin_amdgcn_mfma_f32_16x16x32_f16(qfh[ks], blA, accA, 0, 0, 0);
      accB = __builtin_amdgcn_mfma_f32_16x16x32_f16(qfh[ks], blB, accB, 0, 0, 0);
      accA = __builtin_amdgcn_mfma_f32_16x16x32_f16(qfh[ks], bhA, accA, 0, 0, 0);
      accB = __builtin_amdgcn_mfma_f32_16x16x32_f16(qfh[ks], bhB, accB, 0, 0, 0);
    }
    const int ja = ta*16 + fr, jb = tb*16 + fr;
    #pragma unroll
    for (int jj = 0; jj < 4; ++jj){
      const int row = fq*4 + jj;
      Sj[row*SJP + ja] += accA[jj];
      Sj[row*SJP + jb] += accB[jj];
    }
  }
  __syncthreads();

  // ---- softmax: row r = t>>4, lane g = t&15 handles j = g + 16m ----
  {
    const int r = t >> 4, g = t & 15;
    float sv[64];
    float mx = -3.0e38f;
    #pragma unroll
    for (int m = 0; m < 64; ++m){
      float x = Sj[r*SJP + g + (m<<4)] * 0.125f;
      sv[m] = x; mx = fmaxf(mx, x);
    }
    #pragma unroll
    for (int o = 8; o; o >>= 1) mx = fmaxf(mx, __shfl_xor(mx, o, 64));
    float sum = 0.f;
    #pragma unroll
    for (int m = 0; m < 64; ++m){ sv[m] = __expf(sv[m] - mx); sum += sv[m]; }
    #pragma unroll
    for (int o = 8; o; o >>= 1) sum += __shfl_xor(sum, o, 64);
    const float inv = 1.f / sum;
    __syncthreads();                           // Sj fully consumed into registers
    for (int i = t; i < 17024; i += 256) ((unsigned*)smem)[i] = 0;   // zero Ph+Pl
    __syncthreads();
    #pragma unroll
    for (int m = 0; m < 64; ++m){
      float p = sv[m] * inv;
      u16 hh, ll; fsplit(p, hh, ll);
      const int c = r + g + (m<<4);            // band position (<= 1038)
      Ph[r*1064 + c] = hh;
      Pl[r*1064 + c] = ll;
    }
  }
  __syncthreads();

  // ---- phase C: PV. wave wid owns d-tile wid (16 d); K-dim = 33x32 over c ----
  {
    f32x4 acc0 = {0.f,0.f,0.f,0.f}, acc1 = {0.f,0.f,0.f,0.f};
    const int qq = fq & 1;
    for (int ks = 0; ks < 33; ++ks){
      int kc16 = bx + 2*ks + (fq >> 1);
      if (kc16 > 127) kc16 = 127;              // OOB keys: P' zero there
      const long vo = plane + (((long)kc16*4 + wid)*2 + qq)*128 + fr*8;
      f16x8 vh = *(const f16x8*)(Vph + vo);
      f16x8 vl = *(const f16x8*)(Vpl + vo);
      f16x8 ah = *(const f16x8*)(Ph + fr*1064 + ks*32 + fq*8);
      f16x8 al = *(const f16x8*)(Pl + fr*1064 + ks*32 + fq*8);
      f32x4& a = (ks & 1) ? acc1 : acc0;
      a = __builtin_amdgcn_mfma_f32_16x16x32_f16(al, vh, a, 0, 0, 0);
      a = __builtin_amdgcn_mfma_f32_16x16x32_f16(ah, vl, a, 0, 0, 0);
      a = __builtin_amdgcn_mfma_f32_16x16x32_f16(ah, vh, a, 0, 0, 0);
    }
    #pragma unroll
    for (int jj = 0; jj < 4; ++jj){
      float v = acc0[jj] + acc1[jj];
      u16 hh, ll; fsplit(v, hh, ll);
      const int row = fq*4 + jj;
      const long o = ((long)(b*1024 + q0 + row))*1024 + hd*64 + wid*16 + fr;
      oh[o] = hh; ol[o] = ll;
    }
  }
}

// ======================= MFMA bf16 GEMM for MoE (z-batched, double-buffered) =======================

template<bool GATHER, bool RELU>
__global__ __launch_bounds__(256)
void gemm_bt(const u16* __restrict__ A, const u16* __restrict__ Bt, u16* __restrict__ Cp,
             const float* __restrict__ bias, int N, int Kd, int maxA,
             const int* __restrict__ offs, const int* __restrict__ counts,
             const int* __restrict__ gather, int ebase)
{
  __shared__ __align__(16) u16 As[2][4096];
  __shared__ __align__(16) u16 Bs[2][4096];
  const int z = blockIdx.z;
  const int e = ebase + z;
  const int rbase = offs[e];
  const int cnt   = counts[e];
  const int tm = blockIdx.y, tn = blockIdx.x;
  if (tm * 128 >= cnt) return;
  const u16* BtE = Bt + (long)z * N * Kd;
  const float* biasE = bias + (long)e * N;

  const int t = threadIdx.x;
  const int lane = t & 63, wv = t >> 6;
  const int wm = wv >> 1, wn = wv & 1;
  const int fr = lane & 15, fq = lane >> 4;

  const int r0l = 32*wv + (lane >> 2);
  const int r1l = r0l + 16;
  const int colu = (lane & 3) << 3;
  auto amap = [&](int rl)->long{
    int r = tm*128 + rl;
    int rc = (r < cnt) ? r : (cnt - 1);
    if (GATHER){
      int gi = rbase + rc; gi = (gi < 0) ? 0 : ((gi > 8191) ? 8191 : gi);
      int tok = gather[gi];
      tok = (tok < 0) ? 0 : ((tok >= maxA) ? (maxA - 1) : tok);
      return (long)tok;
    }
    return (long)(rbase + rc);
  };
  const long ar0 = amap(r0l), ar1 = amap(r1l);
  const long br0 = (long)(tn*128 + r0l), br1 = (long)(tn*128 + r1l);
  const u16* pa0 = A + ar0*Kd + colu;    const u16* pa1 = A + ar1*Kd + colu;
  const u16* pb0 = BtE + br0*Kd + colu;  const u16* pb1 = BtE + br1*Kd + colu;

  f32x4 acc[4][4];
  const f32x4 z4 = {0.f,0.f,0.f,0.f};
  #pragma unroll
  for (int m=0;m<4;m++)
    #pragma unroll
    for (int n=0;n<4;n++) acc[m][n] = z4;

  auto issue = [&](int bufi, int kt){
    const int ko = kt << 5;
    gll16(pa0 + ko, As[bufi] + 1024*wv);
    gll16(pa1 + ko, As[bufi] + 1024*wv + 512);
    gll16(pb0 + ko, Bs[bufi] + 1024*wv);
    gll16(pb1 + ko, Bs[bufi] + 1024*wv + 512);
  };

  const int nk = Kd >> 5;
  issue(0, 0);
  for (int kt = 0; kt < nk; ++kt) {
    const int cur = kt & 1;
    __syncthreads();                       // buf[cur] loads done; buf[cur^1] compute done
    if (kt + 1 < nk) issue(cur ^ 1, kt + 1);
    bf16x8 af[4], bfv[4];
    #pragma unroll
    for (int m=0;m<4;m++) af[m]  = *(const bf16x8*)(As[cur] + (wm*64 + m*16 + fr)*32 + fq*8);
    #pragma unroll
    for (int n=0;n<4;n++) bfv[n] = *(const bf16x8*)(Bs[cur] + (wn*64 + n*16 + fr)*32 + fq*8);
    #pragma unroll
    for (int m=0;m<4;m++)
      #pragma unroll
      for (int n=0;n<4;n++)
        acc[m][n] = __builtin_amdgcn_mfma_f32_16x16x32_bf16(af[m], bfv[n], acc[m][n], 0, 0, 0);
  }

  #pragma unroll
  for (int m=0;m<4;m++){
    #pragma unroll
    for (int j=0;j<4;j++){
      const int r = tm*128 + wm*64 + m*16 + fq*4 + j;
      if (r >= cnt) continue;
      const long crow = (long)(rbase + r);
      #pragma unroll
      for (int n=0;n<4;n++){
        const int c = tn*128 + wn*64 + n*16 + fr;
        float vv = acc[m][n][j] + biasE[c];
        if (RELU) vv = fmaxf(vv, 0.f);
        Cp[crow * N + c] = f2bf(vv);
      }
    }
  }
}

// ======================= layernorm / gate / moe plumbing =======================

__device__ __forceinline__ void block_reduce2(float& s1, float& s2){
  #pragma unroll
  for (int o = 32; o; o >>= 1){
    s1 += __shfl_xor(s1, o, 64);
    s2 += __shfl_xor(s2, o, 64);
  }
  __shared__ float r1[4], r2[4];
  const int wid = threadIdx.x >> 6;
  if ((threadIdx.x & 63) == 0){ r1[wid] = s1; r2[wid] = s2; }
  __syncthreads();
  s1 = r1[0] + r1[1] + r1[2] + r1[3];
  s2 = r2[0] + r2[1] + r2[2] + r2[3];
  __syncthreads();
}

__global__ __launch_bounds__(256)
void add_ln_kernel(const float* __restrict__ a, const float* __restrict__ r,
                   const float* __restrict__ g, const float* __restrict__ bb,
                   float* __restrict__ of, u16* __restrict__ ob)
{
  const long row = blockIdx.x;
  const int t = threadIdx.x;
  float y[4]; float sum = 0.f, sq = 0.f;
  #pragma unroll
  for (int i = 0; i < 4; ++i){
    const long idx = row*1024 + t + (i<<8);
    float vv = a[idx] + r[idx];
    y[i] = vv; sum += vv; sq += vv*vv;
  }
  block_reduce2(sum, sq);
  const float mu = sum * (1.f/1024.f);
  const float var = fmaxf(sq * (1.f/1024.f) - mu*mu, 0.f);
  const float rs = rsqrtf(var + 1e-5f);
  #pragma unroll
  for (int i = 0; i < 4; ++i){
    const int hcol = t + (i<<8);
    float o = (y[i] - mu) * rs * g[hcol] + bb[hcol];
    of[row*1024 + hcol] = o;
    ob[row*1024 + hcol] = f2bf(o);
  }
}

__global__ __launch_bounds__(256)
void gate_kernel(const float* __restrict__ x, const float* __restrict__ gw,
                 const float* __restrict__ gb, int* __restrict__ eidx,
                 float* __restrict__ esc, int* __restrict__ counts)
{
  const long row = blockIdx.x;
  const int t = threadIdx.x;
  float a[8];
  #pragma unroll
  for (int e=0;e<8;e++) a[e]=0.f;
  for (int hcol = t; hcol < 1024; hcol += 256){
    float xv = x[row*1024 + hcol];
    const float* gr = gw + hcol*8;
    #pragma unroll
    for (int e=0;e<8;e++) a[e] += xv * gr[e];
  }
  #pragma unroll
  for (int e=0;e<8;e++)
    #pragma unroll
    for (int o=32;o;o>>=1) a[e] += __shfl_xor(a[e], o, 64);
  __shared__ float red[4][8];
  const int wid = t >> 6;
  if ((t & 63)==0){
    #pragma unroll
    for (int e=0;e<8;e++) red[wid][e]=a[e];
  }
  __syncthreads();
  if (t == 0){
    float l[8];
    #pragma unroll
    for (int e=0;e<8;e++) l[e] = red[0][e]+red[1][e]+red[2][e]+red[3][e] + gb[e];
    int i0 = 0; float v0 = l[0];
    #pragma unroll
    for (int e=1;e<8;e++) if (l[e] > v0){ v0=l[e]; i0=e; }
    int i1 = -1; float v1 = -3.0e38f;
    #pragma unroll
    for (int e=0;e<8;e++) if (e != i0 && l[e] > v1){ v1=l[e]; i1=e; }
    float e1 = __expf(v1 - v0);
    float den = 1.f + e1;
    eidx[row*2+0]=i0; eidx[row*2+1]=i1;
    esc[row*2+0]=1.f/den; esc[row*2+1]=e1/den;
    atomicAdd(&counts[i0],1); atomicAdd(&counts[i1],1);
  }
}

__global__ void scan_kernel(const int* __restrict__ counts, int* __restrict__ offs,
                            int* __restrict__ curs)
{
  if (threadIdx.x == 0 && blockIdx.x == 0){
    int acc = 0;
    for (int e=0;e<8;e++){ offs[e]=acc; curs[e]=acc; acc += counts[e]; }
  }
}

__global__ __launch_bounds__(256)
void scatter_kernel(const int* __restrict__ eidx, int* __restrict__ curs,
                    int* __restrict__ stok, int* __restrict__ ppos)
{
  int id = blockIdx.x*256 + threadIdx.x;
  if (id >= 8192) return;
  int e = eidx[id];
  e = (e < 0) ? 0 : ((e > 7) ? 7 : e);
  int pos = atomicAdd(&curs[e], 1);
  pos = (pos < 0) ? 0 : ((pos > 8191) ? 8191 : pos);
  stok[pos] = id >> 1;
  ppos[id] = pos;
}

__global__ __launch_bounds__(256)
void moe_combine_ln(const float* __restrict__ h1, const u16* __restrict__ pout,
                    const float* __restrict__ esc, const int* __restrict__ ppos,
                    const float* __restrict__ mg, const float* __restrict__ mb,
                    const float* __restrict__ n2g, const float* __restrict__ n2b,
                    float* __restrict__ outp)
{
  const long row = blockIdx.x;
  const int t = threadIdx.x;
  int p0i = ppos[row*2+0], p1i = ppos[row*2+1];
  p0i = (p0i < 0) ? 0 : ((p0i > 8191) ? 8191 : p0i);
  p1i = (p1i < 0) ? 0 : ((p1i > 8191) ? 8191 : p1i);
  const long p0 = p0i, p1 = p1i;
  const float s0 = esc[row*2+0], s1 = esc[row*2+1];
  float x[4], y[4];
  float sum=0.f, sq=0.f;
  #pragma unroll
  for (int i=0;i<4;i++){
    const int hcol = t + (i<<8);
    const long idx = row*1024 + hcol;
    float xv = h1[idx];
    float m = s0 * bf2f(pout[p0*1024 + hcol]) + s1 * bf2f(pout[p1*1024 + hcol]);
    x[i]=xv; y[i]=xv+m; sum+=y[i]; sq+=y[i]*y[i];
  }
  block_reduce2(sum, sq);
  float mu = sum*(1.f/1024.f), var = fmaxf(sq*(1.f/1024.f)-mu*mu, 0.f), rs = rsqrtf(var+1e-5f);
  float zz[4]; float sum2=0.f, sq2=0.f;
  #pragma unroll
  for (int i=0;i<4;i++){
    const int hcol = t + (i<<8);
    float core = (y[i]-mu)*rs*mg[hcol]+mb[hcol];
    zz[i] = x[i] + core; sum2+=zz[i]; sq2+=zz[i]*zz[i];
  }
  block_reduce2(sum2, sq2);
  float mu2 = sum2*(1.f/1024.f), var2 = fmaxf(sq2*(1.f/1024.f)-mu2*mu2, 0.f), rs2 = rsqrtf(var2+1e-5f);
  #pragma unroll
  for (int i=0;i<4;i++){
    const int hcol = t + (i<<8);
    outp[row*1024 + hcol] = (zz[i]-mu2)*rs2*n2g[hcol]+n2b[hcol];
  }
}

// ======================= launcher =======================
// Workspace (peak 146 MB; metadata at offset 0):
//  0..1     metadata
//  1..1.5   PEp_h (1..1.125), PEp_l (1.25..1.375)
//  2..18    hall_h   -> h1 f32 (post-QKV)
//  18..34   hall_l   -> h1b bf16 18..26 (post-QKV)
//  34..50   wall_h 34..40, wall_l 40..46, wo_h 46..48, wo_l 48..50
//           -> wTg 34..66 (post add_ln)
//  50..66   qh 50..58, ql 58..66   -> aproj f32 50..66 (post-attn)
//  66..82   Kp_h     -> xhid 66..130 (post-attn)
//  82..98   Kp_l
//  98..114  Vp_h
//  114..130 Vp_l
//  130..138 aout_h   -> pout 130..146 (post-WO)
//  138..146 aout_l

extern "C" void kernel_launch(void* const* d_in, const int* in_sizes, int n_in,
                              void* d_out, int out_size, void* d_ws, size_t ws_size,
                              hipStream_t stream)
{
  const float* h      = (const float*)d_in[0];
  const float* hc     = (const float*)d_in[1];
  const float* key_pe = (const float*)d_in[2];
  const float* wq     = (const float*)d_in[3];
  const float* wk     = (const float*)d_in[4];
  const float* wv     = (const float*)d_in[5];
  const float* wo     = (const float*)d_in[6];
  const float* n1g    = (const float*)d_in[7];
  const float* n1b    = (const float*)d_in[8];
  const float* n2g    = (const float*)d_in[9];
  const float* n2b    = (const float*)d_in[10];
  const float* mlg    = (const float*)d_in[11];
  const float* mlb    = (const float*)d_in[12];
  const float* gw     = (const float*)d_in[13];
  const float* gb     = (const float*)d_in[14];
  const float* ew1    = (const float*)d_in[15];
  const float* eb1    = (const float*)d_in[16];
  const float* ew2    = (const float*)d_in[17];
  const float* eb2    = (const float*)d_in[18];
  float* outp = (float*)d_out;

  const size_t MB = 1ull << 20;
  char* base = (char*)d_ws;
  int*   counts = (int*)(base);
  int*   offs   = (int*)(base + 256);
  int*   curs   = (int*)(base + 512);
  int*   eidx   = (int*)(base + 1024);
  float* esc    = (float*)(base + 64*1024);
  int*   stok   = (int*)(base + 128*1024);
  int*   ppos   = (int*)(base + 192*1024);
  u16*   PEp_h  = (u16*)(base + 1*MB);
  u16*   PEp_l  = (u16*)(base + 1*MB + 256*1024);
  u16*   hall_h = (u16*)(base + 2*MB);      // 16MB
  float* h1     = (float*)(base + 2*MB);    //   alias (post-QKV; hall_h dead)
  u16*   hall_l = (u16*)(base + 18*MB);     // 16MB
  u16*   h1b    = (u16*)(base + 18*MB);     //   alias (post-QKV; 18..26)
  u16*   wall_h = (u16*)(base + 34*MB);     // 6MB  [wk|wv|wq]^T
  u16*   wall_l = (u16*)(base + 40*MB);     // 6MB
  u16*   woT_h  = (u16*)(base + 46*MB);     // 2MB
  u16*   woT_l  = (u16*)(base + 48*MB);     // 2MB
  u16*   wTg    = (u16*)(base + 34*MB);     //   alias (post add_ln; 34..66)
  u16*   qh     = (u16*)(base + 50*MB);     // 8MB
  u16*   ql     = (u16*)(base + 58*MB);     // 8MB
  float* aproj  = (float*)(base + 50*MB);   //   alias (post-attn; 50..66)
  u16*   Kp_h   = (u16*)(base + 66*MB);     // 16MB
  u16*   Kp_l   = (u16*)(base + 82*MB);     // 16MB
  u16*   Vp_h   = (u16*)(base + 98*MB);     // 16MB
  u16*   Vp_l   = (u16*)(base + 114*MB);    // 16MB
  u16*   xhid   = (u16*)(base + 66*MB);     //   alias (post-attn; 66..130)
  u16*   aout_h = (u16*)(base + 130*MB);    // 8MB
  u16*   aout_l = (u16*)(base + 138*MB);    // 8MB
  u16*   pout   = (u16*)(base + 130*MB);    //   alias (post-WO; 130..146)

  zero8<<<1, 64, 0, stream>>>(counts);
  dim3 tb32(32, 8);

  // conversions
  cvt_split_hall<<<8192, 256, 0, stream>>>(hc, h, hall_h, hall_l);
  pack_pe<<<64, 128, 0, stream>>>(key_pe, PEp_h, PEp_l);
  transpose_split4<<<dim3(32,32,4), tb32, 0, stream>>>(wk, wv, wq, wo,
                                                       wall_h, wall_l, woT_h, woT_l);

  // fused QKV projection (split-f16 MFMA, f32-exact): one dispatch, N=3072
  gemm_sp<4><<<dim3(24,64), 256, 0, stream>>>(hall_h, hall_l, wall_h, wall_l, nullptr,
                                              Kp_h, Kp_l, Vp_h, Vp_l, qh, ql, 3072, 1024);

  // MFMA attention (16 q-rows/block, fragment-packed operands)
  attn_mfma<<<dim3(64,16,4), 256, 0, stream>>>(qh, ql, Kp_h, Kp_l, Vp_h, Vp_l, PEp_h, PEp_l, aout_h, aout_l);

  // WO projection + residual LN
  gemm_sp<0><<<dim3(8,32), 256, 0, stream>>>(aout_h, aout_l, woT_h, woT_l, aproj,
                                             nullptr, nullptr, nullptr, nullptr, nullptr, nullptr, 1024, 1024);
  add_ln_kernel<<<4096, 256, 0, stream>>>(h, aproj, n1g, n1b, h1, h1b);

  // MoE gate + bucketing (f32 — exact top-2 vs reference)
  gate_kernel<<<4096, 256, 0, stream>>>(h1, gw, gb, eidx, esc, counts);
  scan_kernel<<<1, 64, 0, stream>>>(counts, offs, curs);
  scatter_kernel<<<32, 256, 0, stream>>>(eidx, curs, stok, ppos);

  // per-group (4 experts) FFN: z-batched transposes + double-buffered gemms
  for (int g = 0; g < 2; ++g){
    transpose_cvt_z<<<dim3(128,32,4), tb32, 0, stream>>>(
        ew1 + (long)g*4*1024*4096, wTg, 1024, 4096, 4096L*1024, 4096L*1024);
    gemm_bt<true, true ><<<dim3(32,64,4), 256, 0, stream>>>(
        h1b, wTg, xhid, eb1, 4096, 1024, 4096, offs, counts, stok, g*4);
  }
  for (int g = 0; g < 2; ++g){
    transpose_cvt_z<<<dim3(32,128,4), tb32, 0, stream>>>(
        ew2 + (long)g*4*4096*1024, wTg, 4096, 1024, 4096L*1024, 4096L*1024);
    gemm_bt<false, false><<<dim3(8,64,4), 256, 0, stream>>>(
        xhid, wTg, pout, eb2, 1024, 4096, 8192, offs, counts, nullptr, g*4);
  }

  // combine + the two trailing layernorms
  moe_combine_ln<<<4096, 256, 0, stream>>>(h1, pout, esc, ppos, mlg, mlb, n2g, n2b, outp);
}

// Round 13
// 1059.081 us; speedup vs baseline: 6.7796x; 1.0130x over previous
//
#include <hip/hip_runtime.h>

typedef unsigned short u16;
typedef unsigned int u32;
typedef __attribute__((ext_vector_type(8))) __bf16 bf16x8;
typedef __attribute__((ext_vector_type(8))) _Float16 f16x8;
typedef __attribute__((ext_vector_type(4))) float f32x4;

__device__ __forceinline__ u16 f2bf(float f){
  unsigned int u = __float_as_uint(f);
  u += 0x7FFFu + ((u >> 16) & 1u);     // RNE
  return (u16)(u >> 16);
}
__device__ __forceinline__ float bf2f(u16 s){
  return __uint_as_float(((unsigned int)s) << 16);
}
// split-f16: x = hi + lo with |x - hi - lo| <= 2^-24 |x|
__device__ __forceinline__ void fsplit(float x, u16& hi, u16& lo){
  _Float16 h = (_Float16)x;
  float r = x - (float)h;
  _Float16 l = (_Float16)r;
  hi = *(u16*)&h; lo = *(u16*)&l;
}
// async global->LDS, 16B per lane (wave-uniform LDS base; HW adds lane*16)
__device__ __forceinline__ void gll16(const u16* g, u16* lds){
  __builtin_amdgcn_global_load_lds(
      (const __attribute__((address_space(1))) u32*)g,
      (__attribute__((address_space(3))) u32*)(u32)(unsigned long long)lds,
      16, 0, 0);
}

// ======================= small utility kernels =======================

__global__ void zero8(int* c){ if (threadIdx.x < 8) c[threadIdx.x] = 0; }

// z-batched transpose + convert: in [Z][R][C] f32 -> out [Z][C][R] bf16
__global__ __launch_bounds__(256)
void transpose_cvt_z(const float* __restrict__ in, u16* __restrict__ outp,
                     int R, int C, long zin, long zout)
{
  __shared__ float tile[32][33];
  in  += (long)blockIdx.z * zin;
  outp+= (long)blockIdx.z * zout;
  const int c0 = blockIdx.x << 5, r0 = blockIdx.y << 5;
  const int tx = threadIdx.x, ty = threadIdx.y;
  #pragma unroll
  for (int i = ty; i < 32; i += 8)
    tile[i][tx] = in[(long)(r0 + i) * C + c0 + tx];
  __syncthreads();
  #pragma unroll
  for (int i = ty; i < 32; i += 8)
    outp[(long)(c0 + i) * R + r0 + tx] = f2bf(tile[tx][i]);
}

// 4-way z-batched 1024x1024 transpose+split: z 0..2 -> wall (wk|wv|wq), z=3 -> wo
__global__ __launch_bounds__(256)
void transpose_split4(const float* __restrict__ s0, const float* __restrict__ s1,
                      const float* __restrict__ s2, const float* __restrict__ s3,
                      u16* __restrict__ wall_h, u16* __restrict__ wall_l,
                      u16* __restrict__ wo_h, u16* __restrict__ wo_l)
{
  __shared__ float tile[32][33];
  const int z = blockIdx.z;
  const float* in = (z==0)?s0:(z==1)?s1:(z==2)?s2:s3;
  u16* oh = (z<3) ? (wall_h + (long)z*1024*1024) : wo_h;
  u16* ol = (z<3) ? (wall_l + (long)z*1024*1024) : wo_l;
  const int c0 = blockIdx.x << 5, r0 = blockIdx.y << 5;
  const int tx = threadIdx.x, ty = threadIdx.y;
  #pragma unroll
  for (int i = ty; i < 32; i += 8)
    tile[i][tx] = in[(long)(r0 + i) * 1024 + c0 + tx];
  __syncthreads();
  #pragma unroll
  for (int i = ty; i < 32; i += 8){
    u16 hh, ll;
    fsplit(tile[tx][i], hh, ll);
    oh[(long)(c0 + i) * 1024 + r0 + tx] = hh;
    ol[(long)(c0 + i) * 1024 + r0 + tx] = ll;
  }
}

// h_all = concat(hc, h) per batch -> split-f16 pair [8192][1024]
__global__ __launch_bounds__(256)
void cvt_split_hall(const float* __restrict__ hc, const float* __restrict__ h,
                    u16* __restrict__ hi, u16* __restrict__ lo)
{
  long i4 = (long)blockIdx.x * 256 + threadIdx.x;
  long row = i4 >> 8;
  int c4 = (int)(i4 & 255);
  int b = (int)(row >> 11), tt = (int)(row & 2047);
  const float4* src = (const float4*)((tt < 1024) ? (hc + ((long)b*1024 + tt)*1024)
                                                  : (h  + ((long)b*1024 + (tt-1024))*1024));
  float4 v = src[c4];
  ushort4 h4, l4;
  fsplit(v.x, h4.x, l4.x); fsplit(v.y, h4.y, l4.y);
  fsplit(v.z, h4.z, l4.z); fsplit(v.w, h4.w, l4.w);
  ((ushort4*)hi)[i4] = h4;
  ((ushort4*)lo)[i4] = l4;
}

// pack key_pe [64][1024] f32 -> PEp[jt][ks][lane][8] split-f16 (fragment-contiguous)
__global__ __launch_bounds__(128)
void pack_pe(const float* __restrict__ pe, u16* __restrict__ PEh, u16* __restrict__ PEl)
{
  const int jt = blockIdx.x;           // 0..63
  const int t = threadIdx.x;           // 0..127
  const int ks = t >> 6, lane = t & 63;
  const int fq = lane >> 4, fr = lane & 15;
  const long o = ((long)(jt*2 + ks)*64 + lane)*8;
  #pragma unroll
  for (int e = 0; e < 8; ++e){
    float v = pe[(long)(ks*32 + fq*8 + e)*1024 + jt*16 + fr];
    u16 hh, ll; fsplit(v, hh, ll);
    PEh[o+e] = hh; PEl[o+e] = ll;
  }
}

// ======================= split-f16 emulated-f32 MFMA GEMM =======================
// 128x128 tile, BK=32, linear LDS [128][32], global_load_lds staging.
// EPI 0: C f32
// EPI 4: fused QKV: c<1024 -> Kp pack, c<2048 -> Vp pack, else Q (h rows only)
// DBUF: double-buffered LDS prefetch (for 1-block/CU dispatches)

template<int EPI, bool DBUF>
__global__ __launch_bounds__(256)
void gemm_sp(const u16* __restrict__ Ah_, const u16* __restrict__ Al_,
             const u16* __restrict__ Bh_, const u16* __restrict__ Bl_,
             float* __restrict__ C,
             u16* __restrict__ Kh, u16* __restrict__ Kl,
             u16* __restrict__ Vh, u16* __restrict__ Vl,
             u16* __restrict__ Qh, u16* __restrict__ Ql,
             int N, int Kd)
{
  __shared__ __align__(16) u16 Ahs[(DBUF?2:1)*4096];
  __shared__ __align__(16) u16 Als[(DBUF?2:1)*4096];
  __shared__ __align__(16) u16 Bhs[(DBUF?2:1)*4096];
  __shared__ __align__(16) u16 Bls[(DBUF?2:1)*4096];
  const int tm = blockIdx.y, tn = blockIdx.x;
  const int t = threadIdx.x;
  const int lane = t & 63, wv = t >> 6;
  const int wm = wv >> 1, wn = wv & 1;
  const int fr = lane & 15, fq = lane >> 4;

  const int r0l = 32*wv + (lane >> 2);
  const int r1l = r0l + 16;
  const int colu = (lane & 3) << 3;
  const long ar0 = (long)(tm*128 + r0l), ar1 = (long)(tm*128 + r1l);
  const long br0 = (long)(tn*128 + r0l), br1 = (long)(tn*128 + r1l);
  const u16* pah0 = Ah_ + ar0*Kd + colu;  const u16* pah1 = Ah_ + ar1*Kd + colu;
  const u16* pal0 = Al_ + ar0*Kd + colu;  const u16* pal1 = Al_ + ar1*Kd + colu;
  const u16* pbh0 = Bh_ + br0*Kd + colu;  const u16* pbh1 = Bh_ + br1*Kd + colu;
  const u16* pbl0 = Bl_ + br0*Kd + colu;  const u16* pbl1 = Bl_ + br1*Kd + colu;

  f32x4 acc[4][4];
  const f32x4 z4 = {0.f,0.f,0.f,0.f};
  #pragma unroll
  for (int m=0;m<4;m++)
    #pragma unroll
    for (int n=0;n<4;n++) acc[m][n] = z4;

  auto issue = [&](int bufi, int kt){
    const int ko = kt << 5;
    u16* a0 = Ahs + bufi*4096 + 1024*wv;
    u16* l0 = Als + bufi*4096 + 1024*wv;
    u16* b0 = Bhs + bufi*4096 + 1024*wv;
    u16* c0 = Bls + bufi*4096 + 1024*wv;
    gll16(pah0 + ko, a0); gll16(pah1 + ko, a0 + 512);
    gll16(pal0 + ko, l0); gll16(pal1 + ko, l0 + 512);
    gll16(pbh0 + ko, b0); gll16(pbh1 + ko, b0 + 512);
    gll16(pbl0 + ko, c0); gll16(pbl1 + ko, c0 + 512);
  };

  const int nk = Kd >> 5;
  if (DBUF) issue(0, 0);
  for (int kt = 0; kt < nk; ++kt) {
    int cur;
    if (DBUF){
      cur = kt & 1;
      __syncthreads();
      if (kt + 1 < nk) issue(cur ^ 1, kt + 1);
    } else {
      cur = 0;
      __syncthreads();
      issue(0, kt);
      __syncthreads();
    }
    f16x8 afh[4], afl[4], bfh[4], bfl[4];
    #pragma unroll
    for (int m=0;m<4;m++){
      afh[m] = *(const f16x8*)(Ahs + cur*4096 + (wm*64 + m*16 + fr)*32 + fq*8);
      afl[m] = *(const f16x8*)(Als + cur*4096 + (wm*64 + m*16 + fr)*32 + fq*8);
    }
    #pragma unroll
    for (int n=0;n<4;n++){
      bfh[n] = *(const f16x8*)(Bhs + cur*4096 + (wn*64 + n*16 + fr)*32 + fq*8);
      bfl[n] = *(const f16x8*)(Bls + cur*4096 + (wn*64 + n*16 + fr)*32 + fq*8);
    }
    #pragma unroll
    for (int m=0;m<4;m++)
      #pragma unroll
      for (int n=0;n<4;n++){
        acc[m][n] = __builtin_amdgcn_mfma_f32_16x16x32_f16(afl[m], bfh[n], acc[m][n], 0, 0, 0);
        acc[m][n] = __builtin_amdgcn_mfma_f32_16x16x32_f16(afh[m], bfl[n], acc[m][n], 0, 0, 0);
        acc[m][n] = __builtin_amdgcn_mfma_f32_16x16x32_f16(afh[m], bfh[n], acc[m][n], 0, 0, 0);
      }
  }

  // C/D layout: col = lane&15, row = (lane>>4)*4 + reg
  #pragma unroll
  for (int m=0;m<4;m++){
    #pragma unroll
    for (int j=0;j<4;j++){
      const long crow = (long)(tm*128 + wm*64 + m*16 + fq*4 + j);
      #pragma unroll
      for (int n=0;n<4;n++){
        const int c = tn*128 + wn*64 + n*16 + fr;
        float vv = acc[m][n][j];
        if (EPI == 0){
          C[crow * N + c] = vv;
        } else {
          const int b2 = (int)(crow >> 11), key = (int)(crow & 2047);
          u16 hh, ll; fsplit(vv, hh, ll);
          if (c < 1024){
            const int hd2 = c >> 6, dd = c & 63;
            const long addr = ((long)(b2*16 + hd2))*131072
                            + ((long)((key>>4)*2 + (dd>>5)))*512
                            + (((dd>>3)&3)*16 + (key&15))*8 + (dd&7);
            Kh[addr] = hh; Kl[addr] = ll;
          } else if (c < 2048){
            const int c2 = c - 1024;
            const int hd2 = c2 >> 6, dd = c2 & 63;
            const long addr = ((long)(b2*16 + hd2))*131072
                            + ((((long)(key>>4)*4 + (dd>>4))*2 + ((key>>3)&1)))*128
                            + (dd&15)*8 + (key&7);
            Vh[addr] = hh; Vl[addr] = ll;
          } else if (key >= 1024){
            const int c2 = c - 2048;
            const long qrow = (long)b2*1024 + (key - 1024);
            Qh[qrow*1024 + c2] = hh;
            Ql[qrow*1024 + c2] = ll;
          }
        }
      }
    }
  }
}

// ======================= MFMA split-f16 sliding-window attention =======================
// 16 q-rows per block, 4 waves, 2-tile ILP + register software-pipelining of all
// B-fragment loads. P stride 1066 (odd dword stride -> <=2-way LDS banks).
// 1D grid 4096 with XCD swizzle for per-XCD L2 plane locality.

#define SJP 1032
#define PJP 1066

__global__ __launch_bounds__(256)
void attn_mfma(const u16* __restrict__ qh, const u16* __restrict__ ql,
               const u16* __restrict__ Kph, const u16* __restrict__ Kpl,
               const u16* __restrict__ Vph, const u16* __restrict__ Vpl,
               const u16* __restrict__ PEh, const u16* __restrict__ PEl,
               u16* __restrict__ oh, u16* __restrict__ ol)
{
  __shared__ __align__(16) char smem[68608];
  float* Sj = (float*)smem;                  // [16][SJP] f32
  u16*   Ph = (u16*)smem;                    // [16][PJP] u16 (overlay)
  u16*   Pl = (u16*)(smem + 34112);          // [16][PJP] u16
  // XCD swizzle: consecutive ids on one XCD cover consecutive bx of same plane
  const int id = blockIdx.x;
  const int sw = (id & 7) * 512 + (id >> 3);
  const int bx = sw & 63;
  const int hd = (sw >> 6) & 15;
  const int b  = sw >> 10;
  const int q0 = bx << 4;
  const int t = threadIdx.x, lane = t & 63, wid = t >> 6;
  const int fr = lane & 15, fq = lane >> 4;
  const long plane = ((long)(b*16 + hd)) * 131072;

  // Q A-fragments
  f16x8 qfh[2], qfl[2];
  {
    const long qoff = ((long)(b*1024 + q0 + fr))*1024 + hd*64 + fq*8;
    qfh[0] = *(const f16x8*)(qh + qoff);
    qfh[1] = *(const f16x8*)(qh + qoff + 32);
    qfl[0] = *(const f16x8*)(ql + qoff);
    qfl[1] = *(const f16x8*)(ql + qoff + 32);
  }

  // ---- phase A: Sj = Q @ Kwin^T (65 col-tiles; pairs + reg pipeline) ----
  {
    f16x8 cA[4], cB[4], nA[4], nB[4];
    auto kfrag = [&](int tile, f16x8* d){
      const int tc = (tile < 65) ? tile : 64;
      const u16* f  = Kph + plane + ((long)(bx + tc))*1024 + lane*8;
      const u16* fl = Kpl + plane + ((long)(bx + tc))*1024 + lane*8;
      d[0] = *(const f16x8*)(f);
      d[1] = *(const f16x8*)(fl);
      d[2] = *(const f16x8*)(f + 512);
      d[3] = *(const f16x8*)(fl + 512);
    };
    kfrag(wid, cA); kfrag(wid + 4, cB);
    for (int base = 0; base < 65; base += 8){
      const int ta = base + wid, tb = base + wid + 4;
      if (base + 8 < 65){ kfrag(base + 8 + wid, nA); kfrag(base + 12 + wid, nB); }
      f32x4 accA = {0.f,0.f,0.f,0.f}, accB = {0.f,0.f,0.f,0.f};
      accA = __builtin_amdgcn_mfma_f32_16x16x32_f16(qfl[0], cA[0], accA, 0, 0, 0);
      accB = __builtin_amdgcn_mfma_f32_16x16x32_f16(qfl[0], cB[0], accB, 0, 0, 0);
      accA = __builtin_amdgcn_mfma_f32_16x16x32_f16(qfh[0], cA[1], accA, 0, 0, 0);
      accB = __builtin_amdgcn_mfma_f32_16x16x32_f16(qfh[0], cB[1], accB, 0, 0, 0);
      accA = __builtin_amdgcn_mfma_f32_16x16x32_f16(qfh[0], cA[0], accA, 0, 0, 0);
      accB = __builtin_amdgcn_mfma_f32_16x16x32_f16(qfh[0], cB[0], accB, 0, 0, 0);
      accA = __builtin_amdgcn_mfma_f32_16x16x32_f16(qfl[1], cA[2], accA, 0, 0, 0);
      accB = __builtin_amdgcn_mfma_f32_16x16x32_f16(qfl[1], cB[2], accB, 0, 0, 0);
      accA = __builtin_amdgcn_mfma_f32_16x16x32_f16(qfh[1], cA[3], accA, 0, 0, 0);
      accB = __builtin_amdgcn_mfma_f32_16x16x32_f16(qfh[1], cB[3], accB, 0, 0, 0);
      accA = __builtin_amdgcn_mfma_f32_16x16x32_f16(qfh[1], cA[2], accA, 0, 0, 0);
      accB = __builtin_amdgcn_mfma_f32_16x16x32_f16(qfh[1], cB[2], accB, 0, 0, 0);
      if (ta < 65){
        const int ca = ta*16 + fr;
        #pragma unroll
        for (int jj = 0; jj < 4; ++jj){
          const int row = fq*4 + jj;
          const int j = ca - row;
          if (j >= 0 && j < 1024) Sj[row*SJP + j] = accA[jj];
        }
      }
      if (tb < 65){
        const int cb = tb*16 + fr;
        #pragma unroll
        for (int jj = 0; jj < 4; ++jj){
          const int row = fq*4 + jj;
          const int j = cb - row;
          if (j >= 0 && j < 1024) Sj[row*SJP + j] = accB[jj];
        }
      }
      #pragma unroll
      for (int i = 0; i < 4; ++i){ cA[i] = nA[i]; cB[i] = nB[i]; }
    }
  }
  __syncthreads();

  // ---- phase A2: Sj += Q @ PE^T (64 j-tiles; pairs + reg pipeline) ----
  {
    f16x8 cA[4], cB[4], nA[4], nB[4];
    auto pefrag = [&](int tile, f16x8* d){
      const u16* f  = PEh + ((long)tile)*1024 + lane*8;
      const u16* fl = PEl + ((long)tile)*1024 + lane*8;
      d[0] = *(const f16x8*)(f);
      d[1] = *(const f16x8*)(fl);
      d[2] = *(const f16x8*)(f + 512);
      d[3] = *(const f16x8*)(fl + 512);
    };
    pefrag(wid, cA); pefrag(wid + 4, cB);
    for (int base = 0; base < 64; base += 8){
      const int ta = base + wid, tb = base + wid + 4;
      if (base + 8 < 64){ pefrag(base + 8 + wid, nA); pefrag(base + 12 + wid, nB); }
      f32x4 accA = {0.f,0.f,0.f,0.f}, accB = {0.f,0.f,0.f,0.f};
      accA = __builtin_amdgcn_mfma_f32_16x16x32_f16(qfl[0], cA[0], accA, 0, 0, 0);
      accB = __builtin_amdgcn_mfma_f32_16x16x32_f16(qfl[0], cB[0], accB, 0, 0, 0);
      accA = __builtin_amdgcn_mfma_f32_16x16x32_f16(qfh[0], cA[1], accA, 0, 0, 0);
      accB = __builtin_amdgcn_mfma_f32_16x16x32_f16(qfh[0], cB[1], accB, 0, 0, 0);
      accA = __builtin_amdgcn_mfma_f32_16x16x32_f16(qfh[0], cA[0], accA, 0, 0, 0);
      accB = __builtin_amdgcn_mfma_f32_16x16x32_f16(qfh[0], cB[0], accB, 0, 0, 0);
      accA = __builtin_amdgcn_mfma_f32_16x16x32_f16(qfl[1], cA[2], accA, 0, 0, 0);
      accB = __builtin_amdgcn_mfma_f32_16x16x32_f16(qfl[1], cB[2], accB, 0, 0, 0);
      accA = __builtin_amdgcn_mfma_f32_16x16x32_f16(qfh[1], cA[3], accA, 0, 0, 0);
      accB = __builtin_amdgcn_mfma_f32_16x16x32_f16(qfh[1], cB[3], accB, 0, 0, 0);
      accA = __builtin_amdgcn_mfma_f32_16x16x32_f16(qfh[1], cA[2], accA, 0, 0, 0);
      accB = __builtin_amdgcn_mfma_f32_16x16x32_f16(qfh[1], cB[2], accB, 0, 0, 0);
      const int ja = ta*16 + fr, jb = tb*16 + fr;
      #pragma unroll
      for (int jj = 0; jj < 4; ++jj){
        const int row = fq*4 + jj;
        Sj[row*SJP + ja] += accA[jj];
        Sj[row*SJP + jb] += accB[jj];
      }
      #pragma unroll
      for (int i = 0; i < 4; ++i){ cA[i] = nA[i]; cB[i] = nB[i]; }
    }
  }
  __syncthreads();

  // ---- softmax: row r = t>>4, lane g = t&15 handles j = g + 16m ----
  {
    const int r = t >> 4, g = t & 15;
    float sv[64];
    float mx = -3.0e38f;
    #pragma unroll
    for (int m = 0; m < 64; ++m){
      float x = Sj[r*SJP + g + (m<<4)] * 0.125f;
      sv[m] = x; mx = fmaxf(mx, x);
    }
    #pragma unroll
    for (int o = 8; o; o >>= 1) mx = fmaxf(mx, __shfl_xor(mx, o, 64));
    float sum = 0.f;
    #pragma unroll
    for (int m = 0; m < 64; ++m){ sv[m] = __expf(sv[m] - mx); sum += sv[m]; }
    #pragma unroll
    for (int o = 8; o; o >>= 1) sum += __shfl_xor(sum, o, 64);
    const float inv = 1.f / sum;
    __syncthreads();                           // Sj fully consumed into registers
    for (int i = t; i < 17056; i += 256) ((unsigned*)smem)[i] = 0;   // zero Ph+Pl
    __syncthreads();
    #pragma unroll
    for (int m = 0; m < 64; ++m){
      float p = sv[m] * inv;
      u16 hh, ll; fsplit(p, hh, ll);
      const int c = r + g + (m<<4);            // band position (<= 1038)
      Ph[r*PJP + c] = hh;
      Pl[r*PJP + c] = ll;
    }
  }
  __syncthreads();

  // ---- phase C: PV. wave wid owns d-tile wid (16 d); K-dim = 33x32; reg pipeline ----
  {
    f32x4 acc0 = {0.f,0.f,0.f,0.f}, acc1 = {0.f,0.f,0.f,0.f};
    const int qq = fq & 1;
    auto vfrag = [&](int ks, f16x8& vh, f16x8& vl){
      int kc16 = bx + 2*ks + (fq >> 1);
      if (kc16 > 127) kc16 = 127;              // OOB keys: P' zero there
      const long vo = plane + (((long)kc16*4 + wid)*2 + qq)*128 + fr*8;
      vh = *(const f16x8*)(Vph + vo);
      vl = *(const f16x8*)(Vpl + vo);
    };
    auto pfrag = [&](int ks, f16x8& ah, f16x8& al){
      ah = *(const f16x8*)(Ph + fr*PJP + ks*32 + fq*8);
      al = *(const f16x8*)(Pl + fr*PJP + ks*32 + fq*8);
    };
    f16x8 cvh, cvl, cah, cal, nvh, nvl, nah, nal;
    vfrag(0, cvh, cvl); pfrag(0, cah, cal);
    for (int ks = 0; ks < 33; ++ks){
      if (ks + 1 < 33){ vfrag(ks + 1, nvh, nvl); pfrag(ks + 1, nah, nal); }
      f32x4& a = (ks & 1) ? acc1 : acc0;
      a = __builtin_amdgcn_mfma_f32_16x16x32_f16(cal, cvh, a, 0, 0, 0);
      a = __builtin_amdgcn_mfma_f32_16x16x32_f16(cah, cvl, a, 0, 0, 0);
      a = __builtin_amdgcn_mfma_f32_16x16x32_f16(cah, cvh, a, 0, 0, 0);
      cvh = nvh; cvl = nvl; cah = nah; cal = nal;
    }
    #pragma unroll
    for (int jj = 0; jj < 4; ++jj){
      float v = acc0[jj] + acc1[jj];
      u16 hh, ll; fsplit(v, hh, ll);
      const int row = fq*4 + jj;
      const long o = ((long)(b*1024 + q0 + row))*1024 + hd*64 + wid*16 + fr;
      oh[o] = hh; ol[o] = ll;
    }
  }
}

// ======================= MFMA bf16 GEMM for MoE (z-batched, double-buffered) =======================

template<bool GATHER, bool RELU>
__global__ __launch_bounds__(256)
void gemm_bt(const u16* __restrict__ A, const u16* __restrict__ Bt, u16* __restrict__ Cp,
             const float* __restrict__ bias, int N, int Kd, int maxA,
             const int* __restrict__ offs, const int* __restrict__ counts,
             const int* __restrict__ gather, int ebase)
{
  __shared__ __align__(16) u16 As[2][4096];
  __shared__ __align__(16) u16 Bs[2][4096];
  const int z = blockIdx.z;
  const int e = ebase + z;
  const int rbase = offs[e];
  const int cnt   = counts[e];
  const int tm = blockIdx.y, tn = blockIdx.x;
  if (tm * 128 >= cnt) return;
  const u16* BtE = Bt + (long)z * N * Kd;
  const float* biasE = bias + (long)e * N;

  const int t = threadIdx.x;
  const int lane = t & 63, wv = t >> 6;
  const int wm = wv >> 1, wn = wv & 1;
  const int fr = lane & 15, fq = lane >> 4;

  const int r0l = 32*wv + (lane >> 2);
  const int r1l = r0l + 16;
  const int colu = (lane & 3) << 3;
  auto amap = [&](int rl)->long{
    int r = tm*128 + rl;
    int rc = (r < cnt) ? r : (cnt - 1);
    if (GATHER){
      int gi = rbase + rc; gi = (gi < 0) ? 0 : ((gi > 8191) ? 8191 : gi);
      int tok = gather[gi];
      tok = (tok < 0) ? 0 : ((tok >= maxA) ? (maxA - 1) : tok);
      return (long)tok;
    }
    return (long)(rbase + rc);
  };
  const long ar0 = amap(r0l), ar1 = amap(r1l);
  const long br0 = (long)(tn*128 + r0l), br1 = (long)(tn*128 + r1l);
  const u16* pa0 = A + ar0*Kd + colu;    const u16* pa1 = A + ar1*Kd + colu;
  const u16* pb0 = BtE + br0*Kd + colu;  const u16* pb1 = BtE + br1*Kd + colu;

  f32x4 acc[4][4];
  const f32x4 z4 = {0.f,0.f,0.f,0.f};
  #pragma unroll
  for (int m=0;m<4;m++)
    #pragma unroll
    for (int n=0;n<4;n++) acc[m][n] = z4;

  auto issue = [&](int bufi, int kt){
    const int ko = kt << 5;
    gll16(pa0 + ko, As[bufi] + 1024*wv);
    gll16(pa1 + ko, As[bufi] + 1024*wv + 512);
    gll16(pb0 + ko, Bs[bufi] + 1024*wv);
    gll16(pb1 + ko, Bs[bufi] + 1024*wv + 512);
  };

  const int nk = Kd >> 5;
  issue(0, 0);
  for (int kt = 0; kt < nk; ++kt) {
    const int cur = kt & 1;
    __syncthreads();
    if (kt + 1 < nk) issue(cur ^ 1, kt + 1);
    bf16x8 af[4], bfv[4];
    #pragma unroll
    for (int m=0;m<4;m++) af[m]  = *(const bf16x8*)(As[cur] + (wm*64 + m*16 + fr)*32 + fq*8);
    #pragma unroll
    for (int n=0;n<4;n++) bfv[n] = *(const bf16x8*)(Bs[cur] + (wn*64 + n*16 + fr)*32 + fq*8);
    #pragma unroll
    for (int m=0;m<4;m++)
      #pragma unroll
      for (int n=0;n<4;n++)
        acc[m][n] = __builtin_amdgcn_mfma_f32_16x16x32_bf16(af[m], bfv[n], acc[m][n], 0, 0, 0);
  }

  #pragma unroll
  for (int m=0;m<4;m++){
    #pragma unroll
    for (int j=0;j<4;j++){
      const int r = tm*128 + wm*64 + m*16 + fq*4 + j;
      if (r >= cnt) continue;
      const long crow = (long)(rbase + r);
      #pragma unroll
      for (int n=0;n<4;n++){
        const int c = tn*128 + wn*64 + n*16 + fr;
        float vv = acc[m][n][j] + biasE[c];
        if (RELU) vv = fmaxf(vv, 0.f);
        Cp[crow * N + c] = f2bf(vv);
      }
    }
  }
}

// ======================= layernorm / gate / moe plumbing =======================

__device__ __forceinline__ void block_reduce2(float& s1, float& s2){
  #pragma unroll
  for (int o = 32; o; o >>= 1){
    s1 += __shfl_xor(s1, o, 64);
    s2 += __shfl_xor(s2, o, 64);
  }
  __shared__ float r1[4], r2[4];
  const int wid = threadIdx.x >> 6;
  if ((threadIdx.x & 63) == 0){ r1[wid] = s1; r2[wid] = s2; }
  __syncthreads();
  s1 = r1[0] + r1[1] + r1[2] + r1[3];
  s2 = r2[0] + r2[1] + r2[2] + r2[3];
  __syncthreads();
}

// fused: h1 = LN(h + aproj), h1b = bf16(h1), gate logits + top-2 bucketing
__global__ __launch_bounds__(256)
void add_ln_gate(const float* __restrict__ a, const float* __restrict__ r,
                 const float* __restrict__ g, const float* __restrict__ bb,
                 const float* __restrict__ gw, const float* __restrict__ gb,
                 float* __restrict__ of, u16* __restrict__ ob,
                 int* __restrict__ eidx, float* __restrict__ esc, int* __restrict__ counts)
{
  const long row = blockIdx.x;
  const int t = threadIdx.x;
  float y[4]; float sum = 0.f, sq = 0.f;
  #pragma unroll
  for (int i = 0; i < 4; ++i){
    const long idx = row*1024 + t + (i<<8);
    float vv = a[idx] + r[idx];
    y[i] = vv; sum += vv; sq += vv*vv;
  }
  block_reduce2(sum, sq);
  const float mu = sum * (1.f/1024.f);
  const float var = fmaxf(sq * (1.f/1024.f) - mu*mu, 0.f);
  const float rs = rsqrtf(var + 1e-5f);
  float ge[8];
  #pragma unroll
  for (int e=0;e<8;e++) ge[e]=0.f;
  #pragma unroll
  for (int i = 0; i < 4; ++i){
    const int hcol = t + (i<<8);
    float o = (y[i] - mu) * rs * g[hcol] + bb[hcol];
    of[row*1024 + hcol] = o;
    ob[row*1024 + hcol] = f2bf(o);
    const float* gr = gw + hcol*8;
    #pragma unroll
    for (int e=0;e<8;e++) ge[e] += o * gr[e];
  }
  #pragma unroll
  for (int e=0;e<8;e++)
    #pragma unroll
    for (int o=32;o;o>>=1) ge[e] += __shfl_xor(ge[e], o, 64);
  __shared__ float red[4][8];
  const int wid = t >> 6;
  if ((t & 63)==0){
    #pragma unroll
    for (int e=0;e<8;e++) red[wid][e]=ge[e];
  }
  __syncthreads();
  if (t == 0){
    float l[8];
    #pragma unroll
    for (int e=0;e<8;e++) l[e] = red[0][e]+red[1][e]+red[2][e]+red[3][e] + gb[e];
    int i0 = 0; float v0 = l[0];
    #pragma unroll
    for (int e=1;e<8;e++) if (l[e] > v0){ v0=l[e]; i0=e; }
    int i1 = -1; float v1 = -3.0e38f;
    #pragma unroll
    for (int e=0;e<8;e++) if (e != i0 && l[e] > v1){ v1=l[e]; i1=e; }
    float e1 = __expf(v1 - v0);
    float den = 1.f + e1;
    eidx[row*2+0]=i0; eidx[row*2+1]=i1;
    esc[row*2+0]=1.f/den; esc[row*2+1]=e1/den;
    atomicAdd(&counts[i0],1); atomicAdd(&counts[i1],1);
  }
}

__global__ void scan_kernel(const int* __restrict__ counts, int* __restrict__ offs,
                            int* __restrict__ curs)
{
  if (threadIdx.x == 0 && blockIdx.x == 0){
    int acc = 0;
    for (int e=0;e<8;e++){ offs[e]=acc; curs[e]=acc; acc += counts[e]; }
  }
}

__global__ __launch_bounds__(256)
void scatter_kernel(const int* __restrict__ eidx, int* __restrict__ curs,
                    int* __restrict__ stok, int* __restrict__ ppos)
{
  int id = blockIdx.x*256 + threadIdx.x;
  if (id >= 8192) return;
  int e = eidx[id];
  e = (e < 0) ? 0 : ((e > 7) ? 7 : e);
  int pos = atomicAdd(&curs[e], 1);
  pos = (pos < 0) ? 0 : ((pos > 8191) ? 8191 : pos);
  stok[pos] = id >> 1;
  ppos[id] = pos;
}

__global__ __launch_bounds__(256)
void moe_combine_ln(const float* __restrict__ h1, const u16* __restrict__ pout,
                    const float* __restrict__ esc, const int* __restrict__ ppos,
                    const float* __restrict__ mg, const float* __restrict__ mb,
                    const float* __restrict__ n2g, const float* __restrict__ n2b,
                    float* __restrict__ outp)
{
  const long row = blockIdx.x;
  const int t = threadIdx.x;
  int p0i = ppos[row*2+0], p1i = ppos[row*2+1];
  p0i = (p0i < 0) ? 0 : ((p0i > 8191) ? 8191 : p0i);
  p1i = (p1i < 0) ? 0 : ((p1i > 8191) ? 8191 : p1i);
  const long p0 = p0i, p1 = p1i;
  const float s0 = esc[row*2+0], s1 = esc[row*2+1];
  float x[4], y[4];
  float sum=0.f, sq=0.f;
  #pragma unroll
  for (int i=0;i<4;i++){
    const int hcol = t + (i<<8);
    const long idx = row*1024 + hcol;
    float xv = h1[idx];
    float m = s0 * bf2f(pout[p0*1024 + hcol]) + s1 * bf2f(pout[p1*1024 + hcol]);
    x[i]=xv; y[i]=xv+m; sum+=y[i]; sq+=y[i]*y[i];
  }
  block_reduce2(sum, sq);
  float mu = sum*(1.f/1024.f), var = fmaxf(sq*(1.f/1024.f)-mu*mu, 0.f), rs = rsqrtf(var+1e-5f);
  float zz[4]; float sum2=0.f, sq2=0.f;
  #pragma unroll
  for (int i=0;i<4;i++){
    const int hcol = t + (i<<8);
    float core = (y[i]-mu)*rs*mg[hcol]+mb[hcol];
    zz[i] = x[i] + core; sum2+=zz[i]; sq2+=zz[i]*zz[i];
  }
  block_reduce2(sum2, sq2);
  float mu2 = sum2*(1.f/1024.f), var2 = fmaxf(sq2*(1.f/1024.f)-mu2*mu2, 0.f), rs2 = rsqrtf(var2+1e-5f);
  #pragma unroll
  for (int i=0;i<4;i++){
    const int hcol = t + (i<<8);
    outp[row*1024 + hcol] = (zz[i]-mu2)*rs2*n2g[hcol]+n2b[hcol];
  }
}

// ======================= launcher =======================
// Workspace (peak 146 MB; metadata at offset 0) — same map as R12 (proven):
//  0..1 metadata | 1..1.5 PEp | 2..18 hall_h->h1 | 18..34 hall_l->h1b
//  34..50 w pairs -> wTg 34..66 | 50..66 qh/ql -> aproj | 66..82 Kp_h -> xhid 66..130
//  82..98 Kp_l | 98..114 Vp_h | 114..130 Vp_l | 130..146 aout -> pout

extern "C" void kernel_launch(void* const* d_in, const int* in_sizes, int n_in,
                              void* d_out, int out_size, void* d_ws, size_t ws_size,
                              hipStream_t stream)
{
  const float* h      = (const float*)d_in[0];
  const float* hc     = (const float*)d_in[1];
  const float* key_pe = (const float*)d_in[2];
  const float* wq     = (const float*)d_in[3];
  const float* wk     = (const float*)d_in[4];
  const float* wv     = (const float*)d_in[5];
  const float* wo     = (const float*)d_in[6];
  const float* n1g    = (const float*)d_in[7];
  const float* n1b    = (const float*)d_in[8];
  const float* n2g    = (const float*)d_in[9];
  const float* n2b    = (const float*)d_in[10];
  const float* mlg    = (const float*)d_in[11];
  const float* mlb    = (const float*)d_in[12];
  const float* gw     = (const float*)d_in[13];
  const float* gb     = (const float*)d_in[14];
  const float* ew1    = (const float*)d_in[15];
  const float* eb1    = (const float*)d_in[16];
  const float* ew2    = (const float*)d_in[17];
  const float* eb2    = (const float*)d_in[18];
  float* outp = (float*)d_out;

  const size_t MB = 1ull << 20;
  char* base = (char*)d_ws;
  int*   counts = (int*)(base);
  int*   offs   = (int*)(base + 256);
  int*   curs   = (int*)(base + 512);
  int*   eidx   = (int*)(base + 1024);
  float* esc    = (float*)(base + 64*1024);
  int*   stok   = (int*)(base + 128*1024);
  int*   ppos   = (int*)(base + 192*1024);
  u16*   PEp_h  = (u16*)(base + 1*MB);
  u16*   PEp_l  = (u16*)(base + 1*MB + 256*1024);
  u16*   hall_h = (u16*)(base + 2*MB);      // 16MB
  float* h1     = (float*)(base + 2*MB);    //   alias (post-QKV)
  u16*   hall_l = (u16*)(base + 18*MB);     // 16MB
  u16*   h1b    = (u16*)(base + 18*MB);     //   alias (post-QKV; 18..26)
  u16*   wall_h = (u16*)(base + 34*MB);     // 6MB  [wk|wv|wq]^T
  u16*   wall_l = (u16*)(base + 40*MB);     // 6MB
  u16*   woT_h  = (u16*)(base + 46*MB);     // 2MB
  u16*   woT_l  = (u16*)(base + 48*MB);     // 2MB
  u16*   wTg    = (u16*)(base + 34*MB);     //   alias (post add_ln_gate; 34..66)
  u16*   qh     = (u16*)(base + 50*MB);     // 8MB
  u16*   ql     = (u16*)(base + 58*MB);     // 8MB
  float* aproj  = (float*)(base + 50*MB);   //   alias (post-attn; 50..66)
  u16*   Kp_h   = (u16*)(base + 66*MB);     // 16MB
  u16*   Kp_l   = (u16*)(base + 82*MB);     // 16MB
  u16*   Vp_h   = (u16*)(base + 98*MB);     // 16MB
  u16*   Vp_l   = (u16*)(base + 114*MB);    // 16MB
  u16*   xhid   = (u16*)(base + 66*MB);     //   alias (post-attn; 66..130)
  u16*   aout_h = (u16*)(base + 130*MB);    // 8MB
  u16*   aout_l = (u16*)(base + 138*MB);    // 8MB
  u16*   pout   = (u16*)(base + 130*MB);    //   alias (post-WO; 130..146)

  zero8<<<1, 64, 0, stream>>>(counts);
  dim3 tb32(32, 8);

  // conversions
  cvt_split_hall<<<8192, 256, 0, stream>>>(hc, h, hall_h, hall_l);
  pack_pe<<<64, 128, 0, stream>>>(key_pe, PEp_h, PEp_l);
  transpose_split4<<<dim3(32,32,4), tb32, 0, stream>>>(wk, wv, wq, wo,
                                                       wall_h, wall_l, woT_h, woT_l);

  // fused QKV projection (split-f16 MFMA, f32-exact): one dispatch, N=3072
  gemm_sp<4,false><<<dim3(24,64), 256, 0, stream>>>(hall_h, hall_l, wall_h, wall_l, nullptr,
                                                    Kp_h, Kp_l, Vp_h, Vp_l, qh, ql, 3072, 1024);

  // MFMA attention (16 q-rows/block, fragment-packed, reg-pipelined, XCD-swizzled)
  attn_mfma<<<4096, 256, 0, stream>>>(qh, ql, Kp_h, Kp_l, Vp_h, Vp_l, PEp_h, PEp_l, aout_h, aout_l);

  // WO projection (double-buffered; 1 block/CU dispatch) + fused residual-LN+gate
  gemm_sp<0,true><<<dim3(8,32), 256, 0, stream>>>(aout_h, aout_l, woT_h, woT_l, aproj,
                                                  nullptr, nullptr, nullptr, nullptr, nullptr, nullptr, 1024, 1024);
  add_ln_gate<<<4096, 256, 0, stream>>>(h, aproj, n1g, n1b, gw, gb, h1, h1b, eidx, esc, counts);

  scan_kernel<<<1, 64, 0, stream>>>(counts, offs, curs);
  scatter_kernel<<<32, 256, 0, stream>>>(eidx, curs, stok, ppos);

  // per-group (4 experts) FFN: z-batched transposes + double-buffered gemms
  for (int g = 0; g < 2; ++g){
    transpose_cvt_z<<<dim3(128,32,4), tb32, 0, stream>>>(
        ew1 + (long)g*4*1024*4096, wTg, 1024, 4096, 4096L*1024, 4096L*1024);
    gemm_bt<true, true ><<<dim3(32,64,4), 256, 0, stream>>>(
        h1b, wTg, xhid, eb1, 4096, 1024, 4096, offs, counts, stok, g*4);
  }
  for (int g = 0; g < 2; ++g){
    transpose_cvt_z<<<dim3(32,128,4), tb32, 0, stream>>>(
        ew2 + (long)g*4*4096*1024, wTg, 4096, 1024, 4096L*1024, 4096L*1024);
    gemm_bt<false, false><<<dim3(8,64,4), 256, 0, stream>>>(
        xhid, wTg, pout, eb2, 1024, 4096, 8192, offs, counts, nullptr, g*4);
  }

  // combine + the two trailing layernorms
  moe_combine_ln<<<4096, 256, 0, stream>>>(h1, pout, esc, ppos, mlg, mlb, n2g, n2b, outp);
}